// Round 1
// baseline (938.631 us; speedup 1.0000x reference)
//
#include <hip/hip_runtime.h>
#include <cstddef>
#include <cstdint>

// ---------------- problem constants ----------------
#define B8    8
#define CH32  32
#define L256  256
#define DIN   512
#define DIM   256
#define DI    512
#define NSTATE 32
#define DTR   16
#define MROWS 2048           // B8*L256
#define KBIG  16384          // DIN*CH32
#define KSPLIT 16            // lin0 split-K

// ---------------- ws layout (float offsets) ----------------
// early chain
static const size_t F_XT0  = 0;          // 2048*256
static const size_t F_SKIP = 524288;     // 2048*256
static const size_t F_XS   = 1048576;    // 2048*256
static const size_t F_XZ   = 1572864;    // 2048*1024
static const size_t F_XC   = 3670016;    // 2048*512
static const size_t F_XDBL = 4718592;    // 2048*80
static const size_t F_DT   = 4882432;    // 2048*512
static const size_t F_YG   = 5931008;    // 2048*512
static const size_t F_YM   = 6979584;    // 2048*256
static const size_t F_XS2  = 7503872;    // 2048*256
static const size_t F_CAT  = 8028160;    // 2048*512
static const size_t F_DEC  = 9076736;    // 2048*256 (ends 9601024)
// region B: Wp + split-K partials (dead after LN0/lin1) -> conv ping-pong later
static const size_t F_WP   = 10485760;   // 16384*256
static const size_t F_PART = 14680064;   // KSPLIT*2048*256 (ends 23068672)
static const size_t F_C1   = 10485760;   // 8*16*256*256 (alias Wp+part)
static const size_t F_C2   = 0;          // 8*16*256*256 (alias early chain; F_DEC @9076736 is safe)
static const size_t F_C3   = 10485760;   // reuse C1 region (dead once C2 written)
// total ws needed: 23068672 floats = 92,274,688 bytes

__device__ __forceinline__ float siluf(float v)     { return v / (1.f + __expf(-v)); }
__device__ __forceinline__ float softplusf(float v) { return v > 20.f ? v : log1pf(__expf(v)); }

// ---------------- Wp: lin0_w [256][16384] -> Wp[k'=c*512+f][256] ----------------
__global__ __launch_bounds__(256) void transpose_w_k(const float* __restrict__ w,
                                                     float* __restrict__ wp) {
  __shared__ float t[64][65];
  int k0 = blockIdx.x << 6;
  int o0 = blockIdx.y << 6;
  int tid = threadIdx.x;
  for (int i = tid; i < 64 * 64; i += 256) {
    int oo = i >> 6, kk = i & 63;
    t[oo][kk] = w[(size_t)(o0 + oo) * KBIG + k0 + kk];
  }
  __syncthreads();
  for (int i = tid; i < 64 * 64; i += 256) {
    int kk = i >> 6, oo = i & 63;
    int k = k0 + kk;
    int f = k >> 5, c = k & 31;
    wp[((size_t)c * 512 + f) * 256 + o0 + oo] = t[oo][kk];
  }
}

// ---------------- lin0 GEMM: A = gathered x (coalesced along f), W = Wp ----------------
// BM=32, BN=256 (full), BK=16, split-K=16.  grid = 64 m-tiles * 16 z = 1024 blocks.
__global__ __launch_bounds__(256) void gemm_lin0_k(const float* __restrict__ x,
                                                   const float* __restrict__ wp,
                                                   float* __restrict__ part) {
  __shared__ __align__(16) float As[16][36];
  __shared__ __align__(16) float Ws[16][256];
  int id = blockIdx.x;
  int z  = id & 15;           // k-slab; id%8 keys XCD -> 2MB W slab per L2
  int mt = id >> 4;
  int m0 = mt << 5;
  int b  = m0 >> 8, l0 = m0 & 255;
  int tid = threadIdx.x;
  int ty = tid >> 5, tx = tid & 31;
  float acc[4][8];
#pragma unroll
  for (int r = 0; r < 4; ++r)
#pragma unroll
    for (int j = 0; j < 8; ++j) acc[r][j] = 0.f;

  int kbeg = z << 10;  // 1024 k' per slab (2 c-values)
  int arow = tid >> 2, af = (tid & 3) << 2;
  const float* xrow = x + (((size_t)b << 5) << 17) + ((size_t)(l0 + arow) << 9);

  for (int kc = kbeg; kc < kbeg + 1024; kc += 16) {
    int c = kc >> 9, f0 = kc & 511;
    float4 av = make_float4(0.f, 0.f, 0.f, 0.f);
    if (tid < 128) av = *(const float4*)(xrow + ((size_t)c << 17) + f0 + af);
    float4 wv[4];
#pragma unroll
    for (int p = 0; p < 4; ++p) {
      int kk = (tid >> 6) + (p << 2);
      int n  = (tid & 63) << 2;
      wv[p] = *(const float4*)(wp + ((size_t)(kc + kk) << 8) + n);
    }
    __syncthreads();
    if (tid < 128) {
      As[af + 0][arow] = av.x; As[af + 1][arow] = av.y;
      As[af + 2][arow] = av.z; As[af + 3][arow] = av.w;
    }
#pragma unroll
    for (int p = 0; p < 4; ++p) {
      int kk = (tid >> 6) + (p << 2);
      int n  = (tid & 63) << 2;
      *(float4*)&Ws[kk][n] = wv[p];
    }
    __syncthreads();
#pragma unroll
    for (int kk = 0; kk < 16; ++kk) {
      float a[4];
      *(float4*)a = *(const float4*)&As[kk][ty << 2];
      float w[8];
      *(float4*)&w[0] = *(const float4*)&Ws[kk][tx << 3];
      *(float4*)&w[4] = *(const float4*)&Ws[kk][(tx << 3) + 4];
#pragma unroll
      for (int r = 0; r < 4; ++r)
#pragma unroll
        for (int j = 0; j < 8; ++j) acc[r][j] = fmaf(a[r], w[j], acc[r][j]);
    }
  }
  float* po = part + ((size_t)z * MROWS + m0 + (ty << 2)) * 256 + (tx << 3);
#pragma unroll
  for (int r = 0; r < 4; ++r) {
    *(float4*)(po + (size_t)r * 256)     = make_float4(acc[r][0], acc[r][1], acc[r][2], acc[r][3]);
    *(float4*)(po + (size_t)r * 256 + 4) = make_float4(acc[r][4], acc[r][5], acc[r][6], acc[r][7]);
  }
}

// ---------------- sum partials + bias -> relu -> LayerNorm (N=256) ----------------
__global__ __launch_bounds__(256) void ln_k(const float* __restrict__ part, int npart,
                                            const float* __restrict__ bias,
                                            const float* __restrict__ g,
                                            const float* __restrict__ bb,
                                            float* __restrict__ out) {
  int m = blockIdx.x, t = threadIdx.x;
  float s = bias[t];
  for (int z = 0; z < npart; ++z) s += part[((size_t)z * MROWS + m) * 256 + t];
  float v = fmaxf(s, 0.f);
  float sum = v, sq = v * v;
#pragma unroll
  for (int o = 1; o < 64; o <<= 1) { sum += __shfl_xor(sum, o); sq += __shfl_xor(sq, o); }
  __shared__ float s1[4], s2[4];
  int w = t >> 6;
  if ((t & 63) == 0) { s1[w] = sum; s2[w] = sq; }
  __syncthreads();
  sum = s1[0] + s1[1] + s1[2] + s1[3];
  sq  = s2[0] + s2[1] + s2[2] + s2[3];
  float mu  = sum * (1.f / 256.f);
  float var = sq * (1.f / 256.f) - mu * mu;
  out[(size_t)m * 256 + t] = (v - mu) * rsqrtf(var + 1e-5f) * g[t] + bb[t];
}

// ---------------- generic fp32 GEMM: out[M][N] = A[M][K](lda) * W[N][K]^T ----------------
// BM=RM*16, BN=64, BK=16; 256 threads (16x16), thread tile RM x 4.
template <int RM, int ACT, int HASBIAS>
__global__ __launch_bounds__(256) void gemm_k(const float* __restrict__ A, int lda,
                                              const float* __restrict__ W,
                                              const float* __restrict__ bias,
                                              float* __restrict__ out,
                                              int M, int N, int K) {
  const int BM = RM * 16;
  __shared__ __align__(16) float As[16][RM * 16 + 4];
  __shared__ __align__(16) float Ws[16][68];
  int n0 = blockIdx.x << 6;
  int m0 = blockIdx.y * BM;
  int tid = threadIdx.x;
  int tx = tid & 15, ty = tid >> 4;
  float acc[RM][4];
#pragma unroll
  for (int r = 0; r < RM; ++r)
#pragma unroll
    for (int j = 0; j < 4; ++j) acc[r][j] = 0.f;

  for (int k0 = 0; k0 < K; k0 += 16) {
    __syncthreads();
    for (int i = tid; i < BM * 16; i += 256) {
      int r = i >> 4, kk = i & 15;
      As[kk][r] = A[(size_t)(m0 + r) * lda + k0 + kk];
    }
    for (int i = tid; i < 64 * 16; i += 256) {
      int r = i >> 4, kk = i & 15;
      int n = n0 + r;
      Ws[kk][r] = (n < N) ? W[(size_t)n * K + k0 + kk] : 0.f;
    }
    __syncthreads();
#pragma unroll
    for (int kk = 0; kk < 16; ++kk) {
      float4 wv = *(const float4*)&Ws[kk][tx << 2];
#pragma unroll
      for (int r = 0; r < RM; ++r) {
        float a = As[kk][ty * RM + r];
        acc[r][0] = fmaf(a, wv.x, acc[r][0]);
        acc[r][1] = fmaf(a, wv.y, acc[r][1]);
        acc[r][2] = fmaf(a, wv.z, acc[r][2]);
        acc[r][3] = fmaf(a, wv.w, acc[r][3]);
      }
    }
  }
#pragma unroll
  for (int r = 0; r < RM; ++r) {
    int m = m0 + ty * RM + r;
#pragma unroll
    for (int j = 0; j < 4; ++j) {
      int n = n0 + (tx << 2) + j;
      if (n < N) {
        float v = acc[r][j];
        if (HASBIAS) v += bias[n];
        if (ACT == 1) v = fmaxf(v, 0.f);
        if (ACT == 2) v = softplusf(v);
        out[(size_t)m * N + n] = v;
      }
    }
  }
}

// ---------------- xs = skip + pos ----------------
__global__ __launch_bounds__(256) void addpos_k(const float* __restrict__ a,
                                                const float* __restrict__ pos,
                                                float* __restrict__ o) {
  int i = blockIdx.x * 256 + threadIdx.x;
  o[i] = a[i] + pos[i & 65535];
}

// ---------------- causal depthwise conv1d(k=4) + silu ----------------
__global__ __launch_bounds__(256) void conv1d_silu_k(const float* __restrict__ xz,
                                                     const float* __restrict__ w,
                                                     const float* __restrict__ cb,
                                                     float* __restrict__ xc) {
  int i = blockIdx.x * 256 + threadIdx.x;  // over 2048*512
  int m = i >> 9, d = i & 511;
  int b = m >> 8, l = m & 255;
  float s = cb[d];
#pragma unroll
  for (int j = 0; j < 4; ++j) {
    int ll = l - 3 + j;
    if (ll >= 0) s = fmaf(w[(d << 2) + j], xz[((size_t)((b << 8) + ll) << 10) + d], s);
  }
  xc[(size_t)m * 512 + d] = siluf(s);
}

// ---------------- selective scan (+ *silu(z) gating) ----------------
// wave = 2 channels x 32 states; 2048 waves total.
__global__ __launch_bounds__(256) void scan_k(const float* __restrict__ dt,
                                              const float* __restrict__ u,
                                              const float* __restrict__ xdbl,
                                              const float* __restrict__ Alog,
                                              const float* __restrict__ Dp,
                                              const float* __restrict__ xz,
                                              float* __restrict__ yg) {
  int tid  = threadIdx.x;
  int wid  = (blockIdx.x << 2) + (tid >> 6);
  int lane = tid & 63;
  int n = lane & 31;
  int d = ((wid & 255) << 1) + (lane >> 5);
  int b = wid >> 8;
  float Av = -__expf(Alog[(d << 5) + n]);
  float Dv = Dp[d];
  size_t base = (size_t)b << 8;
  float h = 0.f;
  float dtv = dt[(base << 9) + d];
  float uv  = u [(base << 9) + d];
  float Bv  = xdbl[base * 80 + 16 + n];
  float Cv  = xdbl[base * 80 + 48 + n];
  for (int l = 0; l < 256; ++l) {
    float ndt = 0.f, nu = 0.f, nB = 0.f, nC = 0.f;
    if (l < 255) {
      size_t r = base + l + 1;
      ndt = dt[(r << 9) + d];
      nu  = u [(r << 9) + d];
      nB  = xdbl[r * 80 + 16 + n];
      nC  = xdbl[r * 80 + 48 + n];
    }
    float dA = __expf(dtv * Av);
    h = fmaf(dA, h, dtv * Bv * uv);
    float p = h * Cv;
    p += __shfl_xor(p, 1);
    p += __shfl_xor(p, 2);
    p += __shfl_xor(p, 4);
    p += __shfl_xor(p, 8);
    p += __shfl_xor(p, 16);
    if (n == 0) {
      size_t r = base + l;
      float zv = xz[(r << 10) + 512 + d];
      yg[(r << 9) + d] = (p + uv * Dv) * siluf(zv);
    }
    dtv = ndt; uv = nu; Bv = nB; Cv = nC;
  }
}

// ---------------- cat = [xs2 | skip] ----------------
__global__ __launch_bounds__(256) void concat_k(const float* __restrict__ a,
                                                const float* __restrict__ b,
                                                float* __restrict__ o) {
  int i = blockIdx.x * 256 + threadIdx.x;  // 2048*512
  int m = i >> 9, j = i & 511;
  o[i] = (j < 256) ? a[(size_t)m * 256 + j] : b[(size_t)m * 256 + j - 256];
}

// ---------------- direct 3x3 conv, OC=16, relu; tile 64x4, thread = 4px x 4oc ----------------
template <int IC>
__global__ __launch_bounds__(256) void conv3x3_k(const float* __restrict__ in,
                                                 const float* __restrict__ w,
                                                 const float* __restrict__ bias,
                                                 float* __restrict__ out) {
  __shared__ float t[IC][6][68];
  __shared__ float wl[IC * 144];
  __shared__ float bl[16];
  int bid = blockIdx.x;
  int x0 = (bid & 3) << 6;
  int y0 = ((bid >> 2) & 63) << 2;
  int bb = bid >> 8;
  int tid = threadIdx.x;
  for (int i = tid; i < IC * 144; i += 256) {
    int oc = i & 15, t2 = i >> 4;
    wl[i] = w[(size_t)oc * (IC * 9) + t2];
  }
  if (tid < 16) bl[tid] = bias[tid];
  for (int i = tid; i < IC * 396; i += 256) {
    int ic = i / 396, rem = i - ic * 396;
    int r = rem / 66, cx = rem - r * 66;
    int y = y0 - 1 + r, xx = x0 - 1 + cx;
    float v = 0.f;
    if (y >= 0 && y < 256 && xx >= 0 && xx < 256)
      v = in[(((size_t)bb * IC + ic) << 16) + (y << 8) + xx];
    t[ic][r][cx] = v;
  }
  __syncthreads();
  int tx = tid & 15, row = (tid >> 4) & 3, ocq = tid >> 6;
  float acc[4][4];
#pragma unroll
  for (int o = 0; o < 4; ++o)
#pragma unroll
    for (int p = 0; p < 4; ++p) acc[o][p] = 0.f;

  for (int ic = 0; ic < IC; ++ic) {
#pragma unroll
    for (int dy = 0; dy < 3; ++dy) {
      const float* rp = &t[ic][row + dy][tx << 2];
      float rv[6];
#pragma unroll
      for (int q = 0; q < 6; ++q) rv[q] = rp[q];
#pragma unroll
      for (int dx = 0; dx < 3; ++dx) {
        const float* wp4 = &wl[(((ic * 3 + dy) * 3 + dx) << 4) + (ocq << 2)];
#pragma unroll
        for (int o = 0; o < 4; ++o) {
          float wv = wp4[o];
#pragma unroll
          for (int p = 0; p < 4; ++p) acc[o][p] = fmaf(rv[p + dx], wv, acc[o][p]);
        }
      }
    }
  }
  int xo = x0 + (tx << 2), yo = y0 + row;
#pragma unroll
  for (int o = 0; o < 4; ++o) {
    int oc = (ocq << 2) + o;
    float4 v4;
    v4.x = fmaxf(acc[o][0] + bl[oc], 0.f);
    v4.y = fmaxf(acc[o][1] + bl[oc], 0.f);
    v4.z = fmaxf(acc[o][2] + bl[oc], 0.f);
    v4.w = fmaxf(acc[o][3] + bl[oc], 0.f);
    *(float4*)&out[(((size_t)bb * 16 + oc) << 16) + (yo << 8) + xo] = v4;
  }
}

// ---------------- 2x2 mean pool + 1x1 conv (16->1) ----------------
__global__ __launch_bounds__(256) void pool_c4_k(const float* __restrict__ in,
                                                 const float* __restrict__ w4,
                                                 const float* __restrict__ b4,
                                                 float* __restrict__ out) {
  int i = blockIdx.x * 256 + threadIdx.x;  // 8*128*128
  int x = i & 127, y = (i >> 7) & 127, b = i >> 14;
  float s = b4[0];
#pragma unroll
  for (int ic = 0; ic < 16; ++ic) {
    const float* p = in + (((size_t)b * 16 + ic) << 16) + ((size_t)(y << 1) << 8) + (x << 1);
    float m4 = 0.25f * (p[0] + p[1] + p[256] + p[257]);
    s = fmaf(w4[ic], m4, s);
  }
  out[i] = s;
}

// ---------------- launcher ----------------
extern "C" void kernel_launch(void* const* d_in, const int* in_sizes, int n_in,
                              void* d_out, int out_size, void* d_ws, size_t ws_size,
                              hipStream_t stream) {
  const float* x        = (const float*)d_in[0];
  const float* lin0_w   = (const float*)d_in[1];
  const float* lin0_b   = (const float*)d_in[2];
  const float* ln0_g    = (const float*)d_in[3];
  const float* ln0_bb   = (const float*)d_in[4];
  const float* lin1_w   = (const float*)d_in[5];
  const float* lin1_b   = (const float*)d_in[6];
  const float* ln1_g    = (const float*)d_in[7];
  const float* ln1_bb   = (const float*)d_in[8];
  const float* pos      = (const float*)d_in[9];
  const float* m_in_w   = (const float*)d_in[10];
  const float* m_conv_w = (const float*)d_in[11];
  const float* m_conv_b = (const float*)d_in[12];
  const float* m_xproj_w= (const float*)d_in[13];
  const float* m_dt_w   = (const float*)d_in[14];
  const float* m_dt_b   = (const float*)d_in[15];
  const float* m_Alog   = (const float*)d_in[16];
  const float* m_D      = (const float*)d_in[17];
  const float* m_out_w  = (const float*)d_in[18];
  const float* blk_w    = (const float*)d_in[19];
  const float* blk_b    = (const float*)d_in[20];
  const float* dec_w    = (const float*)d_in[21];
  const float* dec_b    = (const float*)d_in[22];
  const float* c1_w     = (const float*)d_in[23];
  const float* c1_b     = (const float*)d_in[24];
  const float* c2_w     = (const float*)d_in[25];
  const float* c2_b     = (const float*)d_in[26];
  const float* c3_w     = (const float*)d_in[27];
  const float* c3_b     = (const float*)d_in[28];
  const float* c4_w     = (const float*)d_in[29];
  const float* c4_b     = (const float*)d_in[30];

  float* ws  = (float*)d_ws;
  float* out = (float*)d_out;

  // 1. permute lin0 weights: Wp[k'=c*512+f][o]
  transpose_w_k<<<dim3(256, 4), 256, 0, stream>>>(lin0_w, ws + F_WP);
  // 2. lin0 GEMM (gathered A, split-K partials)
  gemm_lin0_k<<<64 * KSPLIT, 256, 0, stream>>>(x, ws + F_WP, ws + F_PART);
  // 3. reduce + bias + relu + LN0 -> xt0
  ln_k<<<MROWS, 256, 0, stream>>>(ws + F_PART, KSPLIT, lin0_b, ln0_g, ln0_bb, ws + F_XT0);
  // 4. lin1 (raw) -> part ; 5. bias+relu+LN1 -> skip
  gemm_k<2, 0, 0><<<dim3(4, 64), 256, 0, stream>>>(ws + F_XT0, 256, lin1_w, nullptr,
                                                   ws + F_PART, MROWS, 256, 256);
  ln_k<<<MROWS, 256, 0, stream>>>(ws + F_PART, 1, lin1_b, ln1_g, ln1_bb, ws + F_SKIP);
  // 6. xs = skip + pos
  addpos_k<<<2048, 256, 0, stream>>>(ws + F_SKIP, pos, ws + F_XS);
  // 7. xz = xs @ m_in_w^T  [2048,1024]
  gemm_k<4, 0, 0><<<dim3(16, 32), 256, 0, stream>>>(ws + F_XS, 256, m_in_w, nullptr,
                                                    ws + F_XZ, MROWS, 1024, 256);
  // 8. causal dwconv + silu -> xc
  conv1d_silu_k<<<4096, 256, 0, stream>>>(ws + F_XZ, m_conv_w, m_conv_b, ws + F_XC);
  // 9. x_dbl = xc @ m_xproj_w^T  [2048,80]
  gemm_k<2, 0, 0><<<dim3(2, 64), 256, 0, stream>>>(ws + F_XC, 512, m_xproj_w, nullptr,
                                                   ws + F_XDBL, MROWS, 80, 512);
  // 10. dt = softplus(x_dbl[:, :16] @ m_dt_w^T + m_dt_b)  [2048,512]
  gemm_k<2, 2, 1><<<dim3(8, 64), 256, 0, stream>>>(ws + F_XDBL, 80, m_dt_w, m_dt_b,
                                                   ws + F_DT, MROWS, 512, 16);
  // 11. selective scan + silu(z) gating -> yg
  scan_k<<<512, 256, 0, stream>>>(ws + F_DT, ws + F_XC, ws + F_XDBL, m_Alog, m_D,
                                  ws + F_XZ, ws + F_YG);
  // 12. ym = yg @ m_out_w^T
  gemm_k<2, 0, 0><<<dim3(4, 64), 256, 0, stream>>>(ws + F_YG, 512, m_out_w, nullptr,
                                                   ws + F_YM, MROWS, 256, 512);
  // 13. xs2 = ym @ blk_w^T + blk_b
  gemm_k<2, 0, 1><<<dim3(4, 64), 256, 0, stream>>>(ws + F_YM, 256, blk_w, blk_b,
                                                   ws + F_XS2, MROWS, 256, 256);
  // 14. cat = [xs2 | skip]
  concat_k<<<4096, 256, 0, stream>>>(ws + F_XS2, ws + F_SKIP, ws + F_CAT);
  // 15. dec = relu(cat @ dec_w^T + dec_b)
  gemm_k<2, 1, 1><<<dim3(4, 64), 256, 0, stream>>>(ws + F_CAT, 512, dec_w, dec_b,
                                                   ws + F_DEC, MROWS, 256, 512);
  // 16-18. conv stack
  conv3x3_k<1><<<2048, 256, 0, stream>>>(ws + F_DEC, c1_w, c1_b, ws + F_C1);
  conv3x3_k<16><<<2048, 256, 0, stream>>>(ws + F_C1, c2_w, c2_b, ws + F_C2);
  conv3x3_k<16><<<2048, 256, 0, stream>>>(ws + F_C2, c3_w, c3_b, ws + F_C3);
  // 19. pool + 1x1 conv -> out
  pool_c4_k<<<512, 256, 0, stream>>>(ws + F_C3, c4_w, c4_b, out);
}

// Round 2
// 536.394 us; speedup vs baseline: 1.7499x; 1.7499x over previous
//
#include <hip/hip_runtime.h>
#include <hip/hip_bf16.h>
#include <cstddef>
#include <cstdint>

// ---------------- problem constants ----------------
#define MROWS 2048           // B8*L256
#define KBIG  16384          // DIN*CH32
#define KSPLIT 16            // lin0 split-K

typedef __attribute__((ext_vector_type(8))) short short8v;
typedef __attribute__((ext_vector_type(4))) float f32x4;
typedef unsigned int u32;

// ---------------- ws layout (float offsets) ----------------
static const size_t F_XT0  = 0;          // 2048*256
static const size_t F_SKIP = 524288;     // 2048*256
static const size_t F_XS   = 1048576;    // 2048*256
static const size_t F_XZ   = 1572864;    // 2048*1024
static const size_t F_XC   = 3670016;    // 2048*512
static const size_t F_XDBL = 4718592;    // 2048*80
static const size_t F_DT   = 4882432;    // 2048*512
static const size_t F_YG   = 5931008;    // 2048*512
static const size_t F_YM   = 6979584;    // 2048*256
static const size_t F_XS2  = 7503872;    // 2048*256
static const size_t F_CAT  = 8028160;    // 2048*512
static const size_t F_DEC  = 9076736;    // 2048*256 (ends 9601024)
static const size_t F_WMED = 9700000;    // 655360 floats of med W tiles (ends 10355360)
static const size_t F_WT0  = 10485760;   // lin0 split-bf16 tiles: 4194304 floats (ends 14680064)
static const size_t F_PART = 14680064;   // 16*2048*256 fp32 partials (ends 23068672)
static const size_t F_C1   = 10485760;   // conv ping-pong (aliases WT0+PART, dead by then)
static const size_t F_C2   = 0;          // aliases early chain (DEC @9076736 safe)
static const size_t F_C3   = 14680064;   // aliases PART (dead)
// total ws: 23068672 floats = 92,274,688 bytes (same as round-1 layout)

__device__ __forceinline__ float siluf(float v)     { return v / (1.f + __expf(-v)); }
__device__ __forceinline__ float softplusf(float v) { return v > 20.f ? v : log1pf(__expf(v)); }

__device__ __forceinline__ void split2(float v, short& h, short& l) {
  __hip_bfloat16 hb = __float2bfloat16(v);
  float hf = __bfloat162float(hb);
  __hip_bfloat16 lb = __float2bfloat16(v - hf);
  h = *(short*)&hb; l = *(short*)&lb;
}

__device__ __forceinline__ void glds16(const void* g, void* l) {
  __builtin_amdgcn_global_load_lds((const __attribute__((address_space(1))) u32*)g,
                                   (__attribute__((address_space(3))) u32*)l, 16, 0, 0);
}

#define MFMA3(acc, ah, al, bh, bl)                                            \
  acc = __builtin_amdgcn_mfma_f32_16x16x32_bf16(ah, bh, acc, 0, 0, 0);        \
  acc = __builtin_amdgcn_mfma_f32_16x16x32_bf16(al, bh, acc, 0, 0, 0);        \
  acc = __builtin_amdgcn_mfma_f32_16x16x32_bf16(ah, bl, acc, 0, 0, 0);

// ---------------- lin0 weight tiling: permute k -> k'=c*512+f, split bf16, tile to LDS image
// Wt[s(512)][kg(4)][col(256)][8]  (hi then lo)
__global__ __launch_bounds__(256) void tile_w_lin0(const float* __restrict__ w,
                                                   unsigned short* __restrict__ th,
                                                   unsigned short* __restrict__ tl) {
  int slot = blockIdx.x * 256 + threadIdx.x;       // 524288 slots
  int col = slot & 255, kg = (slot >> 8) & 3, s = slot >> 10;
  int kp = (s << 5) + (kg << 3);                   // k' base (8 contiguous, no 512-crossing)
  int c = kp >> 9, fb = kp & 511;
  const float* src = w + (size_t)col * KBIG + c;
  short8v h8, l8;
#pragma unroll
  for (int j = 0; j < 8; ++j) {
    float v = src[(size_t)(fb + j) << 5];
    short hh, ll; split2(v, hh, ll);
    h8[j] = hh; l8[j] = ll;
  }
  *(short8v*)(th + (size_t)slot * 8) = h8;
  *(short8v*)(tl + (size_t)slot * 8) = l8;
}

// ---------------- generic med weight tiling: Wt[nt][s][kg(4)][col(128)][8]
__global__ __launch_bounds__(256) void tile_w_med(const float* __restrict__ w,
                                                  unsigned short* __restrict__ th,
                                                  unsigned short* __restrict__ tl,
                                                  int K, int nslots) {
  int slot = blockIdx.x * 256 + threadIdx.x;
  if (slot >= nslots) return;
  int NS = K >> 5;
  int col = slot & 127, kg = (slot >> 7) & 3, rest = slot >> 9;
  int s = rest % NS, nt = rest / NS;
  const float* src = w + (size_t)(nt * 128 + col) * K + (s << 5) + (kg << 3);
  short8v h8, l8;
#pragma unroll
  for (int j = 0; j < 8; ++j) {
    short hh, ll; split2(src[j], hh, ll);
    h8[j] = hh; l8[j] = ll;
  }
  *(short8v*)(th + (size_t)slot * 8) = h8;
  *(short8v*)(tl + (size_t)slot * 8) = l8;
}

// ---------------- lin0 MFMA GEMM: BM=128, BN=256(full), BK=32, split-K=16 ----------------
// 512 threads = 8 waves (2m x 4n), wave tile 64x64. A fused fp32->split-bf16 staging.
__global__ __launch_bounds__(512, 2) void lin0_mfma(const float* __restrict__ x,
                                                    const unsigned short* __restrict__ wh,
                                                    const unsigned short* __restrict__ wl,
                                                    float* __restrict__ part) {
  __shared__ short8v Ah[512], Al[512];      // [4 kg][128 row'] of 16B
  __shared__ short8v Bd[2][2][1024];        // [buf][h/l][4 kg][256 col]
  int bid = blockIdx.x;
  int mt = bid >> 4, z = bid & 15;
  int tid = threadIdx.x;
  int lane = tid & 63, wid = tid >> 6;
  int wm = wid >> 2, wn = wid & 3;
  int fi = lane & 15, fq = lane >> 4;
  // A staging mapping: thread -> (row, kg)
  int arow = tid >> 2, akg = tid & 3;
  int awidx = akg * 128 + (arow ^ (akg << 2));
  int m0 = mt << 7;
  int am = m0 + arow;
  int ab = am >> 8, alr = am & 255;
  const float* xbase = x + ((size_t)ab << 5) * 131072 + ((size_t)alr << 9);
  // frag read offsets (loop-invariant)
  int aoff[4], boff[4];
#pragma unroll
  for (int mi = 0; mi < 4; ++mi) {
    int row = wm * 64 + mi * 16 + fi;
    aoff[mi] = fq * 128 + (row ^ (fq << 2));
  }
#pragma unroll
  for (int ni = 0; ni < 4; ++ni) boff[ni] = fq * 256 + wn * 64 + ni * 16 + fi;

  f32x4 acc[4][4];
#pragma unroll
  for (int mi = 0; mi < 4; ++mi)
#pragma unroll
    for (int ni = 0; ni < 4; ++ni) acc[mi][ni] = (f32x4)(0.f);

  // ---- prologue: stage step 0 ----
  {
    int sg = z << 5;  // global k-step
#pragma unroll
    for (int p = 0; p < 2; ++p) {
      int q = (wid << 1) + p;
      size_t gb = (size_t)sg * 16384 + (size_t)q * 1024 + (size_t)lane * 16;
      glds16((const char*)wh + gb, (char*)&Bd[0][0][0] + q * 1024);
      glds16((const char*)wl + gb, (char*)&Bd[0][1][0] + q * 1024);
    }
    int kk = (sg << 5) + (akg << 3);
    int c = kk >> 9, f = kk & 511;
    const float* gp = xbase + (size_t)c * 131072 + f;
    float4 v0 = *(const float4*)gp, v1 = *(const float4*)(gp + 4);
    float vv[8] = {v0.x, v0.y, v0.z, v0.w, v1.x, v1.y, v1.z, v1.w};
    short8v h8, l8;
#pragma unroll
    for (int j = 0; j < 8; ++j) { short hh, ll; split2(vv[j], hh, ll); h8[j] = hh; l8[j] = ll; }
    Ah[awidx] = h8; Al[awidx] = l8;
    __syncthreads();
  }

  for (int s = 0; s < 32; ++s) {
    int cb = s & 1, nb = cb ^ 1;
    bool more = (s + 1) < 32;
    float4 v0, v1;
    if (more) {
      int sg = (z << 5) + s + 1;
#pragma unroll
      for (int p = 0; p < 2; ++p) {
        int q = (wid << 1) + p;
        size_t gb = (size_t)sg * 16384 + (size_t)q * 1024 + (size_t)lane * 16;
        glds16((const char*)wh + gb, (char*)&Bd[nb][0][0] + q * 1024);
        glds16((const char*)wl + gb, (char*)&Bd[nb][1][0] + q * 1024);
      }
      int kk = (sg << 5) + (akg << 3);
      int c = kk >> 9, f = kk & 511;
      const float* gp = xbase + (size_t)c * 131072 + f;
      v0 = *(const float4*)gp; v1 = *(const float4*)(gp + 4);
    }
    // compute on tile s
    short8v fah[4], fal[4];
#pragma unroll
    for (int mi = 0; mi < 4; ++mi) { fah[mi] = Ah[aoff[mi]]; fal[mi] = Al[aoff[mi]]; }
#pragma unroll
    for (int ni = 0; ni < 4; ++ni) {
      short8v bh = Bd[cb][0][boff[ni]];
      short8v bl = Bd[cb][1][boff[ni]];
#pragma unroll
      for (int mi = 0; mi < 4; ++mi) { MFMA3(acc[mi][ni], fah[mi], fal[mi], bh, bl); }
    }
    __syncthreads();   // all reads of A(s)/B done before overwrite
    if (more) {
      float vv[8] = {v0.x, v0.y, v0.z, v0.w, v1.x, v1.y, v1.z, v1.w};
      short8v h8, l8;
#pragma unroll
      for (int j = 0; j < 8; ++j) { short hh, ll; split2(vv[j], hh, ll); h8[j] = hh; l8[j] = ll; }
      Ah[awidx] = h8; Al[awidx] = l8;
    }
    __syncthreads();   // drains lgkm (A writes) + vmcnt (B glds)
  }

  // ---- epilogue: write fp32 partials ----
  float* po = part + ((size_t)z * MROWS + m0) * 256;
#pragma unroll
  for (int mi = 0; mi < 4; ++mi)
#pragma unroll
    for (int ni = 0; ni < 4; ++ni) {
      int mloc = wm * 64 + mi * 16 + fq * 4;
      int n = wn * 64 + ni * 16 + fi;
#pragma unroll
      for (int r = 0; r < 4; ++r)
        po[(size_t)(mloc + r) * 256 + n] = acc[mi][ni][r];
    }
}

// ---------------- medium MFMA GEMM: BM=64, BN=128, BK=32 ----------------
// 256 threads = 4 waves (1m x 4n), wave tile 64x32.
template <int ACT, int HASBIAS>
__global__ __launch_bounds__(256, 2) void med_mfma(const float* __restrict__ A, int lda,
                                                   const unsigned short* __restrict__ wh,
                                                   const unsigned short* __restrict__ wl,
                                                   const float* __restrict__ bias,
                                                   float* __restrict__ out,
                                                   int K, int N) {
  __shared__ short8v Ahs[256], Als[256];    // [4 kg][64 row']
  __shared__ short8v Bd[2][2][512];         // [buf][h/l][4 kg][128 col]
  int nt = blockIdx.x, mt = blockIdx.y;
  int NS = K >> 5;
  int tid = threadIdx.x;
  int lane = tid & 63, wid = tid >> 6;
  int fi = lane & 15, fq = lane >> 4;
  int arow = tid >> 2, akg = tid & 3;
  int awidx = akg * 64 + (arow ^ (akg << 2));
  int m0 = mt << 6;
  const float* ga = A + (size_t)(m0 + arow) * lda;
  size_t wtbase = (size_t)nt * NS;
  int aoff[4], boff[2];
#pragma unroll
  for (int mi = 0; mi < 4; ++mi) {
    int row = mi * 16 + fi;
    aoff[mi] = fq * 64 + (row ^ (fq << 2));
  }
#pragma unroll
  for (int ni = 0; ni < 2; ++ni) boff[ni] = fq * 128 + wid * 32 + ni * 16 + fi;

  f32x4 acc[4][2];
#pragma unroll
  for (int mi = 0; mi < 4; ++mi)
#pragma unroll
    for (int ni = 0; ni < 2; ++ni) acc[mi][ni] = (f32x4)(0.f);

  // prologue
  {
#pragma unroll
    for (int p = 0; p < 2; ++p) {
      int q = (wid << 1) + p;
      size_t gb = wtbase * 8192 + (size_t)q * 1024 + (size_t)lane * 16;
      glds16((const char*)wh + gb, (char*)&Bd[0][0][0] + q * 1024);
      glds16((const char*)wl + gb, (char*)&Bd[0][1][0] + q * 1024);
    }
    const float* gp = ga + (akg << 3);
    float4 v0 = *(const float4*)gp, v1 = *(const float4*)(gp + 4);
    float vv[8] = {v0.x, v0.y, v0.z, v0.w, v1.x, v1.y, v1.z, v1.w};
    short8v h8, l8;
#pragma unroll
    for (int j = 0; j < 8; ++j) { short hh, ll; split2(vv[j], hh, ll); h8[j] = hh; l8[j] = ll; }
    Ahs[awidx] = h8; Als[awidx] = l8;
    __syncthreads();
  }

  for (int s = 0; s < NS; ++s) {
    int cb = s & 1, nb = cb ^ 1;
    bool more = (s + 1) < NS;
    float4 v0, v1;
    if (more) {
#pragma unroll
      for (int p = 0; p < 2; ++p) {
        int q = (wid << 1) + p;
        size_t gb = (wtbase + s + 1) * 8192 + (size_t)q * 1024 + (size_t)lane * 16;
        glds16((const char*)wh + gb, (char*)&Bd[nb][0][0] + q * 1024);
        glds16((const char*)wl + gb, (char*)&Bd[nb][1][0] + q * 1024);
      }
      const float* gp = ga + ((s + 1) << 5) + (akg << 3);
      v0 = *(const float4*)gp; v1 = *(const float4*)(gp + 4);
    }
    short8v fah[4], fal[4];
#pragma unroll
    for (int mi = 0; mi < 4; ++mi) { fah[mi] = Ahs[aoff[mi]]; fal[mi] = Als[aoff[mi]]; }
#pragma unroll
    for (int ni = 0; ni < 2; ++ni) {
      short8v bh = Bd[cb][0][boff[ni]];
      short8v bl = Bd[cb][1][boff[ni]];
#pragma unroll
      for (int mi = 0; mi < 4; ++mi) { MFMA3(acc[mi][ni], fah[mi], fal[mi], bh, bl); }
    }
    __syncthreads();
    if (more) {
      float vv[8] = {v0.x, v0.y, v0.z, v0.w, v1.x, v1.y, v1.z, v1.w};
      short8v h8, l8;
#pragma unroll
      for (int j = 0; j < 8; ++j) { short hh, ll; split2(vv[j], hh, ll); h8[j] = hh; l8[j] = ll; }
      Ahs[awidx] = h8; Als[awidx] = l8;
    }
    __syncthreads();
  }

#pragma unroll
  for (int mi = 0; mi < 4; ++mi)
#pragma unroll
    for (int ni = 0; ni < 2; ++ni) {
      int n = (nt << 7) + wid * 32 + ni * 16 + fi;
      float bv = HASBIAS ? bias[n] : 0.f;
#pragma unroll
      for (int r = 0; r < 4; ++r) {
        int m = m0 + mi * 16 + fq * 4 + r;
        float v = acc[mi][ni][r] + bv;
        if (ACT == 1) v = fmaxf(v, 0.f);
        out[(size_t)m * N + n] = v;
      }
    }
}

// ---------------- sum partials + bias -> relu -> LayerNorm (N=256) ----------------
__global__ __launch_bounds__(256) void ln_k(const float* __restrict__ part, int npart,
                                            const float* __restrict__ bias,
                                            const float* __restrict__ g,
                                            const float* __restrict__ bb,
                                            float* __restrict__ out) {
  int m = blockIdx.x, t = threadIdx.x;
  float s = bias[t];
  for (int z = 0; z < npart; ++z) s += part[((size_t)z * MROWS + m) * 256 + t];
  float v = fmaxf(s, 0.f);
  float sum = v, sq = v * v;
#pragma unroll
  for (int o = 1; o < 64; o <<= 1) { sum += __shfl_xor(sum, o); sq += __shfl_xor(sq, o); }
  __shared__ float s1[4], s2[4];
  int w = t >> 6;
  if ((t & 63) == 0) { s1[w] = sum; s2[w] = sq; }
  __syncthreads();
  sum = s1[0] + s1[1] + s1[2] + s1[3];
  sq  = s2[0] + s2[1] + s2[2] + s2[3];
  float mu  = sum * (1.f / 256.f);
  float var = sq * (1.f / 256.f) - mu * mu;
  out[(size_t)m * 256 + t] = (v - mu) * rsqrtf(var + 1e-5f) * g[t] + bb[t];
}

// ---------------- generic fp32 GEMM (kept for xproj N=80, dt K=16) ----------------
template <int RM, int ACT, int HASBIAS>
__global__ __launch_bounds__(256) void gemm_k(const float* __restrict__ A, int lda,
                                              const float* __restrict__ W,
                                              const float* __restrict__ bias,
                                              float* __restrict__ out,
                                              int M, int N, int K) {
  const int BM = RM * 16;
  __shared__ __align__(16) float As[16][RM * 16 + 4];
  __shared__ __align__(16) float Ws[16][68];
  int n0 = blockIdx.x << 6;
  int m0 = blockIdx.y * BM;
  int tid = threadIdx.x;
  int tx = tid & 15, ty = tid >> 4;
  float acc[RM][4];
#pragma unroll
  for (int r = 0; r < RM; ++r)
#pragma unroll
    for (int j = 0; j < 4; ++j) acc[r][j] = 0.f;

  for (int k0 = 0; k0 < K; k0 += 16) {
    __syncthreads();
    for (int i = tid; i < BM * 16; i += 256) {
      int r = i >> 4, kk = i & 15;
      As[kk][r] = A[(size_t)(m0 + r) * lda + k0 + kk];
    }
    for (int i = tid; i < 64 * 16; i += 256) {
      int r = i >> 4, kk = i & 15;
      int n = n0 + r;
      Ws[kk][r] = (n < N) ? W[(size_t)n * K + k0 + kk] : 0.f;
    }
    __syncthreads();
#pragma unroll
    for (int kk = 0; kk < 16; ++kk) {
      float4 wv = *(const float4*)&Ws[kk][tx << 2];
#pragma unroll
      for (int r = 0; r < RM; ++r) {
        float a = As[kk][ty * RM + r];
        acc[r][0] = fmaf(a, wv.x, acc[r][0]);
        acc[r][1] = fmaf(a, wv.y, acc[r][1]);
        acc[r][2] = fmaf(a, wv.z, acc[r][2]);
        acc[r][3] = fmaf(a, wv.w, acc[r][3]);
      }
    }
  }
#pragma unroll
  for (int r = 0; r < RM; ++r) {
    int m = m0 + ty * RM + r;
#pragma unroll
    for (int j = 0; j < 4; ++j) {
      int n = n0 + (tx << 2) + j;
      if (n < N) {
        float v = acc[r][j];
        if (HASBIAS) v += bias[n];
        if (ACT == 1) v = fmaxf(v, 0.f);
        if (ACT == 2) v = softplusf(v);
        out[(size_t)m * N + n] = v;
      }
    }
  }
}

// ---------------- xs = skip + pos ----------------
__global__ __launch_bounds__(256) void addpos_k(const float* __restrict__ a,
                                                const float* __restrict__ pos,
                                                float* __restrict__ o) {
  int i = blockIdx.x * 256 + threadIdx.x;
  o[i] = a[i] + pos[i & 65535];
}

// ---------------- causal depthwise conv1d(k=4) + silu ----------------
__global__ __launch_bounds__(256) void conv1d_silu_k(const float* __restrict__ xz,
                                                     const float* __restrict__ w,
                                                     const float* __restrict__ cb,
                                                     float* __restrict__ xc) {
  int i = blockIdx.x * 256 + threadIdx.x;  // over 2048*512
  int m = i >> 9, d = i & 511;
  int b = m >> 8, l = m & 255;
  float s = cb[d];
#pragma unroll
  for (int j = 0; j < 4; ++j) {
    int ll = l - 3 + j;
    if (ll >= 0) s = fmaf(w[(d << 2) + j], xz[((size_t)((b << 8) + ll) << 10) + d], s);
  }
  xc[(size_t)m * 512 + d] = siluf(s);
}

// ---------------- selective scan (+ *silu(z) gating) ----------------
__global__ __launch_bounds__(256) void scan_k(const float* __restrict__ dt,
                                              const float* __restrict__ u,
                                              const float* __restrict__ xdbl,
                                              const float* __restrict__ Alog,
                                              const float* __restrict__ Dp,
                                              const float* __restrict__ xz,
                                              float* __restrict__ yg) {
  int tid  = threadIdx.x;
  int wid  = (blockIdx.x << 2) + (tid >> 6);
  int lane = tid & 63;
  int n = lane & 31;
  int d = ((wid & 255) << 1) + (lane >> 5);
  int b = wid >> 8;
  float Av = -__expf(Alog[(d << 5) + n]);
  float Dv = Dp[d];
  size_t base = (size_t)b << 8;
  float h = 0.f;
  float dtv = dt[(base << 9) + d];
  float uv  = u [(base << 9) + d];
  float Bv  = xdbl[base * 80 + 16 + n];
  float Cv  = xdbl[base * 80 + 48 + n];
  for (int l = 0; l < 256; ++l) {
    float ndt = 0.f, nu = 0.f, nB = 0.f, nC = 0.f;
    if (l < 255) {
      size_t r = base + l + 1;
      ndt = dt[(r << 9) + d];
      nu  = u [(r << 9) + d];
      nB  = xdbl[r * 80 + 16 + n];
      nC  = xdbl[r * 80 + 48 + n];
    }
    float dA = __expf(dtv * Av);
    h = fmaf(dA, h, dtv * Bv * uv);
    float p = h * Cv;
    p += __shfl_xor(p, 1);
    p += __shfl_xor(p, 2);
    p += __shfl_xor(p, 4);
    p += __shfl_xor(p, 8);
    p += __shfl_xor(p, 16);
    if (n == 0) {
      size_t r = base + l;
      float zv = xz[(r << 10) + 512 + d];
      yg[(r << 9) + d] = (p + uv * Dv) * siluf(zv);
    }
    dtv = ndt; uv = nu; Bv = nB; Cv = nC;
  }
}

// ---------------- cat = [xs2 | skip] ----------------
__global__ __launch_bounds__(256) void concat_k(const float* __restrict__ a,
                                                const float* __restrict__ b,
                                                float* __restrict__ o) {
  int i = blockIdx.x * 256 + threadIdx.x;  // 2048*512
  int m = i >> 9, j = i & 511;
  o[i] = (j < 256) ? a[(size_t)m * 256 + j] : b[(size_t)m * 256 + j - 256];
}

// ---------------- direct 3x3 conv, OC=16, relu ----------------
template <int IC>
__global__ __launch_bounds__(256) void conv3x3_k(const float* __restrict__ in,
                                                 const float* __restrict__ w,
                                                 const float* __restrict__ bias,
                                                 float* __restrict__ out) {
  __shared__ float t[IC][6][68];
  __shared__ float wl[IC * 144];
  __shared__ float bl[16];
  int bid = blockIdx.x;
  int x0 = (bid & 3) << 6;
  int y0 = ((bid >> 2) & 63) << 2;
  int bb = bid >> 8;
  int tid = threadIdx.x;
  for (int i = tid; i < IC * 144; i += 256) {
    int oc = i & 15, t2 = i >> 4;
    wl[i] = w[(size_t)oc * (IC * 9) + t2];
  }
  if (tid < 16) bl[tid] = bias[tid];
  for (int i = tid; i < IC * 396; i += 256) {
    int ic = i / 396, rem = i - ic * 396;
    int r = rem / 66, cx = rem - r * 66;
    int y = y0 - 1 + r, xx = x0 - 1 + cx;
    float v = 0.f;
    if (y >= 0 && y < 256 && xx >= 0 && xx < 256)
      v = in[(((size_t)bb * IC + ic) << 16) + (y << 8) + xx];
    t[ic][r][cx] = v;
  }
  __syncthreads();
  int tx = tid & 15, row = (tid >> 4) & 3, ocq = tid >> 6;
  float acc[4][4];
#pragma unroll
  for (int o = 0; o < 4; ++o)
#pragma unroll
    for (int p = 0; p < 4; ++p) acc[o][p] = 0.f;

  for (int ic = 0; ic < IC; ++ic) {
#pragma unroll
    for (int dy = 0; dy < 3; ++dy) {
      const float* rp = &t[ic][row + dy][tx << 2];
      float rv[6];
#pragma unroll
      for (int q = 0; q < 6; ++q) rv[q] = rp[q];
#pragma unroll
      for (int dx = 0; dx < 3; ++dx) {
        const float* wp4 = &wl[(((ic * 3 + dy) * 3 + dx) << 4) + (ocq << 2)];
#pragma unroll
        for (int o = 0; o < 4; ++o) {
          float wv = wp4[o];
#pragma unroll
          for (int p = 0; p < 4; ++p) acc[o][p] = fmaf(rv[p + dx], wv, acc[o][p]);
        }
      }
    }
  }
  int xo = x0 + (tx << 2), yo = y0 + row;
#pragma unroll
  for (int o = 0; o < 4; ++o) {
    int oc = (ocq << 2) + o;
    float4 v4;
    v4.x = fmaxf(acc[o][0] + bl[oc], 0.f);
    v4.y = fmaxf(acc[o][1] + bl[oc], 0.f);
    v4.z = fmaxf(acc[o][2] + bl[oc], 0.f);
    v4.w = fmaxf(acc[o][3] + bl[oc], 0.f);
    *(float4*)&out[(((size_t)bb * 16 + oc) << 16) + (yo << 8) + xo] = v4;
  }
}

// ---------------- 2x2 mean pool + 1x1 conv (16->1) ----------------
__global__ __launch_bounds__(256) void pool_c4_k(const float* __restrict__ in,
                                                 const float* __restrict__ w4,
                                                 const float* __restrict__ b4,
                                                 float* __restrict__ out) {
  int i = blockIdx.x * 256 + threadIdx.x;  // 8*128*128
  int x = i & 127, y = (i >> 7) & 127, b = i >> 14;
  float s = b4[0];
#pragma unroll
  for (int ic = 0; ic < 16; ++ic) {
    const float* p = in + (((size_t)b * 16 + ic) << 16) + ((size_t)(y << 1) << 8) + (x << 1);
    float m4 = 0.25f * (p[0] + p[1] + p[256] + p[257]);
    s = fmaf(w4[ic], m4, s);
  }
  out[i] = s;
}

// ---------------- launcher ----------------
extern "C" void kernel_launch(void* const* d_in, const int* in_sizes, int n_in,
                              void* d_out, int out_size, void* d_ws, size_t ws_size,
                              hipStream_t stream) {
  const float* x        = (const float*)d_in[0];
  const float* lin0_w   = (const float*)d_in[1];
  const float* lin0_b   = (const float*)d_in[2];
  const float* ln0_g    = (const float*)d_in[3];
  const float* ln0_bb   = (const float*)d_in[4];
  const float* lin1_w   = (const float*)d_in[5];
  const float* lin1_b   = (const float*)d_in[6];
  const float* ln1_g    = (const float*)d_in[7];
  const float* ln1_bb   = (const float*)d_in[8];
  const float* pos      = (const float*)d_in[9];
  const float* m_in_w   = (const float*)d_in[10];
  const float* m_conv_w = (const float*)d_in[11];
  const float* m_conv_b = (const float*)d_in[12];
  const float* m_xproj_w= (const float*)d_in[13];
  const float* m_dt_w   = (const float*)d_in[14];
  const float* m_dt_b   = (const float*)d_in[15];
  const float* m_Alog   = (const float*)d_in[16];
  const float* m_D      = (const float*)d_in[17];
  const float* m_out_w  = (const float*)d_in[18];
  const float* blk_w    = (const float*)d_in[19];
  const float* blk_b    = (const float*)d_in[20];
  const float* dec_w    = (const float*)d_in[21];
  const float* dec_b    = (const float*)d_in[22];
  const float* c1_w     = (const float*)d_in[23];
  const float* c1_b     = (const float*)d_in[24];
  const float* c2_w     = (const float*)d_in[25];
  const float* c2_b     = (const float*)d_in[26];
  const float* c3_w     = (const float*)d_in[27];
  const float* c3_b     = (const float*)d_in[28];
  const float* c4_w     = (const float*)d_in[29];
  const float* c4_b     = (const float*)d_in[30];

  float* ws  = (float*)d_ws;
  float* out = (float*)d_out;

  unsigned short* wt0h = (unsigned short*)(ws + F_WT0);
  unsigned short* wt0l = wt0h + 4194304;
  unsigned short* wmed = (unsigned short*)(ws + F_WMED);
  unsigned short* inw_h = wmed,           * inw_l = wmed + 262144;   // m_in_w 1024x256
  unsigned short* l1_h  = wmed + 524288,  * l1_l  = wmed + 589824;   // lin1_w 256x256
  unsigned short* ow_h  = wmed + 655360,  * ow_l  = wmed + 786432;   // m_out_w 256x512
  unsigned short* bk_h  = wmed + 917504,  * bk_l  = wmed + 983040;   // blk_w 256x256
  unsigned short* dc_h  = wmed + 1048576, * dc_l  = wmed + 1179648;  // dec_w 256x512

  // 1. weight tiling (split bf16, LDS-image layout)
  tile_w_lin0<<<2048, 256, 0, stream>>>(lin0_w, wt0h, wt0l);
  tile_w_med<<<128, 256, 0, stream>>>(m_in_w, inw_h, inw_l, 256, 32768);
  tile_w_med<<<32, 256, 0, stream>>>(lin1_w, l1_h, l1_l, 256, 8192);
  tile_w_med<<<64, 256, 0, stream>>>(m_out_w, ow_h, ow_l, 512, 16384);
  tile_w_med<<<32, 256, 0, stream>>>(blk_w, bk_h, bk_l, 256, 8192);
  tile_w_med<<<64, 256, 0, stream>>>(dec_w, dc_h, dc_l, 512, 16384);
  // 2. lin0 MFMA GEMM -> partials
  lin0_mfma<<<256, 512, 0, stream>>>(x, wt0h, wt0l, ws + F_PART);
  // 3. reduce + bias + relu + LN0 -> xt0
  ln_k<<<MROWS, 256, 0, stream>>>(ws + F_PART, KSPLIT, lin0_b, ln0_g, ln0_bb, ws + F_XT0);
  // 4. lin1 -> part (raw) ; 5. bias+relu+LN1 -> skip
  med_mfma<0, 0><<<dim3(2, 32), 256, 0, stream>>>(ws + F_XT0, 256, l1_h, l1_l, nullptr,
                                                  ws + F_PART, 256, 256);
  ln_k<<<MROWS, 256, 0, stream>>>(ws + F_PART, 1, lin1_b, ln1_g, ln1_bb, ws + F_SKIP);
  // 6. xs = skip + pos
  addpos_k<<<2048, 256, 0, stream>>>(ws + F_SKIP, pos, ws + F_XS);
  // 7. xz = xs @ m_in_w^T  [2048,1024]
  med_mfma<0, 0><<<dim3(8, 32), 256, 0, stream>>>(ws + F_XS, 256, inw_h, inw_l, nullptr,
                                                  ws + F_XZ, 256, 1024);
  // 8. causal dwconv + silu -> xc
  conv1d_silu_k<<<4096, 256, 0, stream>>>(ws + F_XZ, m_conv_w, m_conv_b, ws + F_XC);
  // 9. x_dbl = xc @ m_xproj_w^T  [2048,80]
  gemm_k<2, 0, 0><<<dim3(2, 64), 256, 0, stream>>>(ws + F_XC, 512, m_xproj_w, nullptr,
                                                   ws + F_XDBL, MROWS, 80, 512);
  // 10. dt = softplus(x_dbl[:, :16] @ m_dt_w^T + m_dt_b)
  gemm_k<2, 2, 1><<<dim3(8, 64), 256, 0, stream>>>(ws + F_XDBL, 80, m_dt_w, m_dt_b,
                                                   ws + F_DT, MROWS, 512, 16);
  // 11. selective scan + silu(z) gating -> yg
  scan_k<<<512, 256, 0, stream>>>(ws + F_DT, ws + F_XC, ws + F_XDBL, m_Alog, m_D,
                                  ws + F_XZ, ws + F_YG);
  // 12. ym = yg @ m_out_w^T
  med_mfma<0, 0><<<dim3(2, 32), 256, 0, stream>>>(ws + F_YG, 512, ow_h, ow_l, nullptr,
                                                  ws + F_YM, 512, 256);
  // 13. xs2 = ym @ blk_w^T + blk_b
  med_mfma<0, 1><<<dim3(2, 32), 256, 0, stream>>>(ws + F_YM, 256, bk_h, bk_l, blk_b,
                                                  ws + F_XS2, 256, 256);
  // 14. cat = [xs2 | skip]
  concat_k<<<4096, 256, 0, stream>>>(ws + F_XS2, ws + F_SKIP, ws + F_CAT);
  // 15. dec = relu(cat @ dec_w^T + dec_b)
  med_mfma<1, 1><<<dim3(2, 32), 256, 0, stream>>>(ws + F_CAT, 512, dc_h, dc_l, dec_b,
                                                  ws + F_DEC, 512, 256);
  // 16-18. conv stack
  conv3x3_k<1><<<2048, 256, 0, stream>>>(ws + F_DEC, c1_w, c1_b, ws + F_C1);
  conv3x3_k<16><<<2048, 256, 0, stream>>>(ws + F_C1, c2_w, c2_b, ws + F_C2);
  conv3x3_k<16><<<2048, 256, 0, stream>>>(ws + F_C2, c3_w, c3_b, ws + F_C3);
  // 19. pool + 1x1 conv -> out
  pool_c4_k<<<512, 256, 0, stream>>>(ws + F_C3, c4_w, c4_b, out);
}

// Round 3
// 464.049 us; speedup vs baseline: 2.0227x; 1.1559x over previous
//
#include <hip/hip_runtime.h>
#include <hip/hip_bf16.h>
#include <cstddef>
#include <cstdint>

// ---------------- problem constants ----------------
#define MROWS 2048           // B8*L256
#define KBIG  16384          // DIN*CH32
#define KSPLIT 16            // lin0 split-K

typedef __attribute__((ext_vector_type(8))) short short8v;
typedef __attribute__((ext_vector_type(4))) float f32x4;
typedef unsigned int u32;

// ---------------- ws layout (float offsets) ----------------
static const size_t F_XT0  = 0;          // 2048*256
static const size_t F_SKIP = 524288;     // 2048*256
static const size_t F_XS   = 1048576;    // 2048*256
static const size_t F_XZ   = 1572864;    // 2048*1024
static const size_t F_XC   = 3670016;    // 2048*512
static const size_t F_XDBL = 4718592;    // 2048*80
static const size_t F_DT   = 4882432;    // 2048*512
static const size_t F_YG   = 5931008;    // 2048*512
static const size_t F_YM   = 6979584;    // 2048*256
static const size_t F_XS2  = 7503872;    // 2048*256
static const size_t F_CAT  = 8028160;    // 2048*512
static const size_t F_DEC  = 9076736;    // 2048*256 (ends 9601024)
static const size_t F_WMED = 9700000;    // 655360 floats of med W tiles (ends 10355360)
static const size_t F_WT0  = 10485760;   // lin0 split-bf16 tiles: 4194304 floats (ends 14680064)
static const size_t F_PART = 14680064;   // 16*2048*256 fp32 partials (ends 23068672)
static const size_t F_C1   = 10485760;   // conv ping-pong (aliases WT0+PART, dead by then)
static const size_t F_C2   = 0;          // aliases early chain (DEC @9076736 safe)
static const size_t F_C3   = 14680064;   // aliases PART (dead)
// total ws: 23068672 floats = 92,274,688 bytes

__device__ __forceinline__ float siluf(float v)     { return v / (1.f + __expf(-v)); }
__device__ __forceinline__ float softplusf(float v) { return v > 20.f ? v : log1pf(__expf(v)); }

__device__ __forceinline__ void split2(float v, short& h, short& l) {
  __hip_bfloat16 hb = __float2bfloat16(v);
  float hf = __bfloat162float(hb);
  __hip_bfloat16 lb = __float2bfloat16(v - hf);
  h = *(short*)&hb; l = *(short*)&lb;
}

__device__ __forceinline__ void glds16(const void* g, void* l) {
  __builtin_amdgcn_global_load_lds((const __attribute__((address_space(1))) u32*)g,
                                   (__attribute__((address_space(3))) u32*)l, 16, 0, 0);
}

#define MFMA3(acc, ah, al, bh, bl)                                            \
  acc = __builtin_amdgcn_mfma_f32_16x16x32_bf16(ah, bh, acc, 0, 0, 0);        \
  acc = __builtin_amdgcn_mfma_f32_16x16x32_bf16(al, bh, acc, 0, 0, 0);        \
  acc = __builtin_amdgcn_mfma_f32_16x16x32_bf16(ah, bl, acc, 0, 0, 0);

// ---------------- lin0 weight tiling: permute k -> k'=c*512+f, split bf16, tile to LDS image
__global__ __launch_bounds__(256) void tile_w_lin0(const float* __restrict__ w,
                                                   unsigned short* __restrict__ th,
                                                   unsigned short* __restrict__ tl) {
  int slot = blockIdx.x * 256 + threadIdx.x;       // 524288 slots
  int col = slot & 255, kg = (slot >> 8) & 3, s = slot >> 10;
  int kp = (s << 5) + (kg << 3);                   // k' base (8 contiguous, no 512-crossing)
  int c = kp >> 9, fb = kp & 511;
  const float* src = w + (size_t)col * KBIG + c;
  short8v h8, l8;
#pragma unroll
  for (int j = 0; j < 8; ++j) {
    float v = src[(size_t)(fb + j) << 5];
    short hh, ll; split2(v, hh, ll);
    h8[j] = hh; l8[j] = ll;
  }
  *(short8v*)(th + (size_t)slot * 8) = h8;
  *(short8v*)(tl + (size_t)slot * 8) = l8;
}

// ---------------- generic med weight tiling: Wt[nt][s][kg(4)][col(128)][8]
__global__ __launch_bounds__(256) void tile_w_med(const float* __restrict__ w,
                                                  unsigned short* __restrict__ th,
                                                  unsigned short* __restrict__ tl,
                                                  int K, int nslots) {
  int slot = blockIdx.x * 256 + threadIdx.x;
  if (slot >= nslots) return;
  int NS = K >> 5;
  int col = slot & 127, kg = (slot >> 7) & 3, rest = slot >> 9;
  int s = rest % NS, nt = rest / NS;
  const float* src = w + (size_t)(nt * 128 + col) * K + (s << 5) + (kg << 3);
  short8v h8, l8;
#pragma unroll
  for (int j = 0; j < 8; ++j) {
    short hh, ll; split2(src[j], hh, ll);
    h8[j] = hh; l8[j] = ll;
  }
  *(short8v*)(th + (size_t)slot * 8) = h8;
  *(short8v*)(tl + (size_t)slot * 8) = l8;
}

// ---------------- lin0 MFMA GEMM: BM=128, BN=256(full), BK=32, split-K=16 ----------------
__global__ __launch_bounds__(512, 2) void lin0_mfma(const float* __restrict__ x,
                                                    const unsigned short* __restrict__ wh,
                                                    const unsigned short* __restrict__ wl,
                                                    float* __restrict__ part) {
  __shared__ short8v Ah[512], Al[512];      // [4 kg][128 row'] of 16B
  __shared__ short8v Bd[2][2][1024];        // [buf][h/l][4 kg][256 col]
  int bid = blockIdx.x;
  int mt = bid >> 4, z = bid & 15;
  int tid = threadIdx.x;
  int lane = tid & 63, wid = tid >> 6;
  int wm = wid >> 2, wn = wid & 3;
  int fi = lane & 15, fq = lane >> 4;
  int arow = tid >> 2, akg = tid & 3;
  int awidx = akg * 128 + (arow ^ (akg << 2));
  int m0 = mt << 7;
  int am = m0 + arow;
  int ab = am >> 8, alr = am & 255;
  const float* xbase = x + ((size_t)ab << 5) * 131072 + ((size_t)alr << 9);
  int aoff[4], boff[4];
#pragma unroll
  for (int mi = 0; mi < 4; ++mi) {
    int row = wm * 64 + mi * 16 + fi;
    aoff[mi] = fq * 128 + (row ^ (fq << 2));
  }
#pragma unroll
  for (int ni = 0; ni < 4; ++ni) boff[ni] = fq * 256 + wn * 64 + ni * 16 + fi;

  f32x4 acc[4][4];
#pragma unroll
  for (int mi = 0; mi < 4; ++mi)
#pragma unroll
    for (int ni = 0; ni < 4; ++ni) acc[mi][ni] = (f32x4)(0.f);

  {
    int sg = z << 5;
#pragma unroll
    for (int p = 0; p < 2; ++p) {
      int q = (wid << 1) + p;
      size_t gb = (size_t)sg * 16384 + (size_t)q * 1024 + (size_t)lane * 16;
      glds16((const char*)wh + gb, (char*)&Bd[0][0][0] + q * 1024);
      glds16((const char*)wl + gb, (char*)&Bd[0][1][0] + q * 1024);
    }
    int kk = (sg << 5) + (akg << 3);
    int c = kk >> 9, f = kk & 511;
    const float* gp = xbase + (size_t)c * 131072 + f;
    float4 v0 = *(const float4*)gp, v1 = *(const float4*)(gp + 4);
    float vv[8] = {v0.x, v0.y, v0.z, v0.w, v1.x, v1.y, v1.z, v1.w};
    short8v h8, l8;
#pragma unroll
    for (int j = 0; j < 8; ++j) { short hh, ll; split2(vv[j], hh, ll); h8[j] = hh; l8[j] = ll; }
    Ah[awidx] = h8; Al[awidx] = l8;
    __syncthreads();
  }

  for (int s = 0; s < 32; ++s) {
    int cb = s & 1, nb = cb ^ 1;
    bool more = (s + 1) < 32;
    float4 v0, v1;
    if (more) {
      int sg = (z << 5) + s + 1;
#pragma unroll
      for (int p = 0; p < 2; ++p) {
        int q = (wid << 1) + p;
        size_t gb = (size_t)sg * 16384 + (size_t)q * 1024 + (size_t)lane * 16;
        glds16((const char*)wh + gb, (char*)&Bd[nb][0][0] + q * 1024);
        glds16((const char*)wl + gb, (char*)&Bd[nb][1][0] + q * 1024);
      }
      int kk = (sg << 5) + (akg << 3);
      int c = kk >> 9, f = kk & 511;
      const float* gp = xbase + (size_t)c * 131072 + f;
      v0 = *(const float4*)gp; v1 = *(const float4*)(gp + 4);
    }
    short8v fah[4], fal[4];
#pragma unroll
    for (int mi = 0; mi < 4; ++mi) { fah[mi] = Ah[aoff[mi]]; fal[mi] = Al[aoff[mi]]; }
#pragma unroll
    for (int ni = 0; ni < 4; ++ni) {
      short8v bh = Bd[cb][0][boff[ni]];
      short8v bl = Bd[cb][1][boff[ni]];
#pragma unroll
      for (int mi = 0; mi < 4; ++mi) { MFMA3(acc[mi][ni], fah[mi], fal[mi], bh, bl); }
    }
    __syncthreads();
    if (more) {
      float vv[8] = {v0.x, v0.y, v0.z, v0.w, v1.x, v1.y, v1.z, v1.w};
      short8v h8, l8;
#pragma unroll
      for (int j = 0; j < 8; ++j) { short hh, ll; split2(vv[j], hh, ll); h8[j] = hh; l8[j] = ll; }
      Ah[awidx] = h8; Al[awidx] = l8;
    }
    __syncthreads();
  }

  float* po = part + ((size_t)z * MROWS + m0) * 256;
#pragma unroll
  for (int mi = 0; mi < 4; ++mi)
#pragma unroll
    for (int ni = 0; ni < 4; ++ni) {
      int mloc = wm * 64 + mi * 16 + fq * 4;
      int n = wn * 64 + ni * 16 + fi;
#pragma unroll
      for (int r = 0; r < 4; ++r)
        po[(size_t)(mloc + r) * 256 + n] = acc[mi][ni][r];
    }
}

// ---------------- medium MFMA GEMM: BM=64, BN=128, BK=32 ----------------
template <int ACT, int HASBIAS>
__global__ __launch_bounds__(256, 2) void med_mfma(const float* __restrict__ A, int lda,
                                                   const unsigned short* __restrict__ wh,
                                                   const unsigned short* __restrict__ wl,
                                                   const float* __restrict__ bias,
                                                   float* __restrict__ out,
                                                   int K, int N) {
  __shared__ short8v Ahs[256], Als[256];
  __shared__ short8v Bd[2][2][512];
  int nt = blockIdx.x, mt = blockIdx.y;
  int NS = K >> 5;
  int tid = threadIdx.x;
  int lane = tid & 63, wid = tid >> 6;
  int fi = lane & 15, fq = lane >> 4;
  int arow = tid >> 2, akg = tid & 3;
  int awidx = akg * 64 + (arow ^ (akg << 2));
  int m0 = mt << 6;
  const float* ga = A + (size_t)(m0 + arow) * lda;
  size_t wtbase = (size_t)nt * NS;
  int aoff[4], boff[2];
#pragma unroll
  for (int mi = 0; mi < 4; ++mi) {
    int row = mi * 16 + fi;
    aoff[mi] = fq * 64 + (row ^ (fq << 2));
  }
#pragma unroll
  for (int ni = 0; ni < 2; ++ni) boff[ni] = fq * 128 + wid * 32 + ni * 16 + fi;

  f32x4 acc[4][2];
#pragma unroll
  for (int mi = 0; mi < 4; ++mi)
#pragma unroll
    for (int ni = 0; ni < 2; ++ni) acc[mi][ni] = (f32x4)(0.f);

  {
#pragma unroll
    for (int p = 0; p < 2; ++p) {
      int q = (wid << 1) + p;
      size_t gb = wtbase * 8192 + (size_t)q * 1024 + (size_t)lane * 16;
      glds16((const char*)wh + gb, (char*)&Bd[0][0][0] + q * 1024);
      glds16((const char*)wl + gb, (char*)&Bd[0][1][0] + q * 1024);
    }
    const float* gp = ga + (akg << 3);
    float4 v0 = *(const float4*)gp, v1 = *(const float4*)(gp + 4);
    float vv[8] = {v0.x, v0.y, v0.z, v0.w, v1.x, v1.y, v1.z, v1.w};
    short8v h8, l8;
#pragma unroll
    for (int j = 0; j < 8; ++j) { short hh, ll; split2(vv[j], hh, ll); h8[j] = hh; l8[j] = ll; }
    Ahs[awidx] = h8; Als[awidx] = l8;
    __syncthreads();
  }

  for (int s = 0; s < NS; ++s) {
    int cb = s & 1, nb = cb ^ 1;
    bool more = (s + 1) < NS;
    float4 v0, v1;
    if (more) {
#pragma unroll
      for (int p = 0; p < 2; ++p) {
        int q = (wid << 1) + p;
        size_t gb = (wtbase + s + 1) * 8192 + (size_t)q * 1024 + (size_t)lane * 16;
        glds16((const char*)wh + gb, (char*)&Bd[nb][0][0] + q * 1024);
        glds16((const char*)wl + gb, (char*)&Bd[nb][1][0] + q * 1024);
      }
      const float* gp = ga + ((s + 1) << 5) + (akg << 3);
      v0 = *(const float4*)gp; v1 = *(const float4*)(gp + 4);
    }
    short8v fah[4], fal[4];
#pragma unroll
    for (int mi = 0; mi < 4; ++mi) { fah[mi] = Ahs[aoff[mi]]; fal[mi] = Als[aoff[mi]]; }
#pragma unroll
    for (int ni = 0; ni < 2; ++ni) {
      short8v bh = Bd[cb][0][boff[ni]];
      short8v bl = Bd[cb][1][boff[ni]];
#pragma unroll
      for (int mi = 0; mi < 4; ++mi) { MFMA3(acc[mi][ni], fah[mi], fal[mi], bh, bl); }
    }
    __syncthreads();
    if (more) {
      float vv[8] = {v0.x, v0.y, v0.z, v0.w, v1.x, v1.y, v1.z, v1.w};
      short8v h8, l8;
#pragma unroll
      for (int j = 0; j < 8; ++j) { short hh, ll; split2(vv[j], hh, ll); h8[j] = hh; l8[j] = ll; }
      Ahs[awidx] = h8; Als[awidx] = l8;
    }
    __syncthreads();
  }

#pragma unroll
  for (int mi = 0; mi < 4; ++mi)
#pragma unroll
    for (int ni = 0; ni < 2; ++ni) {
      int n = (nt << 7) + wid * 32 + ni * 16 + fi;
      float bv = HASBIAS ? bias[n] : 0.f;
#pragma unroll
      for (int r = 0; r < 4; ++r) {
        int m = m0 + mi * 16 + fq * 4 + r;
        float v = acc[mi][ni][r] + bv;
        if (ACT == 1) v = fmaxf(v, 0.f);
        out[(size_t)m * N + n] = v;
      }
    }
}

// ---------------- sum partials + bias -> relu -> LayerNorm (N=256) ----------------
__global__ __launch_bounds__(256) void ln_k(const float* __restrict__ part, int npart,
                                            const float* __restrict__ bias,
                                            const float* __restrict__ g,
                                            const float* __restrict__ bb,
                                            float* __restrict__ out) {
  int m = blockIdx.x, t = threadIdx.x;
  float s = bias[t];
  for (int z = 0; z < npart; ++z) s += part[((size_t)z * MROWS + m) * 256 + t];
  float v = fmaxf(s, 0.f);
  float sum = v, sq = v * v;
#pragma unroll
  for (int o = 1; o < 64; o <<= 1) { sum += __shfl_xor(sum, o); sq += __shfl_xor(sq, o); }
  __shared__ float s1[4], s2[4];
  int w = t >> 6;
  if ((t & 63) == 0) { s1[w] = sum; s2[w] = sq; }
  __syncthreads();
  sum = s1[0] + s1[1] + s1[2] + s1[3];
  sq  = s2[0] + s2[1] + s2[2] + s2[3];
  float mu  = sum * (1.f / 256.f);
  float var = sq * (1.f / 256.f) - mu * mu;
  out[(size_t)m * 256 + t] = (v - mu) * rsqrtf(var + 1e-5f) * g[t] + bb[t];
}

// ---------------- generic fp32 GEMM (kept for xproj N=80, dt K=16) ----------------
template <int RM, int ACT, int HASBIAS>
__global__ __launch_bounds__(256) void gemm_k(const float* __restrict__ A, int lda,
                                              const float* __restrict__ W,
                                              const float* __restrict__ bias,
                                              float* __restrict__ out,
                                              int M, int N, int K) {
  const int BM = RM * 16;
  __shared__ __align__(16) float As[16][RM * 16 + 4];
  __shared__ __align__(16) float Ws[16][68];
  int n0 = blockIdx.x << 6;
  int m0 = blockIdx.y * BM;
  int tid = threadIdx.x;
  int tx = tid & 15, ty = tid >> 4;
  float acc[RM][4];
#pragma unroll
  for (int r = 0; r < RM; ++r)
#pragma unroll
    for (int j = 0; j < 4; ++j) acc[r][j] = 0.f;

  for (int k0 = 0; k0 < K; k0 += 16) {
    __syncthreads();
    for (int i = tid; i < BM * 16; i += 256) {
      int r = i >> 4, kk = i & 15;
      As[kk][r] = A[(size_t)(m0 + r) * lda + k0 + kk];
    }
    for (int i = tid; i < 64 * 16; i += 256) {
      int r = i >> 4, kk = i & 15;
      int n = n0 + r;
      Ws[kk][r] = (n < N) ? W[(size_t)n * K + k0 + kk] : 0.f;
    }
    __syncthreads();
#pragma unroll
    for (int kk = 0; kk < 16; ++kk) {
      float4 wv = *(const float4*)&Ws[kk][tx << 2];
#pragma unroll
      for (int r = 0; r < RM; ++r) {
        float a = As[kk][ty * RM + r];
        acc[r][0] = fmaf(a, wv.x, acc[r][0]);
        acc[r][1] = fmaf(a, wv.y, acc[r][1]);
        acc[r][2] = fmaf(a, wv.z, acc[r][2]);
        acc[r][3] = fmaf(a, wv.w, acc[r][3]);
      }
    }
  }
#pragma unroll
  for (int r = 0; r < RM; ++r) {
    int m = m0 + ty * RM + r;
#pragma unroll
    for (int j = 0; j < 4; ++j) {
      int n = n0 + (tx << 2) + j;
      if (n < N) {
        float v = acc[r][j];
        if (HASBIAS) v += bias[n];
        if (ACT == 1) v = fmaxf(v, 0.f);
        if (ACT == 2) v = softplusf(v);
        out[(size_t)m * N + n] = v;
      }
    }
  }
}

// ---------------- xs = skip + pos ----------------
__global__ __launch_bounds__(256) void addpos_k(const float* __restrict__ a,
                                                const float* __restrict__ pos,
                                                float* __restrict__ o) {
  int i = blockIdx.x * 256 + threadIdx.x;
  o[i] = a[i] + pos[i & 65535];
}

// ---------------- causal depthwise conv1d(k=4) + silu ----------------
__global__ __launch_bounds__(256) void conv1d_silu_k(const float* __restrict__ xz,
                                                     const float* __restrict__ w,
                                                     const float* __restrict__ cb,
                                                     float* __restrict__ xc) {
  int i = blockIdx.x * 256 + threadIdx.x;  // over 2048*512
  int m = i >> 9, d = i & 511;
  int b = m >> 8, l = m & 255;
  float s = cb[d];
#pragma unroll
  for (int j = 0; j < 4; ++j) {
    int ll = l - 3 + j;
    if (ll >= 0) s = fmaf(w[(d << 2) + j], xz[((size_t)((b << 8) + ll) << 10) + d], s);
  }
  xc[(size_t)m * 512 + d] = siluf(s);
}

// ---------------- selective scan, windowed (32-step windows) ----------------
// wave = 2 channels x 32 states; block = 4 waves; 512 blocks.
// Per window: batch-load dt/u/B/C, precompute dA/dBu in regs, pure-FMA serial
// chain writing p=h*C to LDS, then lane-remap (ch,l) reduce over n from LDS.
__global__ __launch_bounds__(256) void scan_k(const float* __restrict__ dt,
                                              const float* __restrict__ u,
                                              const float* __restrict__ xdbl,
                                              const float* __restrict__ Alog,
                                              const float* __restrict__ Dp,
                                              const float* __restrict__ xz,
                                              float* __restrict__ yg) {
  __shared__ float pbuf[4][2][32][33];   // [wave][ch][l][n] pad-33 -> conflict-free
  __shared__ float uDl[4][2][32];        // u*D per (ch, l)
  int tid  = threadIdx.x;
  int widx = tid >> 6, lane = tid & 63;
  int wid  = (blockIdx.x << 2) + widx;
  int n = lane & 31, ch = lane >> 5;
  int d = ((wid & 255) << 1) + ch;
  int b = wid >> 8;
  size_t base = (size_t)b << 8;
  float Av = -__expf(Alog[(d << 5) + n]);
  float Dv = Dp[d];
  float h = 0.f;
  // phase-C roles: lane -> (chp, lp); d is the same value (ch==chp)
  int lp = lane & 31, chp = lane >> 5;
  (void)chp;

  for (int w0 = 0; w0 < 256; w0 += 32) {
    float dA[32], dBu[32], Cv[32];
#pragma unroll
    for (int j = 0; j < 32; ++j) {
      size_t r = base + w0 + j;
      float dtv = dt[(r << 9) + d];
      float uv  = u [(r << 9) + d];
      float Bv  = xdbl[r * 80 + 16 + n];
      Cv[j]     = xdbl[r * 80 + 48 + n];
      dA[j]  = __expf(dtv * Av);
      dBu[j] = dtv * Bv * uv;
      if (n == 0) uDl[widx][ch][j] = uv * Dv;
    }
    // serial chain: pure FMA; p off critical path
#pragma unroll
    for (int j = 0; j < 32; ++j) {
      h = fmaf(dA[j], h, dBu[j]);
      pbuf[widx][ch][j][n] = h * Cv[j];
    }
    __syncthreads();
    // reduce: lane (ch, lp) sums over n
    float s = 0.f;
#pragma unroll
    for (int nn = 0; nn < 32; ++nn) s += pbuf[widx][ch][lp][nn];
    s += uDl[widx][ch][lp];
    size_t r = base + w0 + lp;
    float zv = xz[(r << 10) + 512 + d - ch + ch];  // d corresponds to (ch==chp)
    yg[(r << 9) + d] = s * siluf(zv);
    __syncthreads();   // protect pbuf/uDl before next window's writes
  }
}

// ---------------- cat = [xs2 | skip] ----------------
__global__ __launch_bounds__(256) void concat_k(const float* __restrict__ a,
                                                const float* __restrict__ b,
                                                float* __restrict__ o) {
  int i = blockIdx.x * 256 + threadIdx.x;  // 2048*512
  int m = i >> 9, j = i & 511;
  o[i] = (j < 256) ? a[(size_t)m * 256 + j] : b[(size_t)m * 256 + j - 256];
}

// ---------------- direct 3x3 conv, OC=16, relu ----------------
template <int IC>
__global__ __launch_bounds__(256) void conv3x3_k(const float* __restrict__ in,
                                                 const float* __restrict__ w,
                                                 const float* __restrict__ bias,
                                                 float* __restrict__ out) {
  __shared__ float t[IC][6][68];
  __shared__ float wl[IC * 144];
  __shared__ float bl[16];
  int bid = blockIdx.x;
  int x0 = (bid & 3) << 6;
  int y0 = ((bid >> 2) & 63) << 2;
  int bb = bid >> 8;
  int tid = threadIdx.x;
  for (int i = tid; i < IC * 144; i += 256) {
    int oc = i & 15, t2 = i >> 4;
    wl[i] = w[(size_t)oc * (IC * 9) + t2];
  }
  if (tid < 16) bl[tid] = bias[tid];
  for (int i = tid; i < IC * 396; i += 256) {
    int ic = i / 396, rem = i - ic * 396;
    int r = rem / 66, cx = rem - r * 66;
    int y = y0 - 1 + r, xx = x0 - 1 + cx;
    float v = 0.f;
    if (y >= 0 && y < 256 && xx >= 0 && xx < 256)
      v = in[(((size_t)bb * IC + ic) << 16) + (y << 8) + xx];
    t[ic][r][cx] = v;
  }
  __syncthreads();
  int tx = tid & 15, row = (tid >> 4) & 3, ocq = tid >> 6;
  float acc[4][4];
#pragma unroll
  for (int o = 0; o < 4; ++o)
#pragma unroll
    for (int p = 0; p < 4; ++p) acc[o][p] = 0.f;

  for (int ic = 0; ic < IC; ++ic) {
#pragma unroll
    for (int dy = 0; dy < 3; ++dy) {
      const float* rp = &t[ic][row + dy][tx << 2];
      float rv[6];
#pragma unroll
      for (int q = 0; q < 6; ++q) rv[q] = rp[q];
#pragma unroll
      for (int dx = 0; dx < 3; ++dx) {
        const float* wp4 = &wl[(((ic * 3 + dy) * 3 + dx) << 4) + (ocq << 2)];
#pragma unroll
        for (int o = 0; o < 4; ++o) {
          float wv = wp4[o];
#pragma unroll
          for (int p = 0; p < 4; ++p) acc[o][p] = fmaf(rv[p + dx], wv, acc[o][p]);
        }
      }
    }
  }
  int xo = x0 + (tx << 2), yo = y0 + row;
#pragma unroll
  for (int o = 0; o < 4; ++o) {
    int oc = (ocq << 2) + o;
    float4 v4;
    v4.x = fmaxf(acc[o][0] + bl[oc], 0.f);
    v4.y = fmaxf(acc[o][1] + bl[oc], 0.f);
    v4.z = fmaxf(acc[o][2] + bl[oc], 0.f);
    v4.w = fmaxf(acc[o][3] + bl[oc], 0.f);
    *(float4*)&out[(((size_t)bb * 16 + oc) << 16) + (yo << 8) + xo] = v4;
  }
}

// ---------------- 2x2 mean pool + 1x1 conv (16->1) ----------------
__global__ __launch_bounds__(256) void pool_c4_k(const float* __restrict__ in,
                                                 const float* __restrict__ w4,
                                                 const float* __restrict__ b4,
                                                 float* __restrict__ out) {
  int i = blockIdx.x * 256 + threadIdx.x;  // 8*128*128
  int x = i & 127, y = (i >> 7) & 127, b = i >> 14;
  float s = b4[0];
#pragma unroll
  for (int ic = 0; ic < 16; ++ic) {
    const float* p = in + (((size_t)b * 16 + ic) << 16) + ((size_t)(y << 1) << 8) + (x << 1);
    float m4 = 0.25f * (p[0] + p[1] + p[256] + p[257]);
    s = fmaf(w4[ic], m4, s);
  }
  out[i] = s;
}

// ---------------- launcher ----------------
extern "C" void kernel_launch(void* const* d_in, const int* in_sizes, int n_in,
                              void* d_out, int out_size, void* d_ws, size_t ws_size,
                              hipStream_t stream) {
  const float* x        = (const float*)d_in[0];
  const float* lin0_w   = (const float*)d_in[1];
  const float* lin0_b   = (const float*)d_in[2];
  const float* ln0_g    = (const float*)d_in[3];
  const float* ln0_bb   = (const float*)d_in[4];
  const float* lin1_w   = (const float*)d_in[5];
  const float* lin1_b   = (const float*)d_in[6];
  const float* ln1_g    = (const float*)d_in[7];
  const float* ln1_bb   = (const float*)d_in[8];
  const float* pos      = (const float*)d_in[9];
  const float* m_in_w   = (const float*)d_in[10];
  const float* m_conv_w = (const float*)d_in[11];
  const float* m_conv_b = (const float*)d_in[12];
  const float* m_xproj_w= (const float*)d_in[13];
  const float* m_dt_w   = (const float*)d_in[14];
  const float* m_dt_b   = (const float*)d_in[15];
  const float* m_Alog   = (const float*)d_in[16];
  const float* m_D      = (const float*)d_in[17];
  const float* m_out_w  = (const float*)d_in[18];
  const float* blk_w    = (const float*)d_in[19];
  const float* blk_b    = (const float*)d_in[20];
  const float* dec_w    = (const float*)d_in[21];
  const float* dec_b    = (const float*)d_in[22];
  const float* c1_w     = (const float*)d_in[23];
  const float* c1_b     = (const float*)d_in[24];
  const float* c2_w     = (const float*)d_in[25];
  const float* c2_b     = (const float*)d_in[26];
  const float* c3_w     = (const float*)d_in[27];
  const float* c3_b     = (const float*)d_in[28];
  const float* c4_w     = (const float*)d_in[29];
  const float* c4_b     = (const float*)d_in[30];

  float* ws  = (float*)d_ws;
  float* out = (float*)d_out;

  unsigned short* wt0h = (unsigned short*)(ws + F_WT0);
  unsigned short* wt0l = wt0h + 4194304;
  unsigned short* wmed = (unsigned short*)(ws + F_WMED);
  unsigned short* inw_h = wmed,           * inw_l = wmed + 262144;   // m_in_w 1024x256
  unsigned short* l1_h  = wmed + 524288,  * l1_l  = wmed + 589824;   // lin1_w 256x256
  unsigned short* ow_h  = wmed + 655360,  * ow_l  = wmed + 786432;   // m_out_w 256x512
  unsigned short* bk_h  = wmed + 917504,  * bk_l  = wmed + 983040;   // blk_w 256x256
  unsigned short* dc_h  = wmed + 1048576, * dc_l  = wmed + 1179648;  // dec_w 256x512

  // 1. weight tiling (split bf16, LDS-image layout)
  tile_w_lin0<<<2048, 256, 0, stream>>>(lin0_w, wt0h, wt0l);
  tile_w_med<<<128, 256, 0, stream>>>(m_in_w, inw_h, inw_l, 256, 32768);
  tile_w_med<<<32, 256, 0, stream>>>(lin1_w, l1_h, l1_l, 256, 8192);
  tile_w_med<<<64, 256, 0, stream>>>(m_out_w, ow_h, ow_l, 512, 16384);
  tile_w_med<<<32, 256, 0, stream>>>(blk_w, bk_h, bk_l, 256, 8192);
  tile_w_med<<<64, 256, 0, stream>>>(dec_w, dc_h, dc_l, 512, 16384);
  // 2. lin0 MFMA GEMM -> partials
  lin0_mfma<<<256, 512, 0, stream>>>(x, wt0h, wt0l, ws + F_PART);
  // 3. reduce + bias + relu + LN0 -> xt0
  ln_k<<<MROWS, 256, 0, stream>>>(ws + F_PART, KSPLIT, lin0_b, ln0_g, ln0_bb, ws + F_XT0);
  // 4. lin1 -> part (raw) ; 5. bias+relu+LN1 -> skip
  med_mfma<0, 0><<<dim3(2, 32), 256, 0, stream>>>(ws + F_XT0, 256, l1_h, l1_l, nullptr,
                                                  ws + F_PART, 256, 256);
  ln_k<<<MROWS, 256, 0, stream>>>(ws + F_PART, 1, lin1_b, ln1_g, ln1_bb, ws + F_SKIP);
  // 6. xs = skip + pos
  addpos_k<<<2048, 256, 0, stream>>>(ws + F_SKIP, pos, ws + F_XS);
  // 7. xz = xs @ m_in_w^T  [2048,1024]
  med_mfma<0, 0><<<dim3(8, 32), 256, 0, stream>>>(ws + F_XS, 256, inw_h, inw_l, nullptr,
                                                  ws + F_XZ, 256, 1024);
  // 8. causal dwconv + silu -> xc
  conv1d_silu_k<<<4096, 256, 0, stream>>>(ws + F_XZ, m_conv_w, m_conv_b, ws + F_XC);
  // 9. x_dbl = xc @ m_xproj_w^T  [2048,80]
  gemm_k<2, 0, 0><<<dim3(2, 64), 256, 0, stream>>>(ws + F_XC, 512, m_xproj_w, nullptr,
                                                   ws + F_XDBL, MROWS, 80, 512);
  // 10. dt = softplus(x_dbl[:, :16] @ m_dt_w^T + m_dt_b)
  gemm_k<2, 2, 1><<<dim3(8, 64), 256, 0, stream>>>(ws + F_XDBL, 80, m_dt_w, m_dt_b,
                                                   ws + F_DT, MROWS, 512, 16);
  // 11. selective scan + silu(z) gating -> yg
  scan_k<<<512, 256, 0, stream>>>(ws + F_DT, ws + F_XC, ws + F_XDBL, m_Alog, m_D,
                                  ws + F_XZ, ws + F_YG);
  // 12. ym = yg @ m_out_w^T
  med_mfma<0, 0><<<dim3(2, 32), 256, 0, stream>>>(ws + F_YG, 512, ow_h, ow_l, nullptr,
                                                  ws + F_YM, 512, 256);
  // 13. xs2 = ym @ blk_w^T + blk_b
  med_mfma<0, 1><<<dim3(2, 32), 256, 0, stream>>>(ws + F_YM, 256, bk_h, bk_l, blk_b,
                                                  ws + F_XS2, 256, 256);
  // 14. cat = [xs2 | skip]
  concat_k<<<4096, 256, 0, stream>>>(ws + F_XS2, ws + F_SKIP, ws + F_CAT);
  // 15. dec = relu(cat @ dec_w^T + dec_b)
  med_mfma<1, 1><<<dim3(2, 32), 256, 0, stream>>>(ws + F_CAT, 512, dc_h, dc_l, dec_b,
                                                  ws + F_DEC, 512, 256);
  // 16-18. conv stack
  conv3x3_k<1><<<2048, 256, 0, stream>>>(ws + F_DEC, c1_w, c1_b, ws + F_C1);
  conv3x3_k<16><<<2048, 256, 0, stream>>>(ws + F_C1, c2_w, c2_b, ws + F_C2);
  conv3x3_k<16><<<2048, 256, 0, stream>>>(ws + F_C2, c3_w, c3_b, ws + F_C3);
  // 19. pool + 1x1 conv -> out
  pool_c4_k<<<512, 256, 0, stream>>>(ws + F_C3, c4_w, c4_b, out);
}

// Round 4
// 409.325 us; speedup vs baseline: 2.2931x; 1.1337x over previous
//
#include <hip/hip_runtime.h>
#include <hip/hip_bf16.h>
#include <cstddef>
#include <cstdint>

// ---------------- problem constants ----------------
#define MROWS 2048           // B8*L256
#define KBIG  16384          // DIN*CH32
#define KSPLIT 16            // lin0 split-K

typedef __attribute__((ext_vector_type(8))) short short8v;
typedef __attribute__((ext_vector_type(4))) float f32x4;
typedef unsigned int u32;

// ---------------- ws layout (float offsets) ----------------
static const size_t F_XT0  = 0;          // 2048*256
static const size_t F_SKIP = 524288;     // 2048*256
static const size_t F_XS   = 1048576;    // 2048*256
static const size_t F_XZ   = 1572864;    // 2048*1024
static const size_t F_XC   = 3670016;    // 2048*512
static const size_t F_XDBL = 4718592;    // 2048*80
static const size_t F_DT   = 4882432;    // 2048*512
static const size_t F_YG   = 5931008;    // 2048*512
static const size_t F_YM   = 6979584;    // 2048*256
static const size_t F_XS2  = 7503872;    // 2048*256
static const size_t F_CAT  = 8028160;    // 2048*512
static const size_t F_DEC  = 9076736;    // 2048*256 (ends 9601024)
static const size_t F_WMED = 9700000;    // 655360 floats of med W tiles (ends 10355360)
static const size_t F_WT0  = 10485760;   // lin0 split-bf16 tiles: 4194304 floats (ends 14680064)
static const size_t F_PART = 14680064;   // 16*2048*256 fp32 partials (ends 23068672)
static const size_t F_C1   = 10485760;   // conv ping-pong (aliases WT0+PART, dead by then)
static const size_t F_C2   = 0;          // aliases early chain (DEC @9076736 safe)
static const size_t F_C3   = 14680064;   // aliases PART (dead)
// total ws: 23068672 floats = 92,274,688 bytes

__device__ __forceinline__ float siluf(float v)     { return v / (1.f + __expf(-v)); }
__device__ __forceinline__ float softplusf(float v) { return v > 20.f ? v : log1pf(__expf(v)); }

__device__ __forceinline__ void split2(float v, short& h, short& l) {
  __hip_bfloat16 hb = __float2bfloat16(v);
  float hf = __bfloat162float(hb);
  __hip_bfloat16 lb = __float2bfloat16(v - hf);
  h = *(short*)&hb; l = *(short*)&lb;
}

__device__ __forceinline__ void glds16(const void* g, void* l) {
  __builtin_amdgcn_global_load_lds((const __attribute__((address_space(1))) u32*)g,
                                   (__attribute__((address_space(3))) u32*)l, 16, 0, 0);
}

#define MFMA3(acc, ah, al, bh, bl)                                            \
  acc = __builtin_amdgcn_mfma_f32_16x16x32_bf16(ah, bh, acc, 0, 0, 0);        \
  acc = __builtin_amdgcn_mfma_f32_16x16x32_bf16(al, bh, acc, 0, 0, 0);        \
  acc = __builtin_amdgcn_mfma_f32_16x16x32_bf16(ah, bl, acc, 0, 0, 0);

// ---------------- lin0 weight tiling: permute k -> k'=c*512+f, split bf16, tile to LDS image
__global__ __launch_bounds__(256) void tile_w_lin0(const float* __restrict__ w,
                                                   unsigned short* __restrict__ th,
                                                   unsigned short* __restrict__ tl) {
  int slot = blockIdx.x * 256 + threadIdx.x;       // 524288 slots
  int col = slot & 255, kg = (slot >> 8) & 3, s = slot >> 10;
  int kp = (s << 5) + (kg << 3);                   // k' base (8 contiguous, no 512-crossing)
  int c = kp >> 9, fb = kp & 511;
  const float* src = w + (size_t)col * KBIG + c;
  short8v h8, l8;
#pragma unroll
  for (int j = 0; j < 8; ++j) {
    float v = src[(size_t)(fb + j) << 5];
    short hh, ll; split2(v, hh, ll);
    h8[j] = hh; l8[j] = ll;
  }
  *(short8v*)(th + (size_t)slot * 8) = h8;
  *(short8v*)(tl + (size_t)slot * 8) = l8;
}

// ---------------- generic med weight tiling: Wt[nt][s][kg(4)][col(128)][8]
__global__ __launch_bounds__(256) void tile_w_med(const float* __restrict__ w,
                                                  unsigned short* __restrict__ th,
                                                  unsigned short* __restrict__ tl,
                                                  int K, int nslots) {
  int slot = blockIdx.x * 256 + threadIdx.x;
  if (slot >= nslots) return;
  int NS = K >> 5;
  int col = slot & 127, kg = (slot >> 7) & 3, rest = slot >> 9;
  int s = rest % NS, nt = rest / NS;
  const float* src = w + (size_t)(nt * 128 + col) * K + (s << 5) + (kg << 3);
  short8v h8, l8;
#pragma unroll
  for (int j = 0; j < 8; ++j) {
    short hh, ll; split2(src[j], hh, ll);
    h8[j] = hh; l8[j] = ll;
  }
  *(short8v*)(th + (size_t)slot * 8) = h8;
  *(short8v*)(tl + (size_t)slot * 8) = l8;
}

// ---------------- lin0 MFMA GEMM: BM=128, BN=256(full), BK=32, split-K=16 ----------------
__global__ __launch_bounds__(512, 2) void lin0_mfma(const float* __restrict__ x,
                                                    const unsigned short* __restrict__ wh,
                                                    const unsigned short* __restrict__ wl,
                                                    float* __restrict__ part) {
  __shared__ short8v Ah[512], Al[512];      // [4 kg][128 row'] of 16B
  __shared__ short8v Bd[2][2][1024];        // [buf][h/l][4 kg][256 col]
  int bid = blockIdx.x;
  int mt = bid >> 4, z = bid & 15;
  int tid = threadIdx.x;
  int lane = tid & 63, wid = tid >> 6;
  int wm = wid >> 2, wn = wid & 3;
  int fi = lane & 15, fq = lane >> 4;
  int arow = tid >> 2, akg = tid & 3;
  int awidx = akg * 128 + (arow ^ (akg << 2));
  int m0 = mt << 7;
  int am = m0 + arow;
  int ab = am >> 8, alr = am & 255;
  const float* xbase = x + ((size_t)ab << 5) * 131072 + ((size_t)alr << 9);
  int aoff[4], boff[4];
#pragma unroll
  for (int mi = 0; mi < 4; ++mi) {
    int row = wm * 64 + mi * 16 + fi;
    aoff[mi] = fq * 128 + (row ^ (fq << 2));
  }
#pragma unroll
  for (int ni = 0; ni < 4; ++ni) boff[ni] = fq * 256 + wn * 64 + ni * 16 + fi;

  f32x4 acc[4][4];
#pragma unroll
  for (int mi = 0; mi < 4; ++mi)
#pragma unroll
    for (int ni = 0; ni < 4; ++ni) acc[mi][ni] = (f32x4)(0.f);

  {
    int sg = z << 5;
#pragma unroll
    for (int p = 0; p < 2; ++p) {
      int q = (wid << 1) + p;
      size_t gb = (size_t)sg * 16384 + (size_t)q * 1024 + (size_t)lane * 16;
      glds16((const char*)wh + gb, (char*)&Bd[0][0][0] + q * 1024);
      glds16((const char*)wl + gb, (char*)&Bd[0][1][0] + q * 1024);
    }
    int kk = (sg << 5) + (akg << 3);
    int c = kk >> 9, f = kk & 511;
    const float* gp = xbase + (size_t)c * 131072 + f;
    float4 v0 = *(const float4*)gp, v1 = *(const float4*)(gp + 4);
    float vv[8] = {v0.x, v0.y, v0.z, v0.w, v1.x, v1.y, v1.z, v1.w};
    short8v h8, l8;
#pragma unroll
    for (int j = 0; j < 8; ++j) { short hh, ll; split2(vv[j], hh, ll); h8[j] = hh; l8[j] = ll; }
    Ah[awidx] = h8; Al[awidx] = l8;
    __syncthreads();
  }

  for (int s = 0; s < 32; ++s) {
    int cb = s & 1, nb = cb ^ 1;
    bool more = (s + 1) < 32;
    float4 v0, v1;
    if (more) {
      int sg = (z << 5) + s + 1;
#pragma unroll
      for (int p = 0; p < 2; ++p) {
        int q = (wid << 1) + p;
        size_t gb = (size_t)sg * 16384 + (size_t)q * 1024 + (size_t)lane * 16;
        glds16((const char*)wh + gb, (char*)&Bd[nb][0][0] + q * 1024);
        glds16((const char*)wl + gb, (char*)&Bd[nb][1][0] + q * 1024);
      }
      int kk = (sg << 5) + (akg << 3);
      int c = kk >> 9, f = kk & 511;
      const float* gp = xbase + (size_t)c * 131072 + f;
      v0 = *(const float4*)gp; v1 = *(const float4*)(gp + 4);
    }
    short8v fah[4], fal[4];
#pragma unroll
    for (int mi = 0; mi < 4; ++mi) { fah[mi] = Ah[aoff[mi]]; fal[mi] = Al[aoff[mi]]; }
#pragma unroll
    for (int ni = 0; ni < 4; ++ni) {
      short8v bh = Bd[cb][0][boff[ni]];
      short8v bl = Bd[cb][1][boff[ni]];
#pragma unroll
      for (int mi = 0; mi < 4; ++mi) { MFMA3(acc[mi][ni], fah[mi], fal[mi], bh, bl); }
    }
    __syncthreads();
    if (more) {
      float vv[8] = {v0.x, v0.y, v0.z, v0.w, v1.x, v1.y, v1.z, v1.w};
      short8v h8, l8;
#pragma unroll
      for (int j = 0; j < 8; ++j) { short hh, ll; split2(vv[j], hh, ll); h8[j] = hh; l8[j] = ll; }
      Ah[awidx] = h8; Al[awidx] = l8;
    }
    __syncthreads();
  }

  float* po = part + ((size_t)z * MROWS + m0) * 256;
#pragma unroll
  for (int mi = 0; mi < 4; ++mi)
#pragma unroll
    for (int ni = 0; ni < 4; ++ni) {
      int mloc = wm * 64 + mi * 16 + fq * 4;
      int n = wn * 64 + ni * 16 + fi;
#pragma unroll
      for (int r = 0; r < 4; ++r)
        po[(size_t)(mloc + r) * 256 + n] = acc[mi][ni][r];
    }
}

// ---------------- medium MFMA GEMM: BM=64, BN=128, BK=32 ----------------
template <int ACT, int HASBIAS>
__global__ __launch_bounds__(256, 2) void med_mfma(const float* __restrict__ A, int lda,
                                                   const unsigned short* __restrict__ wh,
                                                   const unsigned short* __restrict__ wl,
                                                   const float* __restrict__ bias,
                                                   float* __restrict__ out,
                                                   int K, int N) {
  __shared__ short8v Ahs[256], Als[256];
  __shared__ short8v Bd[2][2][512];
  int nt = blockIdx.x, mt = blockIdx.y;
  int NS = K >> 5;
  int tid = threadIdx.x;
  int lane = tid & 63, wid = tid >> 6;
  int fi = lane & 15, fq = lane >> 4;
  int arow = tid >> 2, akg = tid & 3;
  int awidx = akg * 64 + (arow ^ (akg << 2));
  int m0 = mt << 6;
  const float* ga = A + (size_t)(m0 + arow) * lda;
  size_t wtbase = (size_t)nt * NS;
  int aoff[4], boff[2];
#pragma unroll
  for (int mi = 0; mi < 4; ++mi) {
    int row = mi * 16 + fi;
    aoff[mi] = fq * 64 + (row ^ (fq << 2));
  }
#pragma unroll
  for (int ni = 0; ni < 2; ++ni) boff[ni] = fq * 128 + wid * 32 + ni * 16 + fi;

  f32x4 acc[4][2];
#pragma unroll
  for (int mi = 0; mi < 4; ++mi)
#pragma unroll
    for (int ni = 0; ni < 2; ++ni) acc[mi][ni] = (f32x4)(0.f);

  {
#pragma unroll
    for (int p = 0; p < 2; ++p) {
      int q = (wid << 1) + p;
      size_t gb = wtbase * 8192 + (size_t)q * 1024 + (size_t)lane * 16;
      glds16((const char*)wh + gb, (char*)&Bd[0][0][0] + q * 1024);
      glds16((const char*)wl + gb, (char*)&Bd[0][1][0] + q * 1024);
    }
    const float* gp = ga + (akg << 3);
    float4 v0 = *(const float4*)gp, v1 = *(const float4*)(gp + 4);
    float vv[8] = {v0.x, v0.y, v0.z, v0.w, v1.x, v1.y, v1.z, v1.w};
    short8v h8, l8;
#pragma unroll
    for (int j = 0; j < 8; ++j) { short hh, ll; split2(vv[j], hh, ll); h8[j] = hh; l8[j] = ll; }
    Ahs[awidx] = h8; Als[awidx] = l8;
    __syncthreads();
  }

  for (int s = 0; s < NS; ++s) {
    int cb = s & 1, nb = cb ^ 1;
    bool more = (s + 1) < NS;
    float4 v0, v1;
    if (more) {
#pragma unroll
      for (int p = 0; p < 2; ++p) {
        int q = (wid << 1) + p;
        size_t gb = (wtbase + s + 1) * 8192 + (size_t)q * 1024 + (size_t)lane * 16;
        glds16((const char*)wh + gb, (char*)&Bd[nb][0][0] + q * 1024);
        glds16((const char*)wl + gb, (char*)&Bd[nb][1][0] + q * 1024);
      }
      const float* gp = ga + ((s + 1) << 5) + (akg << 3);
      v0 = *(const float4*)gp; v1 = *(const float4*)(gp + 4);
    }
    short8v fah[4], fal[4];
#pragma unroll
    for (int mi = 0; mi < 4; ++mi) { fah[mi] = Ahs[aoff[mi]]; fal[mi] = Als[aoff[mi]]; }
#pragma unroll
    for (int ni = 0; ni < 2; ++ni) {
      short8v bh = Bd[cb][0][boff[ni]];
      short8v bl = Bd[cb][1][boff[ni]];
#pragma unroll
      for (int mi = 0; mi < 4; ++mi) { MFMA3(acc[mi][ni], fah[mi], fal[mi], bh, bl); }
    }
    __syncthreads();
    if (more) {
      float vv[8] = {v0.x, v0.y, v0.z, v0.w, v1.x, v1.y, v1.z, v1.w};
      short8v h8, l8;
#pragma unroll
      for (int j = 0; j < 8; ++j) { short hh, ll; split2(vv[j], hh, ll); h8[j] = hh; l8[j] = ll; }
      Ahs[awidx] = h8; Als[awidx] = l8;
    }
    __syncthreads();
  }

#pragma unroll
  for (int mi = 0; mi < 4; ++mi)
#pragma unroll
    for (int ni = 0; ni < 2; ++ni) {
      int n = (nt << 7) + wid * 32 + ni * 16 + fi;
      float bv = HASBIAS ? bias[n] : 0.f;
#pragma unroll
      for (int r = 0; r < 4; ++r) {
        int m = m0 + mi * 16 + fq * 4 + r;
        float v = acc[mi][ni][r] + bv;
        if (ACT == 1) v = fmaxf(v, 0.f);
        out[(size_t)m * N + n] = v;
      }
    }
}

// ---------------- sum partials + bias -> relu -> LayerNorm (N=256) ----------------
__global__ __launch_bounds__(256) void ln_k(const float* __restrict__ part, int npart,
                                            const float* __restrict__ bias,
                                            const float* __restrict__ g,
                                            const float* __restrict__ bb,
                                            float* __restrict__ out) {
  int m = blockIdx.x, t = threadIdx.x;
  float s = bias[t];
  for (int z = 0; z < npart; ++z) s += part[((size_t)z * MROWS + m) * 256 + t];
  float v = fmaxf(s, 0.f);
  float sum = v, sq = v * v;
#pragma unroll
  for (int o = 1; o < 64; o <<= 1) { sum += __shfl_xor(sum, o); sq += __shfl_xor(sq, o); }
  __shared__ float s1[4], s2[4];
  int w = t >> 6;
  if ((t & 63) == 0) { s1[w] = sum; s2[w] = sq; }
  __syncthreads();
  sum = s1[0] + s1[1] + s1[2] + s1[3];
  sq  = s2[0] + s2[1] + s2[2] + s2[3];
  float mu  = sum * (1.f / 256.f);
  float var = sq * (1.f / 256.f) - mu * mu;
  out[(size_t)m * 256 + t] = (v - mu) * rsqrtf(var + 1e-5f) * g[t] + bb[t];
}

// ---------------- generic fp32 GEMM (kept for xproj N=80, dt K=16) ----------------
template <int RM, int ACT, int HASBIAS>
__global__ __launch_bounds__(256) void gemm_k(const float* __restrict__ A, int lda,
                                              const float* __restrict__ W,
                                              const float* __restrict__ bias,
                                              float* __restrict__ out,
                                              int M, int N, int K) {
  const int BM = RM * 16;
  __shared__ __align__(16) float As[16][RM * 16 + 4];
  __shared__ __align__(16) float Ws[16][68];
  int n0 = blockIdx.x << 6;
  int m0 = blockIdx.y * BM;
  int tid = threadIdx.x;
  int tx = tid & 15, ty = tid >> 4;
  float acc[RM][4];
#pragma unroll
  for (int r = 0; r < RM; ++r)
#pragma unroll
    for (int j = 0; j < 4; ++j) acc[r][j] = 0.f;

  for (int k0 = 0; k0 < K; k0 += 16) {
    __syncthreads();
    for (int i = tid; i < BM * 16; i += 256) {
      int r = i >> 4, kk = i & 15;
      As[kk][r] = A[(size_t)(m0 + r) * lda + k0 + kk];
    }
    for (int i = tid; i < 64 * 16; i += 256) {
      int r = i >> 4, kk = i & 15;
      int n = n0 + r;
      Ws[kk][r] = (n < N) ? W[(size_t)n * K + k0 + kk] : 0.f;
    }
    __syncthreads();
#pragma unroll
    for (int kk = 0; kk < 16; ++kk) {
      float4 wv = *(const float4*)&Ws[kk][tx << 2];
#pragma unroll
      for (int r = 0; r < RM; ++r) {
        float a = As[kk][ty * RM + r];
        acc[r][0] = fmaf(a, wv.x, acc[r][0]);
        acc[r][1] = fmaf(a, wv.y, acc[r][1]);
        acc[r][2] = fmaf(a, wv.z, acc[r][2]);
        acc[r][3] = fmaf(a, wv.w, acc[r][3]);
      }
    }
  }
#pragma unroll
  for (int r = 0; r < RM; ++r) {
    int m = m0 + ty * RM + r;
#pragma unroll
    for (int j = 0; j < 4; ++j) {
      int n = n0 + (tx << 2) + j;
      if (n < N) {
        float v = acc[r][j];
        if (HASBIAS) v += bias[n];
        if (ACT == 1) v = fmaxf(v, 0.f);
        if (ACT == 2) v = softplusf(v);
        out[(size_t)m * N + n] = v;
      }
    }
  }
}

// ---------------- xs = skip + pos ----------------
__global__ __launch_bounds__(256) void addpos_k(const float* __restrict__ a,
                                                const float* __restrict__ pos,
                                                float* __restrict__ o) {
  int i = blockIdx.x * 256 + threadIdx.x;
  o[i] = a[i] + pos[i & 65535];
}

// ---------------- causal depthwise conv1d(k=4) + silu ----------------
__global__ __launch_bounds__(256) void conv1d_silu_k(const float* __restrict__ xz,
                                                     const float* __restrict__ w,
                                                     const float* __restrict__ cb,
                                                     float* __restrict__ xc) {
  int i = blockIdx.x * 256 + threadIdx.x;  // over 2048*512
  int m = i >> 9, d = i & 511;
  int b = m >> 8, l = m & 255;
  float s = cb[d];
#pragma unroll
  for (int j = 0; j < 4; ++j) {
    int ll = l - 3 + j;
    if (ll >= 0) s = fmaf(w[(d << 2) + j], xz[((size_t)((b << 8) + ll) << 10) + d], s);
  }
  xc[(size_t)m * 512 + d] = siluf(s);
}

// ---------------- selective scan, windowed (16-step windows, spill-free) ----------------
// wave = 2 channels x 32 states over full L=256; block = 4 waves; 512 blocks.
// Per window: 64 indep global loads -> dA/dBu/Cv regs (48 floats, no spill),
// pure-FMA serial chain -> p to LDS, 64-lane reduce (2 n-halves + shfl combine).
__global__ __launch_bounds__(256, 1) void scan_k(const float* __restrict__ dt,
                                                 const float* __restrict__ u,
                                                 const float* __restrict__ xdbl,
                                                 const float* __restrict__ Alog,
                                                 const float* __restrict__ Dp,
                                                 const float* __restrict__ xz,
                                                 float* __restrict__ yg) {
  __shared__ float pbuf[4][2][16][33];   // [wave][ch][l][n] pad-33 -> <=2-way banks
  int tid  = threadIdx.x;
  int widx = tid >> 6, lane = tid & 63;
  int wid  = (blockIdx.x << 2) + widx;
  int n = lane & 31, ch = lane >> 5;
  int d0 = (wid & 255) << 1;
  int d = d0 + ch;
  int b = wid >> 8;
  size_t base = (size_t)b << 8;
  float Av = -__expf(Alog[(d << 5) + n]);
  float Dv0 = Dp[d0], Dv1 = Dp[d0 + 1];
  float h = 0.f;
  // reduce-phase roles
  int row = lane & 31;         // (rch, rlp)
  int rch = row >> 4, rlp = row & 15;
  int nh  = lane >> 5;         // n-half
  int drow = d0 + rch;
  float Dsel = rch ? Dv1 : Dv0;

  for (int w0 = 0; w0 < 256; w0 += 16) {
    float dA[16], dBu[16], Cv[16];
#pragma unroll
    for (int j = 0; j < 16; ++j) {
      size_t r = base + w0 + j;
      float dtv = dt[(r << 9) + d];
      float uv  = u [(r << 9) + d];
      float Bv  = xdbl[r * 80 + 16 + n];
      Cv[j]     = xdbl[r * 80 + 48 + n];
      dA[j]  = __expf(dtv * Av);
      dBu[j] = dtv * Bv * uv;
    }
    // serial chain: pure FMA; p write off critical path
#pragma unroll
    for (int j = 0; j < 16; ++j) {
      h = fmaf(dA[j], h, dBu[j]);
      pbuf[widx][ch][j][n] = h * Cv[j];
    }
    __syncthreads();
    // reduce: each lane sums 16 of the 32 n for row (rch, rlp)
    float s = 0.f;
#pragma unroll
    for (int nn = 0; nn < 16; ++nn) s += pbuf[widx][rch][rlp][(nh << 4) + nn];
    s += __shfl_xor(s, 32);
    if (lane < 32) {
      size_t r = base + w0 + rlp;
      float uv = u[(r << 9) + drow];
      float zv = xz[(r << 10) + 512 + drow];
      yg[(r << 9) + drow] = (s + uv * Dsel) * siluf(zv);
    }
    __syncthreads();   // pbuf reads done before next window's writes
  }
}

// ---------------- cat = [xs2 | skip] ----------------
__global__ __launch_bounds__(256) void concat_k(const float* __restrict__ a,
                                                const float* __restrict__ b,
                                                float* __restrict__ o) {
  int i = blockIdx.x * 256 + threadIdx.x;  // 2048*512
  int m = i >> 9, j = i & 511;
  o[i] = (j < 256) ? a[(size_t)m * 256 + j] : b[(size_t)m * 256 + j - 256];
}

// ---------------- direct 3x3 conv, OC=16, relu ----------------
template <int IC>
__global__ __launch_bounds__(256) void conv3x3_k(const float* __restrict__ in,
                                                 const float* __restrict__ w,
                                                 const float* __restrict__ bias,
                                                 float* __restrict__ out) {
  __shared__ float t[IC][6][68];
  __shared__ float wl[IC * 144];
  __shared__ float bl[16];
  int bid = blockIdx.x;
  int x0 = (bid & 3) << 6;
  int y0 = ((bid >> 2) & 63) << 2;
  int bb = bid >> 8;
  int tid = threadIdx.x;
  for (int i = tid; i < IC * 144; i += 256) {
    int oc = i & 15, t2 = i >> 4;
    wl[i] = w[(size_t)oc * (IC * 9) + t2];
  }
  if (tid < 16) bl[tid] = bias[tid];
  for (int i = tid; i < IC * 396; i += 256) {
    int ic = i / 396, rem = i - ic * 396;
    int r = rem / 66, cx = rem - r * 66;
    int y = y0 - 1 + r, xx = x0 - 1 + cx;
    float v = 0.f;
    if (y >= 0 && y < 256 && xx >= 0 && xx < 256)
      v = in[(((size_t)bb * IC + ic) << 16) + (y << 8) + xx];
    t[ic][r][cx] = v;
  }
  __syncthreads();
  int tx = tid & 15, row = (tid >> 4) & 3, ocq = tid >> 6;
  float acc[4][4];
#pragma unroll
  for (int o = 0; o < 4; ++o)
#pragma unroll
    for (int p = 0; p < 4; ++p) acc[o][p] = 0.f;

  for (int ic = 0; ic < IC; ++ic) {
#pragma unroll
    for (int dy = 0; dy < 3; ++dy) {
      const float* rp = &t[ic][row + dy][tx << 2];
      float rv[6];
#pragma unroll
      for (int q = 0; q < 6; ++q) rv[q] = rp[q];
#pragma unroll
      for (int dx = 0; dx < 3; ++dx) {
        const float* wp4 = &wl[(((ic * 3 + dy) * 3 + dx) << 4) + (ocq << 2)];
#pragma unroll
        for (int o = 0; o < 4; ++o) {
          float wv = wp4[o];
#pragma unroll
          for (int p = 0; p < 4; ++p) acc[o][p] = fmaf(rv[p + dx], wv, acc[o][p]);
        }
      }
    }
  }
  int xo = x0 + (tx << 2), yo = y0 + row;
#pragma unroll
  for (int o = 0; o < 4; ++o) {
    int oc = (ocq << 2) + o;
    float4 v4;
    v4.x = fmaxf(acc[o][0] + bl[oc], 0.f);
    v4.y = fmaxf(acc[o][1] + bl[oc], 0.f);
    v4.z = fmaxf(acc[o][2] + bl[oc], 0.f);
    v4.w = fmaxf(acc[o][3] + bl[oc], 0.f);
    *(float4*)&out[(((size_t)bb * 16 + oc) << 16) + (yo << 8) + xo] = v4;
  }
}

// ---------------- 2x2 mean pool + 1x1 conv (16->1) ----------------
__global__ __launch_bounds__(256) void pool_c4_k(const float* __restrict__ in,
                                                 const float* __restrict__ w4,
                                                 const float* __restrict__ b4,
                                                 float* __restrict__ out) {
  int i = blockIdx.x * 256 + threadIdx.x;  // 8*128*128
  int x = i & 127, y = (i >> 7) & 127, b = i >> 14;
  float s = b4[0];
#pragma unroll
  for (int ic = 0; ic < 16; ++ic) {
    const float* p = in + (((size_t)b * 16 + ic) << 16) + ((size_t)(y << 1) << 8) + (x << 1);
    float m4 = 0.25f * (p[0] + p[1] + p[256] + p[257]);
    s = fmaf(w4[ic], m4, s);
  }
  out[i] = s;
}

// ---------------- launcher ----------------
extern "C" void kernel_launch(void* const* d_in, const int* in_sizes, int n_in,
                              void* d_out, int out_size, void* d_ws, size_t ws_size,
                              hipStream_t stream) {
  const float* x        = (const float*)d_in[0];
  const float* lin0_w   = (const float*)d_in[1];
  const float* lin0_b   = (const float*)d_in[2];
  const float* ln0_g    = (const float*)d_in[3];
  const float* ln0_bb   = (const float*)d_in[4];
  const float* lin1_w   = (const float*)d_in[5];
  const float* lin1_b   = (const float*)d_in[6];
  const float* ln1_g    = (const float*)d_in[7];
  const float* ln1_bb   = (const float*)d_in[8];
  const float* pos      = (const float*)d_in[9];
  const float* m_in_w   = (const float*)d_in[10];
  const float* m_conv_w = (const float*)d_in[11];
  const float* m_conv_b = (const float*)d_in[12];
  const float* m_xproj_w= (const float*)d_in[13];
  const float* m_dt_w   = (const float*)d_in[14];
  const float* m_dt_b   = (const float*)d_in[15];
  const float* m_Alog   = (const float*)d_in[16];
  const float* m_D      = (const float*)d_in[17];
  const float* m_out_w  = (const float*)d_in[18];
  const float* blk_w    = (const float*)d_in[19];
  const float* blk_b    = (const float*)d_in[20];
  const float* dec_w    = (const float*)d_in[21];
  const float* dec_b    = (const float*)d_in[22];
  const float* c1_w     = (const float*)d_in[23];
  const float* c1_b     = (const float*)d_in[24];
  const float* c2_w     = (const float*)d_in[25];
  const float* c2_b     = (const float*)d_in[26];
  const float* c3_w     = (const float*)d_in[27];
  const float* c3_b     = (const float*)d_in[28];
  const float* c4_w     = (const float*)d_in[29];
  const float* c4_b     = (const float*)d_in[30];

  float* ws  = (float*)d_ws;
  float* out = (float*)d_out;

  unsigned short* wt0h = (unsigned short*)(ws + F_WT0);
  unsigned short* wt0l = wt0h + 4194304;
  unsigned short* wmed = (unsigned short*)(ws + F_WMED);
  unsigned short* inw_h = wmed,           * inw_l = wmed + 262144;   // m_in_w 1024x256
  unsigned short* l1_h  = wmed + 524288,  * l1_l  = wmed + 589824;   // lin1_w 256x256
  unsigned short* ow_h  = wmed + 655360,  * ow_l  = wmed + 786432;   // m_out_w 256x512
  unsigned short* bk_h  = wmed + 917504,  * bk_l  = wmed + 983040;   // blk_w 256x256
  unsigned short* dc_h  = wmed + 1048576, * dc_l  = wmed + 1179648;  // dec_w 256x512

  // 1. weight tiling (split bf16, LDS-image layout)
  tile_w_lin0<<<2048, 256, 0, stream>>>(lin0_w, wt0h, wt0l);
  tile_w_med<<<128, 256, 0, stream>>>(m_in_w, inw_h, inw_l, 256, 32768);
  tile_w_med<<<32, 256, 0, stream>>>(lin1_w, l1_h, l1_l, 256, 8192);
  tile_w_med<<<64, 256, 0, stream>>>(m_out_w, ow_h, ow_l, 512, 16384);
  tile_w_med<<<32, 256, 0, stream>>>(blk_w, bk_h, bk_l, 256, 8192);
  tile_w_med<<<64, 256, 0, stream>>>(dec_w, dc_h, dc_l, 512, 16384);
  // 2. lin0 MFMA GEMM -> partials
  lin0_mfma<<<256, 512, 0, stream>>>(x, wt0h, wt0l, ws + F_PART);
  // 3. reduce + bias + relu + LN0 -> xt0
  ln_k<<<MROWS, 256, 0, stream>>>(ws + F_PART, KSPLIT, lin0_b, ln0_g, ln0_bb, ws + F_XT0);
  // 4. lin1 -> part (raw) ; 5. bias+relu+LN1 -> skip
  med_mfma<0, 0><<<dim3(2, 32), 256, 0, stream>>>(ws + F_XT0, 256, l1_h, l1_l, nullptr,
                                                  ws + F_PART, 256, 256);
  ln_k<<<MROWS, 256, 0, stream>>>(ws + F_PART, 1, lin1_b, ln1_g, ln1_bb, ws + F_SKIP);
  // 6. xs = skip + pos
  addpos_k<<<2048, 256, 0, stream>>>(ws + F_SKIP, pos, ws + F_XS);
  // 7. xz = xs @ m_in_w^T  [2048,1024]
  med_mfma<0, 0><<<dim3(8, 32), 256, 0, stream>>>(ws + F_XS, 256, inw_h, inw_l, nullptr,
                                                  ws + F_XZ, 256, 1024);
  // 8. causal dwconv + silu -> xc
  conv1d_silu_k<<<4096, 256, 0, stream>>>(ws + F_XZ, m_conv_w, m_conv_b, ws + F_XC);
  // 9. x_dbl = xc @ m_xproj_w^T  [2048,80]
  gemm_k<2, 0, 0><<<dim3(2, 64), 256, 0, stream>>>(ws + F_XC, 512, m_xproj_w, nullptr,
                                                   ws + F_XDBL, MROWS, 80, 512);
  // 10. dt = softplus(x_dbl[:, :16] @ m_dt_w^T + m_dt_b)
  gemm_k<2, 2, 1><<<dim3(8, 64), 256, 0, stream>>>(ws + F_XDBL, 80, m_dt_w, m_dt_b,
                                                   ws + F_DT, MROWS, 512, 16);
  // 11. selective scan + silu(z) gating -> yg
  scan_k<<<512, 256, 0, stream>>>(ws + F_DT, ws + F_XC, ws + F_XDBL, m_Alog, m_D,
                                  ws + F_XZ, ws + F_YG);
  // 12. ym = yg @ m_out_w^T
  med_mfma<0, 0><<<dim3(2, 32), 256, 0, stream>>>(ws + F_YG, 512, ow_h, ow_l, nullptr,
                                                  ws + F_YM, 512, 256);
  // 13. xs2 = ym @ blk_w^T + blk_b
  med_mfma<0, 1><<<dim3(2, 32), 256, 0, stream>>>(ws + F_YM, 256, bk_h, bk_l, blk_b,
                                                  ws + F_XS2, 256, 256);
  // 14. cat = [xs2 | skip]
  concat_k<<<4096, 256, 0, stream>>>(ws + F_XS2, ws + F_SKIP, ws + F_CAT);
  // 15. dec = relu(cat @ dec_w^T + dec_b)
  med_mfma<1, 1><<<dim3(2, 32), 256, 0, stream>>>(ws + F_CAT, 512, dc_h, dc_l, dec_b,
                                                  ws + F_DEC, 512, 256);
  // 16-18. conv stack
  conv3x3_k<1><<<2048, 256, 0, stream>>>(ws + F_DEC, c1_w, c1_b, ws + F_C1);
  conv3x3_k<16><<<2048, 256, 0, stream>>>(ws + F_C1, c2_w, c2_b, ws + F_C2);
  conv3x3_k<16><<<2048, 256, 0, stream>>>(ws + F_C2, c3_w, c3_b, ws + F_C3);
  // 19. pool + 1x1 conv -> out
  pool_c4_k<<<512, 256, 0, stream>>>(ws + F_C3, c4_w, c4_b, out);
}

// Round 5
// 398.896 us; speedup vs baseline: 2.3531x; 1.0261x over previous
//
#include <hip/hip_runtime.h>
#include <hip/hip_bf16.h>
#include <cstddef>
#include <cstdint>

// ---------------- problem constants ----------------
#define MROWS 2048           // B8*L256
#define KBIG  16384          // DIN*CH32
#define KSPLIT 16            // lin0 split-K

typedef __attribute__((ext_vector_type(8))) short short8v;
typedef __attribute__((ext_vector_type(4))) short short4v;
typedef __attribute__((ext_vector_type(4))) float f32x4;
typedef unsigned int u32;

// ---------------- ws layout (float offsets) ----------------
static const size_t F_XT0  = 0;          // 2048*256
static const size_t F_SKIP = 524288;     // 2048*256
static const size_t F_XS   = 1048576;    // 2048*256
static const size_t F_XZ   = 1572864;    // 2048*1024
static const size_t F_XC   = 3670016;    // 2048*512
static const size_t F_XDBL = 4718592;    // 2048*80
static const size_t F_DT   = 4882432;    // 2048*512
static const size_t F_YG   = 5931008;    // 2048*512
static const size_t F_YM   = 6979584;    // 2048*256
static const size_t F_XS2  = 7503872;    // 2048*256
static const size_t F_CAT  = 8028160;    // 2048*512
static const size_t F_DEC  = 9076736;    // 2048*256 (ends 9601024)
static const size_t F_WMED = 9700000;    // 655360 floats of med W tiles (ends 10355360)
static const size_t F_WT0  = 10485760;   // lin0 split-bf16 tiles: 4194304 floats (ends 14680064)
static const size_t F_PART = 14680064;   // 16*2048*256 fp32 partials (ends 23068672)
static const size_t F_C1   = 10485760;   // conv ping-pong (aliases WT0+PART, dead by then)
static const size_t F_C2   = 0;          // aliases early chain (DEC @9076736 safe)
static const size_t F_C3   = 14680064;   // aliases PART (dead)
// total ws: 23068672 floats = 92,274,688 bytes

__device__ __forceinline__ float siluf(float v)     { return v / (1.f + __expf(-v)); }
__device__ __forceinline__ float softplusf(float v) { return v > 20.f ? v : log1pf(__expf(v)); }

__device__ __forceinline__ void split2(float v, short& h, short& l) {
  __hip_bfloat16 hb = __float2bfloat16(v);
  float hf = __bfloat162float(hb);
  __hip_bfloat16 lb = __float2bfloat16(v - hf);
  h = *(short*)&hb; l = *(short*)&lb;
}

__device__ __forceinline__ void glds16(const void* g, void* l) {
  __builtin_amdgcn_global_load_lds((const __attribute__((address_space(1))) u32*)g,
                                   (__attribute__((address_space(3))) u32*)l, 16, 0, 0);
}

#define MFMA3(acc, ah, al, bh, bl)                                            \
  acc = __builtin_amdgcn_mfma_f32_16x16x32_bf16(ah, bh, acc, 0, 0, 0);        \
  acc = __builtin_amdgcn_mfma_f32_16x16x32_bf16(al, bh, acc, 0, 0, 0);        \
  acc = __builtin_amdgcn_mfma_f32_16x16x32_bf16(ah, bl, acc, 0, 0, 0);

// ---------------- lin0 weight tiling (coalesced LDS-transpose) ----------------
// Target layout unchanged: Wt[slot = (k'>>3)*256 + col][j = k'&7], k' = c*512+f, k = f*32+c.
// Block = 32 cols x 256 k (contiguous). Coalesced float4 reads; pad-per-32 LDS;
// coalesced 16B short8v writes.
__global__ __launch_bounds__(256) void tile_w_lin0(const float* __restrict__ w,
                                                   unsigned short* __restrict__ th,
                                                   unsigned short* __restrict__ tl) {
  __shared__ float ls[32 * 264];   // [col][k_l + k_l/32] pad-per-32
  int ct = blockIdx.x >> 6;        // 0..7  (col tile)
  int kt = blockIdx.x & 63;        // 0..63 (k tile)
  int c0 = ct << 5;
  int k0 = kt << 8;
  int tid = threadIdx.x;
  for (int u = tid; u < 2048; u += 256) {      // 2048 float4 units
    int col_l = u >> 6, f4i = u & 63;
    int k_l = f4i << 2;
    float4 v = *(const float4*)(w + (size_t)(c0 + col_l) * KBIG + k0 + k_l);
    float vv[4] = {v.x, v.y, v.z, v.w};
#pragma unroll
    for (int j = 0; j < 4; ++j) {
      int idx = k_l + j;
      ls[col_l * 264 + idx + (idx >> 5)] = vv[j];
    }
  }
  __syncthreads();
  for (int oi = tid; oi < 1024; oi += 256) {   // 32 cols x 32 c groups
    int col_l = oi & 31, c = oi >> 5;
    short8v h8, l8;
#pragma unroll
    for (int j = 0; j < 8; ++j) {
      float v = ls[col_l * 264 + j * 33 + c];  // (j*32+c) + ((j*32+c)>>5)
      short hh, ll; split2(v, hh, ll);
      h8[j] = hh; l8[j] = ll;
    }
    size_t slot = ((size_t)(c * 64 + kt)) * 256 + c0 + col_l;
    *(short8v*)(th + slot * 8) = h8;
    *(short8v*)(tl + slot * 8) = l8;
  }
}

// ---------------- generic med weight tiling: Wt[nt][s][kg(4)][col(128)][8]
__global__ __launch_bounds__(256) void tile_w_med(const float* __restrict__ w,
                                                  unsigned short* __restrict__ th,
                                                  unsigned short* __restrict__ tl,
                                                  int K, int nslots) {
  int slot = blockIdx.x * 256 + threadIdx.x;
  if (slot >= nslots) return;
  int NS = K >> 5;
  int col = slot & 127, kg = (slot >> 7) & 3, rest = slot >> 9;
  int s = rest % NS, nt = rest / NS;
  const float* src = w + (size_t)(nt * 128 + col) * K + (s << 5) + (kg << 3);
  short8v h8, l8;
#pragma unroll
  for (int j = 0; j < 8; ++j) {
    short hh, ll; split2(src[j], hh, ll);
    h8[j] = hh; l8[j] = ll;
  }
  *(short8v*)(th + (size_t)slot * 8) = h8;
  *(short8v*)(tl + (size_t)slot * 8) = l8;
}

// ---------------- lin0 MFMA GEMM: BM=64, BN=256(full), BK=32, split-K=16 ----------------
// grid = 32 m-tiles x 16 z = 512 blocks -> 2 blocks/CU (LDS 72KB). 8 waves (2m x 4n),
// wave tile 32x64. A fused fp32->split-bf16 staging; B via global_load_lds.
__global__ __launch_bounds__(512, 4) void lin0_mfma(const float* __restrict__ x,
                                                    const unsigned short* __restrict__ wh,
                                                    const unsigned short* __restrict__ wl,
                                                    float* __restrict__ part) {
  __shared__ short Ah[2048], Al[2048];      // [4 kg][64 row'] * 8 shorts = 4KB each
  __shared__ short8v Bd[2][2][1024];        // [buf][h/l][4 kg][256 col] = 64KB
  int bid = blockIdx.x;
  int mt = bid >> 4, z = bid & 15;          // same-z blocks land on the same XCD (id%8=z%8)
  int tid = threadIdx.x;
  int lane = tid & 63, wid = tid >> 6;
  int wm = wid >> 2, wn = wid & 3;
  int fi = lane & 15, fq = lane >> 4;
  // A staging mapping: 64 rows x 32 k; thread -> (row, kg, half)
  int arow = tid >> 3;
  int sub  = tid & 7;
  int akg  = sub >> 1, ahalf = sub & 1;
  int aslot = (akg * 64 + (arow ^ (akg << 2))) * 8 + (ahalf << 2);   // short index
  int m0 = mt << 6;
  int am = m0 + arow;
  int ab = am >> 8, alr = am & 255;
  const float* xbase = x + (size_t)ab * 4194304 + (size_t)alr * 512;
  int aoff[2], boff[4];
#pragma unroll
  for (int mi = 0; mi < 2; ++mi) {
    int row = wm * 32 + mi * 16 + fi;
    aoff[mi] = (fq * 64 + (row ^ (fq << 2))) * 8;                    // short index
  }
#pragma unroll
  for (int ni = 0; ni < 4; ++ni) boff[ni] = fq * 256 + wn * 64 + ni * 16 + fi;

  f32x4 acc[2][4];
#pragma unroll
  for (int mi = 0; mi < 2; ++mi)
#pragma unroll
    for (int ni = 0; ni < 4; ++ni) acc[mi][ni] = (f32x4)(0.f);

  // ---- prologue: stage step 0 ----
  {
    int sg = z << 5;
#pragma unroll
    for (int p = 0; p < 2; ++p) {
      int q = (wid << 1) + p;
      size_t gb = (size_t)sg * 16384 + (size_t)q * 1024 + (size_t)lane * 16;
      glds16((const char*)wh + gb, (char*)&Bd[0][0][0] + q * 1024);
      glds16((const char*)wl + gb, (char*)&Bd[0][1][0] + q * 1024);
    }
    int c = sg >> 4, f = ((sg & 15) << 5) + (akg << 3) + (ahalf << 2);
    float4 v = *(const float4*)(xbase + (size_t)c * 131072 + f);
    float vv[4] = {v.x, v.y, v.z, v.w};
    short4v h4, l4;
#pragma unroll
    for (int j = 0; j < 4; ++j) { short hh, ll; split2(vv[j], hh, ll); h4[j] = hh; l4[j] = ll; }
    *(short4v*)&Ah[aslot] = h4; *(short4v*)&Al[aslot] = l4;
    __syncthreads();
  }

  for (int s = 0; s < 32; ++s) {
    int cb = s & 1, nb = cb ^ 1;
    bool more = (s + 1) < 32;
    float4 v;
    if (more) {
      int sg = (z << 5) + s + 1;
#pragma unroll
      for (int p = 0; p < 2; ++p) {
        int q = (wid << 1) + p;
        size_t gb = (size_t)sg * 16384 + (size_t)q * 1024 + (size_t)lane * 16;
        glds16((const char*)wh + gb, (char*)&Bd[nb][0][0] + q * 1024);
        glds16((const char*)wl + gb, (char*)&Bd[nb][1][0] + q * 1024);
      }
      int c = sg >> 4, f = ((sg & 15) << 5) + (akg << 3) + (ahalf << 2);
      v = *(const float4*)(xbase + (size_t)c * 131072 + f);
    }
    // compute on tile s
    short8v fah[2], fal[2];
#pragma unroll
    for (int mi = 0; mi < 2; ++mi) {
      fah[mi] = *(const short8v*)&Ah[aoff[mi]];
      fal[mi] = *(const short8v*)&Al[aoff[mi]];
    }
#pragma unroll
    for (int ni = 0; ni < 4; ++ni) {
      short8v bh = Bd[cb][0][boff[ni]];
      short8v bl = Bd[cb][1][boff[ni]];
#pragma unroll
      for (int mi = 0; mi < 2; ++mi) { MFMA3(acc[mi][ni], fah[mi], fal[mi], bh, bl); }
    }
    __syncthreads();   // all reads of A(s)/B(s) done before overwrite
    if (more) {
      float vv[4] = {v.x, v.y, v.z, v.w};
      short4v h4, l4;
#pragma unroll
      for (int j = 0; j < 4; ++j) { short hh, ll; split2(vv[j], hh, ll); h4[j] = hh; l4[j] = ll; }
      *(short4v*)&Ah[aslot] = h4; *(short4v*)&Al[aslot] = l4;
    }
    __syncthreads();   // drains lgkm (A writes) + vmcnt (B glds)
  }

  // ---- epilogue: write fp32 partials ----
  float* po = part + ((size_t)z * MROWS + m0) * 256;
#pragma unroll
  for (int mi = 0; mi < 2; ++mi)
#pragma unroll
    for (int ni = 0; ni < 4; ++ni) {
      int mloc = wm * 32 + mi * 16 + fq * 4;
      int n = wn * 64 + ni * 16 + fi;
#pragma unroll
      for (int r = 0; r < 4; ++r)
        po[(size_t)(mloc + r) * 256 + n] = acc[mi][ni][r];
    }
}

// ---------------- medium MFMA GEMM: BM=64, BN=128, BK=32 ----------------
template <int ACT, int HASBIAS>
__global__ __launch_bounds__(256, 2) void med_mfma(const float* __restrict__ A, int lda,
                                                   const unsigned short* __restrict__ wh,
                                                   const unsigned short* __restrict__ wl,
                                                   const float* __restrict__ bias,
                                                   float* __restrict__ out,
                                                   int K, int N) {
  __shared__ short8v Ahs[256], Als[256];
  __shared__ short8v Bd[2][2][512];
  int nt = blockIdx.x, mt = blockIdx.y;
  int NS = K >> 5;
  int tid = threadIdx.x;
  int lane = tid & 63, wid = tid >> 6;
  int fi = lane & 15, fq = lane >> 4;
  int arow = tid >> 2, akg = tid & 3;
  int awidx = akg * 64 + (arow ^ (akg << 2));
  int m0 = mt << 6;
  const float* ga = A + (size_t)(m0 + arow) * lda;
  size_t wtbase = (size_t)nt * NS;
  int aoff[4], boff[2];
#pragma unroll
  for (int mi = 0; mi < 4; ++mi) {
    int row = mi * 16 + fi;
    aoff[mi] = fq * 64 + (row ^ (fq << 2));
  }
#pragma unroll
  for (int ni = 0; ni < 2; ++ni) boff[ni] = fq * 128 + wid * 32 + ni * 16 + fi;

  f32x4 acc[4][2];
#pragma unroll
  for (int mi = 0; mi < 4; ++mi)
#pragma unroll
    for (int ni = 0; ni < 2; ++ni) acc[mi][ni] = (f32x4)(0.f);

  {
#pragma unroll
    for (int p = 0; p < 2; ++p) {
      int q = (wid << 1) + p;
      size_t gb = wtbase * 8192 + (size_t)q * 1024 + (size_t)lane * 16;
      glds16((const char*)wh + gb, (char*)&Bd[0][0][0] + q * 1024);
      glds16((const char*)wl + gb, (char*)&Bd[0][1][0] + q * 1024);
    }
    const float* gp = ga + (akg << 3);
    float4 v0 = *(const float4*)gp, v1 = *(const float4*)(gp + 4);
    float vv[8] = {v0.x, v0.y, v0.z, v0.w, v1.x, v1.y, v1.z, v1.w};
    short8v h8, l8;
#pragma unroll
    for (int j = 0; j < 8; ++j) { short hh, ll; split2(vv[j], hh, ll); h8[j] = hh; l8[j] = ll; }
    Ahs[awidx] = h8; Als[awidx] = l8;
    __syncthreads();
  }

  for (int s = 0; s < NS; ++s) {
    int cb = s & 1, nb = cb ^ 1;
    bool more = (s + 1) < NS;
    float4 v0, v1;
    if (more) {
#pragma unroll
      for (int p = 0; p < 2; ++p) {
        int q = (wid << 1) + p;
        size_t gb = (wtbase + s + 1) * 8192 + (size_t)q * 1024 + (size_t)lane * 16;
        glds16((const char*)wh + gb, (char*)&Bd[nb][0][0] + q * 1024);
        glds16((const char*)wl + gb, (char*)&Bd[nb][1][0] + q * 1024);
      }
      const float* gp = ga + ((s + 1) << 5) + (akg << 3);
      v0 = *(const float4*)gp; v1 = *(const float4*)(gp + 4);
    }
    short8v fah[4], fal[4];
#pragma unroll
    for (int mi = 0; mi < 4; ++mi) { fah[mi] = Ahs[aoff[mi]]; fal[mi] = Als[aoff[mi]]; }
#pragma unroll
    for (int ni = 0; ni < 2; ++ni) {
      short8v bh = Bd[cb][0][boff[ni]];
      short8v bl = Bd[cb][1][boff[ni]];
#pragma unroll
      for (int mi = 0; mi < 4; ++mi) { MFMA3(acc[mi][ni], fah[mi], fal[mi], bh, bl); }
    }
    __syncthreads();
    if (more) {
      float vv[8] = {v0.x, v0.y, v0.z, v0.w, v1.x, v1.y, v1.z, v1.w};
      short8v h8, l8;
#pragma unroll
      for (int j = 0; j < 8; ++j) { short hh, ll; split2(vv[j], hh, ll); h8[j] = hh; l8[j] = ll; }
      Ahs[awidx] = h8; Als[awidx] = l8;
    }
    __syncthreads();
  }

#pragma unroll
  for (int mi = 0; mi < 4; ++mi)
#pragma unroll
    for (int ni = 0; ni < 2; ++ni) {
      int n = (nt << 7) + wid * 32 + ni * 16 + fi;
      float bv = HASBIAS ? bias[n] : 0.f;
#pragma unroll
      for (int r = 0; r < 4; ++r) {
        int m = m0 + mi * 16 + fq * 4 + r;
        float v = acc[mi][ni][r] + bv;
        if (ACT == 1) v = fmaxf(v, 0.f);
        out[(size_t)m * N + n] = v;
      }
    }
}

// ---------------- sum partials + bias -> relu -> LayerNorm (N=256) ----------------
__global__ __launch_bounds__(256) void ln_k(const float* __restrict__ part, int npart,
                                            const float* __restrict__ bias,
                                            const float* __restrict__ g,
                                            const float* __restrict__ bb,
                                            float* __restrict__ out) {
  int m = blockIdx.x, t = threadIdx.x;
  float s = bias[t];
  for (int z = 0; z < npart; ++z) s += part[((size_t)z * MROWS + m) * 256 + t];
  float v = fmaxf(s, 0.f);
  float sum = v, sq = v * v;
#pragma unroll
  for (int o = 1; o < 64; o <<= 1) { sum += __shfl_xor(sum, o); sq += __shfl_xor(sq, o); }
  __shared__ float s1[4], s2[4];
  int w = t >> 6;
  if ((t & 63) == 0) { s1[w] = sum; s2[w] = sq; }
  __syncthreads();
  sum = s1[0] + s1[1] + s1[2] + s1[3];
  sq  = s2[0] + s2[1] + s2[2] + s2[3];
  float mu  = sum * (1.f / 256.f);
  float var = sq * (1.f / 256.f) - mu * mu;
  out[(size_t)m * 256 + t] = (v - mu) * rsqrtf(var + 1e-5f) * g[t] + bb[t];
}

// ---------------- generic fp32 GEMM (kept for xproj N=80, dt K=16) ----------------
template <int RM, int ACT, int HASBIAS>
__global__ __launch_bounds__(256) void gemm_k(const float* __restrict__ A, int lda,
                                              const float* __restrict__ W,
                                              const float* __restrict__ bias,
                                              float* __restrict__ out,
                                              int M, int N, int K) {
  const int BM = RM * 16;
  __shared__ __align__(16) float As[16][RM * 16 + 4];
  __shared__ __align__(16) float Ws[16][68];
  int n0 = blockIdx.x << 6;
  int m0 = blockIdx.y * BM;
  int tid = threadIdx.x;
  int tx = tid & 15, ty = tid >> 4;
  float acc[RM][4];
#pragma unroll
  for (int r = 0; r < RM; ++r)
#pragma unroll
    for (int j = 0; j < 4; ++j) acc[r][j] = 0.f;

  for (int k0 = 0; k0 < K; k0 += 16) {
    __syncthreads();
    for (int i = tid; i < BM * 16; i += 256) {
      int r = i >> 4, kk = i & 15;
      As[kk][r] = A[(size_t)(m0 + r) * lda + k0 + kk];
    }
    for (int i = tid; i < 64 * 16; i += 256) {
      int r = i >> 4, kk = i & 15;
      int n = n0 + r;
      Ws[kk][r] = (n < N) ? W[(size_t)n * K + k0 + kk] : 0.f;
    }
    __syncthreads();
#pragma unroll
    for (int kk = 0; kk < 16; ++kk) {
      float4 wv = *(const float4*)&Ws[kk][tx << 2];
#pragma unroll
      for (int r = 0; r < RM; ++r) {
        float a = As[kk][ty * RM + r];
        acc[r][0] = fmaf(a, wv.x, acc[r][0]);
        acc[r][1] = fmaf(a, wv.y, acc[r][1]);
        acc[r][2] = fmaf(a, wv.z, acc[r][2]);
        acc[r][3] = fmaf(a, wv.w, acc[r][3]);
      }
    }
  }
#pragma unroll
  for (int r = 0; r < RM; ++r) {
    int m = m0 + ty * RM + r;
#pragma unroll
    for (int j = 0; j < 4; ++j) {
      int n = n0 + (tx << 2) + j;
      if (n < N) {
        float v = acc[r][j];
        if (HASBIAS) v += bias[n];
        if (ACT == 1) v = fmaxf(v, 0.f);
        if (ACT == 2) v = softplusf(v);
        out[(size_t)m * N + n] = v;
      }
    }
  }
}

// ---------------- xs = skip + pos ----------------
__global__ __launch_bounds__(256) void addpos_k(const float* __restrict__ a,
                                                const float* __restrict__ pos,
                                                float* __restrict__ o) {
  int i = blockIdx.x * 256 + threadIdx.x;
  o[i] = a[i] + pos[i & 65535];
}

// ---------------- causal depthwise conv1d(k=4) + silu ----------------
__global__ __launch_bounds__(256) void conv1d_silu_k(const float* __restrict__ xz,
                                                     const float* __restrict__ w,
                                                     const float* __restrict__ cb,
                                                     float* __restrict__ xc) {
  int i = blockIdx.x * 256 + threadIdx.x;  // over 2048*512
  int m = i >> 9, d = i & 511;
  int b = m >> 8, l = m & 255;
  float s = cb[d];
#pragma unroll
  for (int j = 0; j < 4; ++j) {
    int ll = l - 3 + j;
    if (ll >= 0) s = fmaf(w[(d << 2) + j], xz[((size_t)((b << 8) + ll) << 10) + d], s);
  }
  xc[(size_t)m * 512 + d] = siluf(s);
}

// ---------------- selective scan, windowed (16-step windows, spill-free) ----------------
__global__ __launch_bounds__(256, 1) void scan_k(const float* __restrict__ dt,
                                                 const float* __restrict__ u,
                                                 const float* __restrict__ xdbl,
                                                 const float* __restrict__ Alog,
                                                 const float* __restrict__ Dp,
                                                 const float* __restrict__ xz,
                                                 float* __restrict__ yg) {
  __shared__ float pbuf[4][2][16][33];   // [wave][ch][l][n] pad-33 -> <=2-way banks
  int tid  = threadIdx.x;
  int widx = tid >> 6, lane = tid & 63;
  int wid  = (blockIdx.x << 2) + widx;
  int n = lane & 31, ch = lane >> 5;
  int d0 = (wid & 255) << 1;
  int d = d0 + ch;
  int b = wid >> 8;
  size_t base = (size_t)b << 8;
  float Av = -__expf(Alog[(d << 5) + n]);
  float Dv0 = Dp[d0], Dv1 = Dp[d0 + 1];
  float h = 0.f;
  int row = lane & 31;
  int rch = row >> 4, rlp = row & 15;
  int nh  = lane >> 5;
  int drow = d0 + rch;
  float Dsel = rch ? Dv1 : Dv0;

  for (int w0 = 0; w0 < 256; w0 += 16) {
    float dA[16], dBu[16], Cv[16];
#pragma unroll
    for (int j = 0; j < 16; ++j) {
      size_t r = base + w0 + j;
      float dtv = dt[(r << 9) + d];
      float uv  = u [(r << 9) + d];
      float Bv  = xdbl[r * 80 + 16 + n];
      Cv[j]     = xdbl[r * 80 + 48 + n];
      dA[j]  = __expf(dtv * Av);
      dBu[j] = dtv * Bv * uv;
    }
#pragma unroll
    for (int j = 0; j < 16; ++j) {
      h = fmaf(dA[j], h, dBu[j]);
      pbuf[widx][ch][j][n] = h * Cv[j];
    }
    __syncthreads();
    float s = 0.f;
#pragma unroll
    for (int nn = 0; nn < 16; ++nn) s += pbuf[widx][rch][rlp][(nh << 4) + nn];
    s += __shfl_xor(s, 32);
    if (lane < 32) {
      size_t r = base + w0 + rlp;
      float uv = u[(r << 9) + drow];
      float zv = xz[(r << 10) + 512 + drow];
      yg[(r << 9) + drow] = (s + uv * Dsel) * siluf(zv);
    }
    __syncthreads();
  }
}

// ---------------- cat = [xs2 | skip] ----------------
__global__ __launch_bounds__(256) void concat_k(const float* __restrict__ a,
                                                const float* __restrict__ b,
                                                float* __restrict__ o) {
  int i = blockIdx.x * 256 + threadIdx.x;  // 2048*512
  int m = i >> 9, j = i & 511;
  o[i] = (j < 256) ? a[(size_t)m * 256 + j] : b[(size_t)m * 256 + j - 256];
}

// ---------------- direct 3x3 conv, OC=16, relu ----------------
template <int IC>
__global__ __launch_bounds__(256) void conv3x3_k(const float* __restrict__ in,
                                                 const float* __restrict__ w,
                                                 const float* __restrict__ bias,
                                                 float* __restrict__ out) {
  __shared__ float t[IC][6][68];
  __shared__ float wl[IC * 144];
  __shared__ float bl[16];
  int bid = blockIdx.x;
  int x0 = (bid & 3) << 6;
  int y0 = ((bid >> 2) & 63) << 2;
  int bb = bid >> 8;
  int tid = threadIdx.x;
  for (int i = tid; i < IC * 144; i += 256) {
    int oc = i & 15, t2 = i >> 4;
    wl[i] = w[(size_t)oc * (IC * 9) + t2];
  }
  if (tid < 16) bl[tid] = bias[tid];
  for (int i = tid; i < IC * 396; i += 256) {
    int ic = i / 396, rem = i - ic * 396;
    int r = rem / 66, cx = rem - r * 66;
    int y = y0 - 1 + r, xx = x0 - 1 + cx;
    float v = 0.f;
    if (y >= 0 && y < 256 && xx >= 0 && xx < 256)
      v = in[(((size_t)bb * IC + ic) << 16) + (y << 8) + xx];
    t[ic][r][cx] = v;
  }
  __syncthreads();
  int tx = tid & 15, row = (tid >> 4) & 3, ocq = tid >> 6;
  float acc[4][4];
#pragma unroll
  for (int o = 0; o < 4; ++o)
#pragma unroll
    for (int p = 0; p < 4; ++p) acc[o][p] = 0.f;

  for (int ic = 0; ic < IC; ++ic) {
#pragma unroll
    for (int dy = 0; dy < 3; ++dy) {
      const float* rp = &t[ic][row + dy][tx << 2];
      float rv[6];
#pragma unroll
      for (int q = 0; q < 6; ++q) rv[q] = rp[q];
#pragma unroll
      for (int dx = 0; dx < 3; ++dx) {
        const float* wp4 = &wl[(((ic * 3 + dy) * 3 + dx) << 4) + (ocq << 2)];
#pragma unroll
        for (int o = 0; o < 4; ++o) {
          float wv = wp4[o];
#pragma unroll
          for (int p = 0; p < 4; ++p) acc[o][p] = fmaf(rv[p + dx], wv, acc[o][p]);
        }
      }
    }
  }
  int xo = x0 + (tx << 2), yo = y0 + row;
#pragma unroll
  for (int o = 0; o < 4; ++o) {
    int oc = (ocq << 2) + o;
    float4 v4;
    v4.x = fmaxf(acc[o][0] + bl[oc], 0.f);
    v4.y = fmaxf(acc[o][1] + bl[oc], 0.f);
    v4.z = fmaxf(acc[o][2] + bl[oc], 0.f);
    v4.w = fmaxf(acc[o][3] + bl[oc], 0.f);
    *(float4*)&out[(((size_t)bb * 16 + oc) << 16) + (yo << 8) + xo] = v4;
  }
}

// ---------------- 2x2 mean pool + 1x1 conv (16->1) ----------------
__global__ __launch_bounds__(256) void pool_c4_k(const float* __restrict__ in,
                                                 const float* __restrict__ w4,
                                                 const float* __restrict__ b4,
                                                 float* __restrict__ out) {
  int i = blockIdx.x * 256 + threadIdx.x;  // 8*128*128
  int x = i & 127, y = (i >> 7) & 127, b = i >> 14;
  float s = b4[0];
#pragma unroll
  for (int ic = 0; ic < 16; ++ic) {
    const float* p = in + (((size_t)b * 16 + ic) << 16) + ((size_t)(y << 1) << 8) + (x << 1);
    float m4 = 0.25f * (p[0] + p[1] + p[256] + p[257]);
    s = fmaf(w4[ic], m4, s);
  }
  out[i] = s;
}

// ---------------- launcher ----------------
extern "C" void kernel_launch(void* const* d_in, const int* in_sizes, int n_in,
                              void* d_out, int out_size, void* d_ws, size_t ws_size,
                              hipStream_t stream) {
  const float* x        = (const float*)d_in[0];
  const float* lin0_w   = (const float*)d_in[1];
  const float* lin0_b   = (const float*)d_in[2];
  const float* ln0_g    = (const float*)d_in[3];
  const float* ln0_bb   = (const float*)d_in[4];
  const float* lin1_w   = (const float*)d_in[5];
  const float* lin1_b   = (const float*)d_in[6];
  const float* ln1_g    = (const float*)d_in[7];
  const float* ln1_bb   = (const float*)d_in[8];
  const float* pos      = (const float*)d_in[9];
  const float* m_in_w   = (const float*)d_in[10];
  const float* m_conv_w = (const float*)d_in[11];
  const float* m_conv_b = (const float*)d_in[12];
  const float* m_xproj_w= (const float*)d_in[13];
  const float* m_dt_w   = (const float*)d_in[14];
  const float* m_dt_b   = (const float*)d_in[15];
  const float* m_Alog   = (const float*)d_in[16];
  const float* m_D      = (const float*)d_in[17];
  const float* m_out_w  = (const float*)d_in[18];
  const float* blk_w    = (const float*)d_in[19];
  const float* blk_b    = (const float*)d_in[20];
  const float* dec_w    = (const float*)d_in[21];
  const float* dec_b    = (const float*)d_in[22];
  const float* c1_w     = (const float*)d_in[23];
  const float* c1_b     = (const float*)d_in[24];
  const float* c2_w     = (const float*)d_in[25];
  const float* c2_b     = (const float*)d_in[26];
  const float* c3_w     = (const float*)d_in[27];
  const float* c3_b     = (const float*)d_in[28];
  const float* c4_w     = (const float*)d_in[29];
  const float* c4_b     = (const float*)d_in[30];

  float* ws  = (float*)d_ws;
  float* out = (float*)d_out;

  unsigned short* wt0h = (unsigned short*)(ws + F_WT0);
  unsigned short* wt0l = wt0h + 4194304;
  unsigned short* wmed = (unsigned short*)(ws + F_WMED);
  unsigned short* inw_h = wmed,           * inw_l = wmed + 262144;   // m_in_w 1024x256
  unsigned short* l1_h  = wmed + 524288,  * l1_l  = wmed + 589824;   // lin1_w 256x256
  unsigned short* ow_h  = wmed + 655360,  * ow_l  = wmed + 786432;   // m_out_w 256x512
  unsigned short* bk_h  = wmed + 917504,  * bk_l  = wmed + 983040;   // blk_w 256x256
  unsigned short* dc_h  = wmed + 1048576, * dc_l  = wmed + 1179648;  // dec_w 256x512

  // 1. weight tiling (split bf16, LDS-image layout)
  tile_w_lin0<<<512, 256, 0, stream>>>(lin0_w, wt0h, wt0l);
  tile_w_med<<<128, 256, 0, stream>>>(m_in_w, inw_h, inw_l, 256, 32768);
  tile_w_med<<<32, 256, 0, stream>>>(lin1_w, l1_h, l1_l, 256, 8192);
  tile_w_med<<<64, 256, 0, stream>>>(m_out_w, ow_h, ow_l, 512, 16384);
  tile_w_med<<<32, 256, 0, stream>>>(blk_w, bk_h, bk_l, 256, 8192);
  tile_w_med<<<64, 256, 0, stream>>>(dec_w, dc_h, dc_l, 512, 16384);
  // 2. lin0 MFMA GEMM -> partials (BM=64, 512 blocks = 2/CU)
  lin0_mfma<<<512, 512, 0, stream>>>(x, wt0h, wt0l, ws + F_PART);
  // 3. reduce + bias + relu + LN0 -> xt0
  ln_k<<<MROWS, 256, 0, stream>>>(ws + F_PART, KSPLIT, lin0_b, ln0_g, ln0_bb, ws + F_XT0);
  // 4. lin1 -> part (raw) ; 5. bias+relu+LN1 -> skip
  med_mfma<0, 0><<<dim3(2, 32), 256, 0, stream>>>(ws + F_XT0, 256, l1_h, l1_l, nullptr,
                                                  ws + F_PART, 256, 256);
  ln_k<<<MROWS, 256, 0, stream>>>(ws + F_PART, 1, lin1_b, ln1_g, ln1_bb, ws + F_SKIP);
  // 6. xs = skip + pos
  addpos_k<<<2048, 256, 0, stream>>>(ws + F_SKIP, pos, ws + F_XS);
  // 7. xz = xs @ m_in_w^T  [2048,1024]
  med_mfma<0, 0><<<dim3(8, 32), 256, 0, stream>>>(ws + F_XS, 256, inw_h, inw_l, nullptr,
                                                  ws + F_XZ, 256, 1024);
  // 8. causal dwconv + silu -> xc
  conv1d_silu_k<<<4096, 256, 0, stream>>>(ws + F_XZ, m_conv_w, m_conv_b, ws + F_XC);
  // 9. x_dbl = xc @ m_xproj_w^T  [2048,80]
  gemm_k<2, 0, 0><<<dim3(2, 64), 256, 0, stream>>>(ws + F_XC, 512, m_xproj_w, nullptr,
                                                   ws + F_XDBL, MROWS, 80, 512);
  // 10. dt = softplus(x_dbl[:, :16] @ m_dt_w^T + m_dt_b)
  gemm_k<2, 2, 1><<<dim3(8, 64), 256, 0, stream>>>(ws + F_XDBL, 80, m_dt_w, m_dt_b,
                                                   ws + F_DT, MROWS, 512, 16);
  // 11. selective scan + silu(z) gating -> yg
  scan_k<<<512, 256, 0, stream>>>(ws + F_DT, ws + F_XC, ws + F_XDBL, m_Alog, m_D,
                                  ws + F_XZ, ws + F_YG);
  // 12. ym = yg @ m_out_w^T
  med_mfma<0, 0><<<dim3(2, 32), 256, 0, stream>>>(ws + F_YG, 512, ow_h, ow_l, nullptr,
                                                  ws + F_YM, 512, 256);
  // 13. xs2 = ym @ blk_w^T + blk_b
  med_mfma<0, 1><<<dim3(2, 32), 256, 0, stream>>>(ws + F_YM, 256, bk_h, bk_l, blk_b,
                                                  ws + F_XS2, 256, 256);
  // 14. cat = [xs2 | skip]
  concat_k<<<4096, 256, 0, stream>>>(ws + F_XS2, ws + F_SKIP, ws + F_CAT);
  // 15. dec = relu(cat @ dec_w^T + dec_b)
  med_mfma<1, 1><<<dim3(2, 32), 256, 0, stream>>>(ws + F_CAT, 512, dc_h, dc_l, dec_b,
                                                  ws + F_DEC, 512, 256);
  // 16-18. conv stack
  conv3x3_k<1><<<2048, 256, 0, stream>>>(ws + F_DEC, c1_w, c1_b, ws + F_C1);
  conv3x3_k<16><<<2048, 256, 0, stream>>>(ws + F_C1, c2_w, c2_b, ws + F_C2);
  conv3x3_k<16><<<2048, 256, 0, stream>>>(ws + F_C2, c3_w, c3_b, ws + F_C3);
  // 19. pool + 1x1 conv -> out
  pool_c4_k<<<512, 256, 0, stream>>>(ws + F_C3, c4_w, c4_b, out);
}

// Round 6
// 368.643 us; speedup vs baseline: 2.5462x; 1.0821x over previous
//
#include <hip/hip_runtime.h>
#include <hip/hip_bf16.h>
#include <cstddef>
#include <cstdint>

// ---------------- problem constants ----------------
#define MROWS 2048           // B8*L256
#define KBIG  16384          // DIN*CH32
#define KSPLIT 16            // lin0 split-K

typedef __attribute__((ext_vector_type(8))) short short8v;
typedef __attribute__((ext_vector_type(4))) short short4v;
typedef __attribute__((ext_vector_type(4))) float f32x4;
typedef unsigned int u32;

// ---------------- ws layout (float offsets) ----------------
static const size_t F_XT0  = 0;          // 2048*256
static const size_t F_SKIP = 524288;     // 2048*256
static const size_t F_XS   = 1048576;    // 2048*256
static const size_t F_XZ   = 1572864;    // 2048*1024
static const size_t F_XC   = 3670016;    // 2048*512
static const size_t F_XDBL = 4718592;    // 2048*80
static const size_t F_DT   = 4882432;    // 2048*512
static const size_t F_YG   = 5931008;    // 2048*512
static const size_t F_YM   = 6979584;    // 2048*256
static const size_t F_XS2  = 7503872;    // 2048*256
static const size_t F_CAT  = 8028160;    // 2048*512
static const size_t F_DEC  = 9076736;    // 2048*256 (ends 9601024)
static const size_t F_WMED = 9700000;    // med W tiles + conv W tiles (ends ~10360480)
static const size_t F_WT0  = 10485760;   // lin0 split-bf16 tiles: 4194304 floats (ends 14680064)
static const size_t F_PART = 14680064;   // 16*2048*256 fp32 partials (ends 23068672)
static const size_t F_C1   = 10485760;   // conv ping-pong (aliases WT0+PART, dead by then)
static const size_t F_C2   = 0;          // aliases early chain (DEC @9076736 safe)
static const size_t F_C3   = 14680064;   // aliases PART (dead)
// total ws: 23068672 floats = 92,274,688 bytes

__device__ __forceinline__ float siluf(float v)     { return v / (1.f + __expf(-v)); }
__device__ __forceinline__ float softplusf(float v) { return v > 20.f ? v : log1pf(__expf(v)); }

__device__ __forceinline__ void split2(float v, short& h, short& l) {
  __hip_bfloat16 hb = __float2bfloat16(v);
  float hf = __bfloat162float(hb);
  __hip_bfloat16 lb = __float2bfloat16(v - hf);
  h = *(short*)&hb; l = *(short*)&lb;
}

__device__ __forceinline__ void glds16(const void* g, void* l) {
  __builtin_amdgcn_global_load_lds((const __attribute__((address_space(1))) u32*)g,
                                   (__attribute__((address_space(3))) u32*)l, 16, 0, 0);
}

#define MFMA3(acc, ah, al, bh, bl)                                            \
  acc = __builtin_amdgcn_mfma_f32_16x16x32_bf16(ah, bh, acc, 0, 0, 0);        \
  acc = __builtin_amdgcn_mfma_f32_16x16x32_bf16(al, bh, acc, 0, 0, 0);        \
  acc = __builtin_amdgcn_mfma_f32_16x16x32_bf16(ah, bl, acc, 0, 0, 0);

// ---------------- lin0 weight tiling (coalesced LDS-transpose) ----------------
__global__ __launch_bounds__(256) void tile_w_lin0(const float* __restrict__ w,
                                                   unsigned short* __restrict__ th,
                                                   unsigned short* __restrict__ tl) {
  __shared__ float ls[32 * 264];   // [col][k_l + k_l/32] pad-per-32
  int ct = blockIdx.x >> 6;        // 0..7  (col tile)
  int kt = blockIdx.x & 63;        // 0..63 (k tile)
  int c0 = ct << 5;
  int k0 = kt << 8;
  int tid = threadIdx.x;
  for (int u = tid; u < 2048; u += 256) {      // 2048 float4 units
    int col_l = u >> 6, f4i = u & 63;
    int k_l = f4i << 2;
    float4 v = *(const float4*)(w + (size_t)(c0 + col_l) * KBIG + k0 + k_l);
    float vv[4] = {v.x, v.y, v.z, v.w};
#pragma unroll
    for (int j = 0; j < 4; ++j) {
      int idx = k_l + j;
      ls[col_l * 264 + idx + (idx >> 5)] = vv[j];
    }
  }
  __syncthreads();
  for (int oi = tid; oi < 1024; oi += 256) {   // 32 cols x 32 c groups
    int col_l = oi & 31, c = oi >> 5;
    short8v h8, l8;
#pragma unroll
    for (int j = 0; j < 8; ++j) {
      float v = ls[col_l * 264 + j * 33 + c];
      short hh, ll; split2(v, hh, ll);
      h8[j] = hh; l8[j] = ll;
    }
    size_t slot = ((size_t)(c * 64 + kt)) * 256 + c0 + col_l;
    *(short8v*)(th + slot * 8) = h8;
    *(short8v*)(tl + slot * 8) = l8;
  }
}

// ---------------- generic med weight tiling: Wt[nt][s][kg(4)][col(128)][8]
__global__ __launch_bounds__(256) void tile_w_med(const float* __restrict__ w,
                                                  unsigned short* __restrict__ th,
                                                  unsigned short* __restrict__ tl,
                                                  int K, int nslots) {
  int slot = blockIdx.x * 256 + threadIdx.x;
  if (slot >= nslots) return;
  int NS = K >> 5;
  int col = slot & 127, kg = (slot >> 7) & 3, rest = slot >> 9;
  int s = rest % NS, nt = rest / NS;
  const float* src = w + (size_t)(nt * 128 + col) * K + (s << 5) + (kg << 3);
  short8v h8, l8;
#pragma unroll
  for (int j = 0; j < 8; ++j) {
    short hh, ll; split2(src[j], hh, ll);
    h8[j] = hh; l8[j] = ll;
  }
  *(short8v*)(th + (size_t)slot * 8) = h8;
  *(short8v*)(tl + (size_t)slot * 8) = l8;
}

// ---------------- conv weight tiling: k = dydx*16+ic (K=144 pad 160) ----------------
// slot layout (matches med image): [(s*4+fq)*16 + oc][8]
__global__ __launch_bounds__(256) void tile_w_conv(const float* __restrict__ w,
                                                   unsigned short* __restrict__ th,
                                                   unsigned short* __restrict__ tl) {
  int slot = blockIdx.x * 256 + threadIdx.x;   // 320 slots
  if (slot >= 320) return;
  int oc = slot & 15;
  int sfq = slot >> 4;           // s*4+fq, 0..19
  int s = sfq >> 2, fq = sfq & 3;
  short8v h8, l8;
#pragma unroll
  for (int j = 0; j < 8; ++j) {
    int k = s * 32 + fq * 8 + j;
    float v = 0.f;
    if (k < 144) {
      int dydx = k >> 4, ic = k & 15;
      v = w[oc * 144 + ic * 9 + dydx];
    }
    short hh, ll; split2(v, hh, ll);
    h8[j] = hh; l8[j] = ll;
  }
  *(short8v*)(th + (size_t)slot * 8) = h8;
  *(short8v*)(tl + (size_t)slot * 8) = l8;
}

// ---------------- lin0 MFMA GEMM: BM=64, BN=256(full), BK=32, split-K=16 ----------------
__global__ __launch_bounds__(512, 4) void lin0_mfma(const float* __restrict__ x,
                                                    const unsigned short* __restrict__ wh,
                                                    const unsigned short* __restrict__ wl,
                                                    float* __restrict__ part) {
  __shared__ short Ah[2048], Al[2048];
  __shared__ short8v Bd[2][2][1024];
  int bid = blockIdx.x;
  int mt = bid >> 4, z = bid & 15;
  int tid = threadIdx.x;
  int lane = tid & 63, wid = tid >> 6;
  int wm = wid >> 2, wn = wid & 3;
  int fi = lane & 15, fq = lane >> 4;
  int arow = tid >> 3;
  int sub  = tid & 7;
  int akg  = sub >> 1, ahalf = sub & 1;
  int aslot = (akg * 64 + (arow ^ (akg << 2))) * 8 + (ahalf << 2);
  int m0 = mt << 6;
  int am = m0 + arow;
  int ab = am >> 8, alr = am & 255;
  const float* xbase = x + (size_t)ab * 4194304 + (size_t)alr * 512;
  int aoff[2], boff[4];
#pragma unroll
  for (int mi = 0; mi < 2; ++mi) {
    int row = wm * 32 + mi * 16 + fi;
    aoff[mi] = (fq * 64 + (row ^ (fq << 2))) * 8;
  }
#pragma unroll
  for (int ni = 0; ni < 4; ++ni) boff[ni] = fq * 256 + wn * 64 + ni * 16 + fi;

  f32x4 acc[2][4];
#pragma unroll
  for (int mi = 0; mi < 2; ++mi)
#pragma unroll
    for (int ni = 0; ni < 4; ++ni) acc[mi][ni] = (f32x4)(0.f);

  {
    int sg = z << 5;
#pragma unroll
    for (int p = 0; p < 2; ++p) {
      int q = (wid << 1) + p;
      size_t gb = (size_t)sg * 16384 + (size_t)q * 1024 + (size_t)lane * 16;
      glds16((const char*)wh + gb, (char*)&Bd[0][0][0] + q * 1024);
      glds16((const char*)wl + gb, (char*)&Bd[0][1][0] + q * 1024);
    }
    int c = sg >> 4, f = ((sg & 15) << 5) + (akg << 3) + (ahalf << 2);
    float4 v = *(const float4*)(xbase + (size_t)c * 131072 + f);
    float vv[4] = {v.x, v.y, v.z, v.w};
    short4v h4, l4;
#pragma unroll
    for (int j = 0; j < 4; ++j) { short hh, ll; split2(vv[j], hh, ll); h4[j] = hh; l4[j] = ll; }
    *(short4v*)&Ah[aslot] = h4; *(short4v*)&Al[aslot] = l4;
    __syncthreads();
  }

  for (int s = 0; s < 32; ++s) {
    int cb = s & 1, nb = cb ^ 1;
    bool more = (s + 1) < 32;
    float4 v;
    if (more) {
      int sg = (z << 5) + s + 1;
#pragma unroll
      for (int p = 0; p < 2; ++p) {
        int q = (wid << 1) + p;
        size_t gb = (size_t)sg * 16384 + (size_t)q * 1024 + (size_t)lane * 16;
        glds16((const char*)wh + gb, (char*)&Bd[nb][0][0] + q * 1024);
        glds16((const char*)wl + gb, (char*)&Bd[nb][1][0] + q * 1024);
      }
      int c = sg >> 4, f = ((sg & 15) << 5) + (akg << 3) + (ahalf << 2);
      v = *(const float4*)(xbase + (size_t)c * 131072 + f);
    }
    short8v fah[2], fal[2];
#pragma unroll
    for (int mi = 0; mi < 2; ++mi) {
      fah[mi] = *(const short8v*)&Ah[aoff[mi]];
      fal[mi] = *(const short8v*)&Al[aoff[mi]];
    }
#pragma unroll
    for (int ni = 0; ni < 4; ++ni) {
      short8v bh = Bd[cb][0][boff[ni]];
      short8v bl = Bd[cb][1][boff[ni]];
#pragma unroll
      for (int mi = 0; mi < 2; ++mi) { MFMA3(acc[mi][ni], fah[mi], fal[mi], bh, bl); }
    }
    __syncthreads();
    if (more) {
      float vv[4] = {v.x, v.y, v.z, v.w};
      short4v h4, l4;
#pragma unroll
      for (int j = 0; j < 4; ++j) { short hh, ll; split2(vv[j], hh, ll); h4[j] = hh; l4[j] = ll; }
      *(short4v*)&Ah[aslot] = h4; *(short4v*)&Al[aslot] = l4;
    }
    __syncthreads();
  }

  float* po = part + ((size_t)z * MROWS + m0) * 256;
#pragma unroll
  for (int mi = 0; mi < 2; ++mi)
#pragma unroll
    for (int ni = 0; ni < 4; ++ni) {
      int mloc = wm * 32 + mi * 16 + fq * 4;
      int n = wn * 64 + ni * 16 + fi;
#pragma unroll
      for (int r = 0; r < 4; ++r)
        po[(size_t)(mloc + r) * 256 + n] = acc[mi][ni][r];
    }
}

// ---------------- medium MFMA GEMM: BM=64, BN=128, BK=32 ----------------
template <int ACT, int HASBIAS>
__global__ __launch_bounds__(256, 2) void med_mfma(const float* __restrict__ A, int lda,
                                                   const unsigned short* __restrict__ wh,
                                                   const unsigned short* __restrict__ wl,
                                                   const float* __restrict__ bias,
                                                   float* __restrict__ out,
                                                   int K, int N) {
  __shared__ short8v Ahs[256], Als[256];
  __shared__ short8v Bd[2][2][512];
  int nt = blockIdx.x, mt = blockIdx.y;
  int NS = K >> 5;
  int tid = threadIdx.x;
  int lane = tid & 63, wid = tid >> 6;
  int fi = lane & 15, fq = lane >> 4;
  int arow = tid >> 2, akg = tid & 3;
  int awidx = akg * 64 + (arow ^ (akg << 2));
  int m0 = mt << 6;
  const float* ga = A + (size_t)(m0 + arow) * lda;
  size_t wtbase = (size_t)nt * NS;
  int aoff[4], boff[2];
#pragma unroll
  for (int mi = 0; mi < 4; ++mi) {
    int row = mi * 16 + fi;
    aoff[mi] = fq * 64 + (row ^ (fq << 2));
  }
#pragma unroll
  for (int ni = 0; ni < 2; ++ni) boff[ni] = fq * 128 + wid * 32 + ni * 16 + fi;

  f32x4 acc[4][2];
#pragma unroll
  for (int mi = 0; mi < 4; ++mi)
#pragma unroll
    for (int ni = 0; ni < 2; ++ni) acc[mi][ni] = (f32x4)(0.f);

  {
#pragma unroll
    for (int p = 0; p < 2; ++p) {
      int q = (wid << 1) + p;
      size_t gb = wtbase * 8192 + (size_t)q * 1024 + (size_t)lane * 16;
      glds16((const char*)wh + gb, (char*)&Bd[0][0][0] + q * 1024);
      glds16((const char*)wl + gb, (char*)&Bd[0][1][0] + q * 1024);
    }
    const float* gp = ga + (akg << 3);
    float4 v0 = *(const float4*)gp, v1 = *(const float4*)(gp + 4);
    float vv[8] = {v0.x, v0.y, v0.z, v0.w, v1.x, v1.y, v1.z, v1.w};
    short8v h8, l8;
#pragma unroll
    for (int j = 0; j < 8; ++j) { short hh, ll; split2(vv[j], hh, ll); h8[j] = hh; l8[j] = ll; }
    Ahs[awidx] = h8; Als[awidx] = l8;
    __syncthreads();
  }

  for (int s = 0; s < NS; ++s) {
    int cb = s & 1, nb = cb ^ 1;
    bool more = (s + 1) < NS;
    float4 v0, v1;
    if (more) {
#pragma unroll
      for (int p = 0; p < 2; ++p) {
        int q = (wid << 1) + p;
        size_t gb = (wtbase + s + 1) * 8192 + (size_t)q * 1024 + (size_t)lane * 16;
        glds16((const char*)wh + gb, (char*)&Bd[nb][0][0] + q * 1024);
        glds16((const char*)wl + gb, (char*)&Bd[nb][1][0] + q * 1024);
      }
      const float* gp = ga + ((s + 1) << 5) + (akg << 3);
      v0 = *(const float4*)gp; v1 = *(const float4*)(gp + 4);
    }
    short8v fah[4], fal[4];
#pragma unroll
    for (int mi = 0; mi < 4; ++mi) { fah[mi] = Ahs[aoff[mi]]; fal[mi] = Als[aoff[mi]]; }
#pragma unroll
    for (int ni = 0; ni < 2; ++ni) {
      short8v bh = Bd[cb][0][boff[ni]];
      short8v bl = Bd[cb][1][boff[ni]];
#pragma unroll
      for (int mi = 0; mi < 4; ++mi) { MFMA3(acc[mi][ni], fah[mi], fal[mi], bh, bl); }
    }
    __syncthreads();
    if (more) {
      float vv[8] = {v0.x, v0.y, v0.z, v0.w, v1.x, v1.y, v1.z, v1.w};
      short8v h8, l8;
#pragma unroll
      for (int j = 0; j < 8; ++j) { short hh, ll; split2(vv[j], hh, ll); h8[j] = hh; l8[j] = ll; }
      Ahs[awidx] = h8; Als[awidx] = l8;
    }
    __syncthreads();
  }

#pragma unroll
  for (int mi = 0; mi < 4; ++mi)
#pragma unroll
    for (int ni = 0; ni < 2; ++ni) {
      int n = (nt << 7) + wid * 32 + ni * 16 + fi;
      float bv = HASBIAS ? bias[n] : 0.f;
#pragma unroll
      for (int r = 0; r < 4; ++r) {
        int m = m0 + mi * 16 + fq * 4 + r;
        float v = acc[mi][ni][r] + bv;
        if (ACT == 1) v = fmaxf(v, 0.f);
        out[(size_t)m * N + n] = v;
      }
    }
}

// ---------------- sum partials + bias -> relu -> LayerNorm (N=256) ----------------
__global__ __launch_bounds__(256) void ln_k(const float* __restrict__ part, int npart,
                                            const float* __restrict__ bias,
                                            const float* __restrict__ g,
                                            const float* __restrict__ bb,
                                            float* __restrict__ out) {
  int m = blockIdx.x, t = threadIdx.x;
  float s = bias[t];
  for (int z = 0; z < npart; ++z) s += part[((size_t)z * MROWS + m) * 256 + t];
  float v = fmaxf(s, 0.f);
  float sum = v, sq = v * v;
#pragma unroll
  for (int o = 1; o < 64; o <<= 1) { sum += __shfl_xor(sum, o); sq += __shfl_xor(sq, o); }
  __shared__ float s1[4], s2[4];
  int w = t >> 6;
  if ((t & 63) == 0) { s1[w] = sum; s2[w] = sq; }
  __syncthreads();
  sum = s1[0] + s1[1] + s1[2] + s1[3];
  sq  = s2[0] + s2[1] + s2[2] + s2[3];
  float mu  = sum * (1.f / 256.f);
  float var = sq * (1.f / 256.f) - mu * mu;
  out[(size_t)m * 256 + t] = (v - mu) * rsqrtf(var + 1e-5f) * g[t] + bb[t];
}

// ---------------- generic fp32 GEMM (kept for xproj N=80, dt K=16) ----------------
template <int RM, int ACT, int HASBIAS>
__global__ __launch_bounds__(256) void gemm_k(const float* __restrict__ A, int lda,
                                              const float* __restrict__ W,
                                              const float* __restrict__ bias,
                                              float* __restrict__ out,
                                              int M, int N, int K) {
  const int BM = RM * 16;
  __shared__ __align__(16) float As[16][RM * 16 + 4];
  __shared__ __align__(16) float Ws[16][68];
  int n0 = blockIdx.x << 6;
  int m0 = blockIdx.y * BM;
  int tid = threadIdx.x;
  int tx = tid & 15, ty = tid >> 4;
  float acc[RM][4];
#pragma unroll
  for (int r = 0; r < RM; ++r)
#pragma unroll
    for (int j = 0; j < 4; ++j) acc[r][j] = 0.f;

  for (int k0 = 0; k0 < K; k0 += 16) {
    __syncthreads();
    for (int i = tid; i < BM * 16; i += 256) {
      int r = i >> 4, kk = i & 15;
      As[kk][r] = A[(size_t)(m0 + r) * lda + k0 + kk];
    }
    for (int i = tid; i < 64 * 16; i += 256) {
      int r = i >> 4, kk = i & 15;
      int n = n0 + r;
      Ws[kk][r] = (n < N) ? W[(size_t)n * K + k0 + kk] : 0.f;
    }
    __syncthreads();
#pragma unroll
    for (int kk = 0; kk < 16; ++kk) {
      float4 wv = *(const float4*)&Ws[kk][tx << 2];
#pragma unroll
      for (int r = 0; r < RM; ++r) {
        float a = As[kk][ty * RM + r];
        acc[r][0] = fmaf(a, wv.x, acc[r][0]);
        acc[r][1] = fmaf(a, wv.y, acc[r][1]);
        acc[r][2] = fmaf(a, wv.z, acc[r][2]);
        acc[r][3] = fmaf(a, wv.w, acc[r][3]);
      }
    }
  }
#pragma unroll
  for (int r = 0; r < RM; ++r) {
    int m = m0 + ty * RM + r;
#pragma unroll
    for (int j = 0; j < 4; ++j) {
      int n = n0 + (tx << 2) + j;
      if (n < N) {
        float v = acc[r][j];
        if (HASBIAS) v += bias[n];
        if (ACT == 1) v = fmaxf(v, 0.f);
        if (ACT == 2) v = softplusf(v);
        out[(size_t)m * N + n] = v;
      }
    }
  }
}

// ---------------- xs = skip + pos ----------------
__global__ __launch_bounds__(256) void addpos_k(const float* __restrict__ a,
                                                const float* __restrict__ pos,
                                                float* __restrict__ o) {
  int i = blockIdx.x * 256 + threadIdx.x;
  o[i] = a[i] + pos[i & 65535];
}

// ---------------- causal depthwise conv1d(k=4) + silu ----------------
__global__ __launch_bounds__(256) void conv1d_silu_k(const float* __restrict__ xz,
                                                     const float* __restrict__ w,
                                                     const float* __restrict__ cb,
                                                     float* __restrict__ xc) {
  int i = blockIdx.x * 256 + threadIdx.x;  // over 2048*512
  int m = i >> 9, d = i & 511;
  int b = m >> 8, l = m & 255;
  float s = cb[d];
#pragma unroll
  for (int j = 0; j < 4; ++j) {
    int ll = l - 3 + j;
    if (ll >= 0) s = fmaf(w[(d << 2) + j], xz[((size_t)((b << 8) + ll) << 10) + d], s);
  }
  xc[(size_t)m * 512 + d] = siluf(s);
}

// ---------------- selective scan, windowed (16-step windows, spill-free) ----------------
__global__ __launch_bounds__(256, 1) void scan_k(const float* __restrict__ dt,
                                                 const float* __restrict__ u,
                                                 const float* __restrict__ xdbl,
                                                 const float* __restrict__ Alog,
                                                 const float* __restrict__ Dp,
                                                 const float* __restrict__ xz,
                                                 float* __restrict__ yg) {
  __shared__ float pbuf[4][2][16][33];
  int tid  = threadIdx.x;
  int widx = tid >> 6, lane = tid & 63;
  int wid  = (blockIdx.x << 2) + widx;
  int n = lane & 31, ch = lane >> 5;
  int d0 = (wid & 255) << 1;
  int d = d0 + ch;
  int b = wid >> 8;
  size_t base = (size_t)b << 8;
  float Av = -__expf(Alog[(d << 5) + n]);
  float Dv0 = Dp[d0], Dv1 = Dp[d0 + 1];
  float h = 0.f;
  int row = lane & 31;
  int rch = row >> 4, rlp = row & 15;
  int nh  = lane >> 5;
  int drow = d0 + rch;
  float Dsel = rch ? Dv1 : Dv0;

  for (int w0 = 0; w0 < 256; w0 += 16) {
    float dA[16], dBu[16], Cv[16];
#pragma unroll
    for (int j = 0; j < 16; ++j) {
      size_t r = base + w0 + j;
      float dtv = dt[(r << 9) + d];
      float uv  = u [(r << 9) + d];
      float Bv  = xdbl[r * 80 + 16 + n];
      Cv[j]     = xdbl[r * 80 + 48 + n];
      dA[j]  = __expf(dtv * Av);
      dBu[j] = dtv * Bv * uv;
    }
#pragma unroll
    for (int j = 0; j < 16; ++j) {
      h = fmaf(dA[j], h, dBu[j]);
      pbuf[widx][ch][j][n] = h * Cv[j];
    }
    __syncthreads();
    float s = 0.f;
#pragma unroll
    for (int nn = 0; nn < 16; ++nn) s += pbuf[widx][rch][rlp][(nh << 4) + nn];
    s += __shfl_xor(s, 32);
    if (lane < 32) {
      size_t r = base + w0 + rlp;
      float uv = u[(r << 9) + drow];
      float zv = xz[(r << 10) + 512 + drow];
      yg[(r << 9) + drow] = (s + uv * Dsel) * siluf(zv);
    }
    __syncthreads();
  }
}

// ---------------- cat = [xs2 | skip] ----------------
__global__ __launch_bounds__(256) void concat_k(const float* __restrict__ a,
                                                const float* __restrict__ b,
                                                float* __restrict__ o) {
  int i = blockIdx.x * 256 + threadIdx.x;  // 2048*512
  int m = i >> 9, j = i & 511;
  o[i] = (j < 256) ? a[(size_t)m * 256 + j] : b[(size_t)m * 256 + j - 256];
}

// ---------------- direct 3x3 conv (IC=1 only), relu ----------------
template <int IC>
__global__ __launch_bounds__(256) void conv3x3_k(const float* __restrict__ in,
                                                 const float* __restrict__ w,
                                                 const float* __restrict__ bias,
                                                 float* __restrict__ out) {
  __shared__ float t[IC][6][68];
  __shared__ float wl[IC * 144];
  __shared__ float bl[16];
  int bid = blockIdx.x;
  int x0 = (bid & 3) << 6;
  int y0 = ((bid >> 2) & 63) << 2;
  int bb = bid >> 8;
  int tid = threadIdx.x;
  for (int i = tid; i < IC * 144; i += 256) {
    int oc = i & 15, t2 = i >> 4;
    wl[i] = w[(size_t)oc * (IC * 9) + t2];
  }
  if (tid < 16) bl[tid] = bias[tid];
  for (int i = tid; i < IC * 396; i += 256) {
    int ic = i / 396, rem = i - ic * 396;
    int r = rem / 66, cx = rem - r * 66;
    int y = y0 - 1 + r, xx = x0 - 1 + cx;
    float v = 0.f;
    if (y >= 0 && y < 256 && xx >= 0 && xx < 256)
      v = in[(((size_t)bb * IC + ic) << 16) + (y << 8) + xx];
    t[ic][r][cx] = v;
  }
  __syncthreads();
  int tx = tid & 15, row = (tid >> 4) & 3, ocq = tid >> 6;
  float acc[4][4];
#pragma unroll
  for (int o = 0; o < 4; ++o)
#pragma unroll
    for (int p = 0; p < 4; ++p) acc[o][p] = 0.f;

  for (int ic = 0; ic < IC; ++ic) {
#pragma unroll
    for (int dy = 0; dy < 3; ++dy) {
      const float* rp = &t[ic][row + dy][tx << 2];
      float rv[6];
#pragma unroll
      for (int q = 0; q < 6; ++q) rv[q] = rp[q];
#pragma unroll
      for (int dx = 0; dx < 3; ++dx) {
        const float* wp4 = &wl[(((ic * 3 + dy) * 3 + dx) << 4) + (ocq << 2)];
#pragma unroll
        for (int o = 0; o < 4; ++o) {
          float wv = wp4[o];
#pragma unroll
          for (int p = 0; p < 4; ++p) acc[o][p] = fmaf(rv[p + dx], wv, acc[o][p]);
        }
      }
    }
  }
  int xo = x0 + (tx << 2), yo = y0 + row;
#pragma unroll
  for (int o = 0; o < 4; ++o) {
    int oc = (ocq << 2) + o;
    float4 v4;
    v4.x = fmaxf(acc[o][0] + bl[oc], 0.f);
    v4.y = fmaxf(acc[o][1] + bl[oc], 0.f);
    v4.z = fmaxf(acc[o][2] + bl[oc], 0.f);
    v4.w = fmaxf(acc[o][3] + bl[oc], 0.f);
    *(float4*)&out[(((size_t)bb * 16 + oc) << 16) + (yo << 8) + xo] = v4;
  }
}

// ---------------- MFMA implicit-GEMM 3x3 conv, IC=OC=16, relu ----------------
// Block = 32x16 px tile (M=512), N=16 oc, K=144 pad 160. 4 waves, 8 m-frags each.
// Input staged split-bf16 in LDS [y:18][x:34][ic pad 24]; W frags direct from L2.
__global__ __launch_bounds__(256, 2) void conv_mfma(const float* __restrict__ in,
                                                    const unsigned short* __restrict__ wth,
                                                    const unsigned short* __restrict__ wtl,
                                                    const float* __restrict__ bias,
                                                    float* __restrict__ out) {
  __shared__ __align__(16) char smem[58752];
  unsigned short* inh = (unsigned short*)smem;          // 14688 elems
  unsigned short* inl = inh + 14688;                    // 14688 elems
  int bid = blockIdx.x;
  int txi = bid & 7;            // x tile (32 px)
  int tyi = (bid >> 3) & 15;    // y tile (16 px)
  int bb  = bid >> 7;
  int x0 = txi << 5, y0 = tyi << 4;
  int tid = threadIdx.x;

  // ---- stage input tile: [ic][gy][gx] fp32 -> LDS [y][x][ic] split h/l ----
  for (int i = tid; i < 9792; i += 256) {     // 16 ic x 18 y x 34 x
    int ic = i / 612, rem = i - ic * 612;
    int y = rem / 34, xx = rem - y * 34;
    int gy = y0 + y - 1, gx = x0 + xx - 1;
    float v = 0.f;
    if (gy >= 0 && gy < 256 && gx >= 0 && gx < 256)
      v = in[(((size_t)bb * 16 + ic) << 16) + (gy << 8) + gx];
    short hh, ll; split2(v, hh, ll);
    int a = (y * 34 + xx) * 24 + ic;
    inh[a] = (unsigned short)hh; inl[a] = (unsigned short)ll;
  }
  __syncthreads();

  int lane = tid & 63, w = tid >> 6;
  int fi = lane & 15, fq = lane >> 4;
  int fqh = fq >> 1, ich8 = (fq & 1) << 3;

  // per-step A deltas (dydx = 2*step + fqh; clamp pad 9->8, B is zero there)
  int adel[5];
#pragma unroll
  for (int s = 0; s < 5; ++s) {
    int dydx = 2 * s + fqh;
    if (dydx > 8) dydx = 8;
    int dy = dydx / 3, dx = dydx - dy * 3;
    adel[s] = (dy * 34 + dx) * 24;
  }
  // m-frag base addrs
  int abase[8];
#pragma unroll
  for (int q = 0; q < 8; ++q) {
    int px = ((w * 8 + q) << 4) + fi;
    int y = px >> 5, xx = px & 31;
    abase[q] = (y * 34 + xx) * 24 + ich8;
  }
  // B frags (L2-resident tiled image)
  short8v bh[5], bl[5];
#pragma unroll
  for (int s = 0; s < 5; ++s) {
    int slot = ((s * 4 + fq) * 16 + fi) * 8;
    bh[s] = *(const short8v*)(wth + slot);
    bl[s] = *(const short8v*)(wtl + slot);
  }

  f32x4 acc[8];
#pragma unroll
  for (int q = 0; q < 8; ++q) acc[q] = (f32x4)(0.f);

#pragma unroll
  for (int s = 0; s < 5; ++s) {
#pragma unroll
    for (int q = 0; q < 8; ++q) {
      short8v ah = *(const short8v*)&inh[abase[q] + adel[s]];
      short8v al = *(const short8v*)&inl[abase[q] + adel[s]];
      MFMA3(acc[q], ah, al, bh[s], bl[s]);
    }
  }
  __syncthreads();   // A reads done; reuse smem as out-stage [16 oc][514]

  float* outs = (float*)smem;
#pragma unroll
  for (int q = 0; q < 8; ++q) {
    int pxb = ((w * 8 + q) << 4) + (fq << 2);
#pragma unroll
    for (int r = 0; r < 4; ++r)
      outs[fi * 514 + pxb + r] = acc[q][r];
  }
  __syncthreads();
  for (int i = tid; i < 8192; i += 256) {
    int oc = i >> 9, px = i & 511;
    int y = px >> 5, xx = px & 31;
    float v = fmaxf(outs[oc * 514 + px] + bias[oc], 0.f);
    out[(((size_t)bb * 16 + oc) << 16) + ((y0 + y) << 8) + x0 + xx] = v;
  }
}

// ---------------- 2x2 mean pool + 1x1 conv (16->1) ----------------
__global__ __launch_bounds__(256) void pool_c4_k(const float* __restrict__ in,
                                                 const float* __restrict__ w4,
                                                 const float* __restrict__ b4,
                                                 float* __restrict__ out) {
  int i = blockIdx.x * 256 + threadIdx.x;  // 8*128*128
  int x = i & 127, y = (i >> 7) & 127, b = i >> 14;
  float s = b4[0];
#pragma unroll
  for (int ic = 0; ic < 16; ++ic) {
    const float* p = in + (((size_t)b * 16 + ic) << 16) + ((size_t)(y << 1) << 8) + (x << 1);
    float m4 = 0.25f * (p[0] + p[1] + p[256] + p[257]);
    s = fmaf(w4[ic], m4, s);
  }
  out[i] = s;
}

// ---------------- launcher ----------------
extern "C" void kernel_launch(void* const* d_in, const int* in_sizes, int n_in,
                              void* d_out, int out_size, void* d_ws, size_t ws_size,
                              hipStream_t stream) {
  const float* x        = (const float*)d_in[0];
  const float* lin0_w   = (const float*)d_in[1];
  const float* lin0_b   = (const float*)d_in[2];
  const float* ln0_g    = (const float*)d_in[3];
  const float* ln0_bb   = (const float*)d_in[4];
  const float* lin1_w   = (const float*)d_in[5];
  const float* lin1_b   = (const float*)d_in[6];
  const float* ln1_g    = (const float*)d_in[7];
  const float* ln1_bb   = (const float*)d_in[8];
  const float* pos      = (const float*)d_in[9];
  const float* m_in_w   = (const float*)d_in[10];
  const float* m_conv_w = (const float*)d_in[11];
  const float* m_conv_b = (const float*)d_in[12];
  const float* m_xproj_w= (const float*)d_in[13];
  const float* m_dt_w   = (const float*)d_in[14];
  const float* m_dt_b   = (const float*)d_in[15];
  const float* m_Alog   = (const float*)d_in[16];
  const float* m_D      = (const float*)d_in[17];
  const float* m_out_w  = (const float*)d_in[18];
  const float* blk_w    = (const float*)d_in[19];
  const float* blk_b    = (const float*)d_in[20];
  const float* dec_w    = (const float*)d_in[21];
  const float* dec_b    = (const float*)d_in[22];
  const float* c1_w     = (const float*)d_in[23];
  const float* c1_b     = (const float*)d_in[24];
  const float* c2_w     = (const float*)d_in[25];
  const float* c2_b     = (const float*)d_in[26];
  const float* c3_w     = (const float*)d_in[27];
  const float* c3_b     = (const float*)d_in[28];
  const float* c4_w     = (const float*)d_in[29];
  const float* c4_b     = (const float*)d_in[30];

  float* ws  = (float*)d_ws;
  float* out = (float*)d_out;

  unsigned short* wt0h = (unsigned short*)(ws + F_WT0);
  unsigned short* wt0l = wt0h + 4194304;
  unsigned short* wmed = (unsigned short*)(ws + F_WMED);
  unsigned short* inw_h = wmed,           * inw_l = wmed + 262144;   // m_in_w 1024x256
  unsigned short* l1_h  = wmed + 524288,  * l1_l  = wmed + 589824;   // lin1_w 256x256
  unsigned short* ow_h  = wmed + 655360,  * ow_l  = wmed + 786432;   // m_out_w 256x512
  unsigned short* bk_h  = wmed + 917504,  * bk_l  = wmed + 983040;   // blk_w 256x256
  unsigned short* dc_h  = wmed + 1048576, * dc_l  = wmed + 1179648;  // dec_w 256x512
  unsigned short* wc2h  = wmed + 1310720, * wc2l  = wmed + 1313280;  // conv2 tiles (2560 each)
  unsigned short* wc3h  = wmed + 1315840, * wc3l  = wmed + 1318400;  // conv3 tiles

  // 1. weight tiling (split bf16, LDS/frag-image layout)
  tile_w_lin0<<<512, 256, 0, stream>>>(lin0_w, wt0h, wt0l);
  tile_w_med<<<128, 256, 0, stream>>>(m_in_w, inw_h, inw_l, 256, 32768);
  tile_w_med<<<32, 256, 0, stream>>>(lin1_w, l1_h, l1_l, 256, 8192);
  tile_w_med<<<64, 256, 0, stream>>>(m_out_w, ow_h, ow_l, 512, 16384);
  tile_w_med<<<32, 256, 0, stream>>>(blk_w, bk_h, bk_l, 256, 8192);
  tile_w_med<<<64, 256, 0, stream>>>(dec_w, dc_h, dc_l, 512, 16384);
  tile_w_conv<<<2, 256, 0, stream>>>(c2_w, wc2h, wc2l);
  tile_w_conv<<<2, 256, 0, stream>>>(c3_w, wc3h, wc3l);
  // 2. lin0 MFMA GEMM -> partials (BM=64, 512 blocks = 2/CU)
  lin0_mfma<<<512, 512, 0, stream>>>(x, wt0h, wt0l, ws + F_PART);
  // 3. reduce + bias + relu + LN0 -> xt0
  ln_k<<<MROWS, 256, 0, stream>>>(ws + F_PART, KSPLIT, lin0_b, ln0_g, ln0_bb, ws + F_XT0);
  // 4. lin1 -> part (raw) ; 5. bias+relu+LN1 -> skip
  med_mfma<0, 0><<<dim3(2, 32), 256, 0, stream>>>(ws + F_XT0, 256, l1_h, l1_l, nullptr,
                                                  ws + F_PART, 256, 256);
  ln_k<<<MROWS, 256, 0, stream>>>(ws + F_PART, 1, lin1_b, ln1_g, ln1_bb, ws + F_SKIP);
  // 6. xs = skip + pos
  addpos_k<<<2048, 256, 0, stream>>>(ws + F_SKIP, pos, ws + F_XS);
  // 7. xz = xs @ m_in_w^T  [2048,1024]
  med_mfma<0, 0><<<dim3(8, 32), 256, 0, stream>>>(ws + F_XS, 256, inw_h, inw_l, nullptr,
                                                  ws + F_XZ, 256, 1024);
  // 8. causal dwconv + silu -> xc
  conv1d_silu_k<<<4096, 256, 0, stream>>>(ws + F_XZ, m_conv_w, m_conv_b, ws + F_XC);
  // 9. x_dbl = xc @ m_xproj_w^T  [2048,80]
  gemm_k<2, 0, 0><<<dim3(2, 64), 256, 0, stream>>>(ws + F_XC, 512, m_xproj_w, nullptr,
                                                   ws + F_XDBL, MROWS, 80, 512);
  // 10. dt = softplus(x_dbl[:, :16] @ m_dt_w^T + m_dt_b)
  gemm_k<2, 2, 1><<<dim3(8, 64), 256, 0, stream>>>(ws + F_XDBL, 80, m_dt_w, m_dt_b,
                                                   ws + F_DT, MROWS, 512, 16);
  // 11. selective scan + silu(z) gating -> yg
  scan_k<<<512, 256, 0, stream>>>(ws + F_DT, ws + F_XC, ws + F_XDBL, m_Alog, m_D,
                                  ws + F_XZ, ws + F_YG);
  // 12. ym = yg @ m_out_w^T
  med_mfma<0, 0><<<dim3(2, 32), 256, 0, stream>>>(ws + F_YG, 512, ow_h, ow_l, nullptr,
                                                  ws + F_YM, 512, 256);
  // 13. xs2 = ym @ blk_w^T + blk_b
  med_mfma<0, 1><<<dim3(2, 32), 256, 0, stream>>>(ws + F_YM, 256, bk_h, bk_l, blk_b,
                                                  ws + F_XS2, 256, 256);
  // 14. cat = [xs2 | skip]
  concat_k<<<4096, 256, 0, stream>>>(ws + F_XS2, ws + F_SKIP, ws + F_CAT);
  // 15. dec = relu(cat @ dec_w^T + dec_b)
  med_mfma<1, 1><<<dim3(2, 32), 256, 0, stream>>>(ws + F_CAT, 512, dc_h, dc_l, dec_b,
                                                  ws + F_DEC, 512, 256);
  // 16. conv1 (IC=1, scalar)
  conv3x3_k<1><<<2048, 256, 0, stream>>>(ws + F_DEC, c1_w, c1_b, ws + F_C1);
  // 17-18. conv2/conv3 via MFMA implicit GEMM
  conv_mfma<<<1024, 256, 0, stream>>>(ws + F_C1, wc2h, wc2l, c2_b, ws + F_C2);
  conv_mfma<<<1024, 256, 0, stream>>>(ws + F_C2, wc3h, wc3l, c3_b, ws + F_C3);
  // 19. pool + 1x1 conv -> out
  pool_c4_k<<<512, 256, 0, stream>>>(ws + F_C3, c4_w, c4_b, out);
}